// Round 1
// baseline (1902.587 us; speedup 1.0000x reference)
//
#include <hip/hip_runtime.h>
#include <math.h>

// Problem constants (B=4, L=2048, C=1024, H=16, D=64)
#define BB 4
#define LL 2048
#define CC 1024
#define HH 16
#define DD 64
#define MM (BB * LL) // 8192 rows

// ---------------------------------------------------------------------------
// GEMM + bias: C[M][N] = A[M][K] @ B[K][N] + bias[N]   (row-major, strided)
// 128x128 tile, BK=8, 256 threads, 8x8 register tile per thread.
// ---------------------------------------------------------------------------
#define BM 128
#define BN 128
#define BKG 8

__global__ __launch_bounds__(256)
void gemm_bias(const float* __restrict__ A, const float* __restrict__ B,
               const float* __restrict__ bias, float* __restrict__ C,
               int M, int N, int K, int lda, int ldb, int ldc)
{
    __shared__ float As[BKG][BM]; // transposed A tile
    __shared__ float Bs[BKG][BN];

    const int tid = threadIdx.x;
    const int m0 = blockIdx.y * BM;
    const int n0 = blockIdx.x * BN;
    const int ty = tid >> 4, tx = tid & 15;

    const int arow = tid >> 1;        // 0..127
    const int acol = (tid & 1) * 4;   // 0 or 4
    const int brow = tid >> 5;        // 0..7
    const int bcol = (tid & 31) * 4;  // 0..124

    const float* Ap = A + (size_t)(m0 + arow) * lda + acol;
    const float* Bp = B + (size_t)brow * ldb + n0 + bcol;

    float acc[8][8];
#pragma unroll
    for (int i = 0; i < 8; ++i)
#pragma unroll
        for (int j = 0; j < 8; ++j) acc[i][j] = 0.f;

    for (int k0 = 0; k0 < K; k0 += BKG) {
        float4 av = *(const float4*)(Ap + k0);
        float4 bv = *(const float4*)(Bp + (size_t)k0 * ldb);
        __syncthreads(); // previous tile fully consumed
        As[acol + 0][arow] = av.x;
        As[acol + 1][arow] = av.y;
        As[acol + 2][arow] = av.z;
        As[acol + 3][arow] = av.w;
        *(float4*)&Bs[brow][bcol] = bv;
        __syncthreads();
#pragma unroll
        for (int kk = 0; kk < BKG; ++kk) {
            float a[8], b[8];
            *(float4*)&a[0] = *(const float4*)&As[kk][ty * 4];
            *(float4*)&a[4] = *(const float4*)&As[kk][64 + ty * 4];
            *(float4*)&b[0] = *(const float4*)&Bs[kk][tx * 4];
            *(float4*)&b[4] = *(const float4*)&Bs[kk][64 + tx * 4];
#pragma unroll
            for (int i = 0; i < 8; ++i)
#pragma unroll
                for (int j = 0; j < 8; ++j)
                    acc[i][j] = fmaf(a[i], b[j], acc[i][j]);
        }
    }

#pragma unroll
    for (int ih = 0; ih < 2; ++ih)
#pragma unroll
    for (int i = 0; i < 4; ++i) {
        const int m = m0 + ih * 64 + ty * 4 + i;
#pragma unroll
        for (int jh = 0; jh < 2; ++jh) {
            const int n = n0 + jh * 64 + tx * 4;
            float4 o;
            o.x = acc[ih*4+i][jh*4+0] + bias[n+0];
            o.y = acc[ih*4+i][jh*4+1] + bias[n+1];
            o.z = acc[ih*4+i][jh*4+2] + bias[n+2];
            o.w = acc[ih*4+i][jh*4+3] + bias[n+3];
            *(float4*)(C + (size_t)m * ldc + n) = o;
        }
    }
}

// ---------------------------------------------------------------------------
// Per-head RMS norm of q and k: t = t / max(||t||_2, 1e-12) * gamma * sqrt(D)
// One wave (64 lanes) per (b,l,h,{q|k}) row; lane = d.
// ---------------------------------------------------------------------------
__global__ __launch_bounds__(256)
void rmsnorm_qk(float* __restrict__ qkv,
                const float* __restrict__ gq, const float* __restrict__ gk)
{
    const int gt    = blockIdx.x * 256 + threadIdx.x;
    const int lane  = gt & 63;
    const int wave  = gt >> 6;          // 0 .. MM*HH*2-1
    const int which = wave & 1;         // 0 = q, 1 = k
    const int h     = (wave >> 1) & (HH - 1);
    const int bl    = wave >> 5;        // / (HH*2)

    float* p = qkv + (size_t)bl * (3 * CC) + which * CC + h * DD + lane;
    float v = *p;
    float ss = v * v;
#pragma unroll
    for (int off = 32; off; off >>= 1) ss += __shfl_xor(ss, off);
    float nrm = fmaxf(sqrtf(ss), 1e-12f);
    const float* g = which ? gk : gq;
    *p = v * (8.0f / nrm) * g[h * DD + lane];
}

// ---------------------------------------------------------------------------
// Flash attention (fp32). One block per (b, h, 64-row Q tile); 256 threads,
// 16x16 thread grid, each thread owns a 4x4 fragment of S/P and of O.
// Writes h in-place over the q slots of the qkv buffer (unique owner).
// ---------------------------------------------------------------------------
#define BQ 64
#define BKV 64

__global__ __launch_bounds__(256)
void flash_attn(float* __restrict__ qkv)
{
    const int qt = blockIdx.x; // 0..31
    const int hh = blockIdx.y; // 0..15
    const int bb = blockIdx.z; // 0..3

    __shared__ float Qt[DD][BQ];       // Q transposed: [d][q]
    __shared__ float Kt[DD][BKV];      // K transposed: [d][k]
    __shared__ float Vs[BKV][DD];      // V natural:    [k][d]
    __shared__ float Ps[BQ][BKV + 4];  // P natural, padded: [q][k]

    const int tid = threadIdx.x;
    const int ty = tid >> 4, tx = tid & 15;

    const size_t rs_ = 3 * CC;
    const float* qbase = qkv + ((size_t)bb * LL + (size_t)qt * BQ) * rs_ + hh * DD;
    const float* kbase = qkv + (size_t)bb * LL * rs_ + CC + hh * DD;
    const float* vbase = kbase + CC;

    // stage Q tile transposed (64 rows x 64 cols; 16 floats per thread)
    {
        const int r  = tid >> 2;
        const int c0 = (tid & 3) * 16;
#pragma unroll
        for (int u = 0; u < 4; ++u) {
            float4 v = *(const float4*)(qbase + (size_t)r * rs_ + c0 + u * 4);
            Qt[c0 + u*4 + 0][r] = v.x;
            Qt[c0 + u*4 + 1][r] = v.y;
            Qt[c0 + u*4 + 2][r] = v.z;
            Qt[c0 + u*4 + 3][r] = v.w;
        }
    }

    float mrow[4], lrow[4], O[4][4];
#pragma unroll
    for (int i = 0; i < 4; ++i) {
        mrow[i] = -INFINITY;
        lrow[i] = 0.f;
#pragma unroll
        for (int j = 0; j < 4; ++j) O[i][j] = 0.f;
    }

    for (int kt = 0; kt < LL / BKV; ++kt) {
        __syncthreads(); // Kt/Vs/Ps from previous iteration fully consumed
        {
            const int r  = tid >> 2;
            const int c0 = (tid & 3) * 16;
            const float* kr = vbase - CC + ((size_t)kt * BKV + r) * rs_; // kbase row
            const float* vr = vbase + ((size_t)kt * BKV + r) * rs_;
#pragma unroll
            for (int u = 0; u < 4; ++u) {
                float4 kv = *(const float4*)(kr + c0 + u * 4);
                Kt[c0 + u*4 + 0][r] = kv.x;
                Kt[c0 + u*4 + 1][r] = kv.y;
                Kt[c0 + u*4 + 2][r] = kv.z;
                Kt[c0 + u*4 + 3][r] = kv.w;
                *(float4*)&Vs[r][c0 + u*4] = *(const float4*)(vr + c0 + u * 4);
            }
        }
        __syncthreads();

        // S = (Q K^T) * 1/sqrt(D); thread fragment 4x4
        float S[4][4];
#pragma unroll
        for (int i = 0; i < 4; ++i)
#pragma unroll
            for (int j = 0; j < 4; ++j) S[i][j] = 0.f;

#pragma unroll 8
        for (int d = 0; d < DD; ++d) {
            float a[4], b[4];
            *(float4*)a = *(const float4*)&Qt[d][ty * 4];
            *(float4*)b = *(const float4*)&Kt[d][tx * 4];
#pragma unroll
            for (int i = 0; i < 4; ++i)
#pragma unroll
                for (int j = 0; j < 4; ++j)
                    S[i][j] = fmaf(a[i], b[j], S[i][j]);
        }

        // online softmax update (row reduce across the 16 tx lanes)
#pragma unroll
        for (int i = 0; i < 4; ++i) {
#pragma unroll
            for (int j = 0; j < 4; ++j) S[i][j] *= 0.125f;
            float pm = fmaxf(fmaxf(S[i][0], S[i][1]), fmaxf(S[i][2], S[i][3]));
#pragma unroll
            for (int off = 1; off < 16; off <<= 1) pm = fmaxf(pm, __shfl_xor(pm, off));
            const float mnew = fmaxf(mrow[i], pm);
            const float corr = __expf(mrow[i] - mnew); // exp(-inf)=0 on first tile
            float rsum = 0.f;
#pragma unroll
            for (int j = 0; j < 4; ++j) { S[i][j] = __expf(S[i][j] - mnew); rsum += S[i][j]; }
#pragma unroll
            for (int off = 1; off < 16; off <<= 1) rsum += __shfl_xor(rsum, off);
            mrow[i] = mnew;
            lrow[i] = lrow[i] * corr + rsum;
#pragma unroll
            for (int j = 0; j < 4; ++j) O[i][j] *= corr;
        }

        // stage P
#pragma unroll
        for (int i = 0; i < 4; ++i)
            *(float4*)&Ps[ty * 4 + i][tx * 4] = *(float4*)&S[i][0];
        __syncthreads();

        // O += P @ V
#pragma unroll 4
        for (int k = 0; k < BKV; k += 4) {
            float a[4][4];
#pragma unroll
            for (int i = 0; i < 4; ++i)
                *(float4*)&a[i][0] = *(const float4*)&Ps[ty * 4 + i][k];
#pragma unroll
            for (int kk = 0; kk < 4; ++kk) {
                float b[4];
                *(float4*)b = *(const float4*)&Vs[k + kk][tx * 4];
#pragma unroll
                for (int i = 0; i < 4; ++i)
#pragma unroll
                    for (int j = 0; j < 4; ++j)
                        O[i][j] = fmaf(a[i][kk], b[j], O[i][j]);
            }
        }
    }

    // epilogue: h = O / l, written over the q slots (cols 0..C-1) of qkv rows
    float* obase = qkv + ((size_t)bb * LL + (size_t)qt * BQ) * rs_ + hh * DD;
#pragma unroll
    for (int i = 0; i < 4; ++i) {
        const float inv = 1.f / lrow[i];
        float4 o;
        o.x = O[i][0] * inv;
        o.y = O[i][1] * inv;
        o.z = O[i][2] * inv;
        o.w = O[i][3] * inv;
        *(float4*)(obase + (size_t)(ty * 4 + i) * rs_ + tx * 4) = o;
    }
}

// ---------------------------------------------------------------------------
extern "C" void kernel_launch(void* const* d_in, const int* in_sizes, int n_in,
                              void* d_out, int out_size, void* d_ws, size_t ws_size,
                              hipStream_t stream)
{
    const float* x    = (const float*)d_in[0]; // [B,L,C]
    const float* Wqkv = (const float*)d_in[1]; // [C,3C]
    const float* bqkv = (const float*)d_in[2]; // [3C]
    const float* gq   = (const float*)d_in[3]; // [H,D]
    const float* gk   = (const float*)d_in[4]; // [H,D]
    const float* Wout = (const float*)d_in[5]; // [C,C]
    const float* bout = (const float*)d_in[6]; // [C]
    float* out = (float*)d_out;                // [B*L, C]
    float* qkv = (float*)d_ws;                 // [MM, 3C] fp32 = 96 MB

    // 1) qkv = x @ Wqkv + bqkv
    gemm_bias<<<dim3((3 * CC) / BN, MM / BM), 256, 0, stream>>>(
        x, Wqkv, bqkv, qkv, MM, 3 * CC, CC, CC, 3 * CC, 3 * CC);

    // 2) per-head RMS norm of q and k
    rmsnorm_qk<<<dim3((MM * HH * 2 * 64) / 256), 256, 0, stream>>>(qkv, gq, gk);

    // 3) flash attention; h overwrites the q region of qkv (stride 3C)
    flash_attn<<<dim3(LL / BQ, HH, BB), 256, 0, stream>>>(qkv);

    // 4) out = h @ Wout + bout   (A = qkv q-region, lda = 3C)
    gemm_bias<<<dim3(CC / BN, MM / BM), 256, 0, stream>>>(
        qkv, Wout, bout, out, MM, CC, CC, 3 * CC, CC, CC);
}

// Round 2
// 1302.461 us; speedup vs baseline: 1.4608x; 1.4608x over previous
//
#include <hip/hip_runtime.h>
#include <math.h>

// Problem constants (B=4, L=2048, C=1024, H=16, D=64)
#define BB 4
#define LL 2048
#define CC 1024
#define HH 16
#define DD 64
#define MM (BB * LL) // 8192 rows

typedef float f32x4 __attribute__((ext_vector_type(4)));
typedef short short8 __attribute__((ext_vector_type(8))); // 8 bf16 (4 VGPRs)

#define MFMA_BF16(A, B, C) __builtin_amdgcn_mfma_f32_16x16x32_bf16(A, B, C, 0, 0, 0)

__device__ __forceinline__ unsigned short f2bf(float x) {
    unsigned int u = __float_as_uint(x);
    u += 0x7fffu + ((u >> 16) & 1u); // RTN-even
    return (unsigned short)(u >> 16);
}
__device__ __forceinline__ float bf2f(unsigned short h) {
    return __uint_as_float(((unsigned int)h) << 16);
}

// ---------------------------------------------------------------------------
// GEMM + bias: C[M][N] = A[M][K] @ B[K][N] + bias[N]   (row-major, strided)
// ---------------------------------------------------------------------------
#define BM 128
#define BN 128
#define BKG 8

__global__ __launch_bounds__(256)
void gemm_bias(const float* __restrict__ A, const float* __restrict__ B,
               const float* __restrict__ bias, float* __restrict__ C,
               int M, int N, int K, int lda, int ldb, int ldc)
{
    __shared__ float As[BKG][BM]; // transposed A tile
    __shared__ float Bs[BKG][BN];

    const int tid = threadIdx.x;
    const int m0 = blockIdx.y * BM;
    const int n0 = blockIdx.x * BN;
    const int ty = tid >> 4, tx = tid & 15;

    const int arow = tid >> 1;
    const int acol = (tid & 1) * 4;
    const int brow = tid >> 5;
    const int bcol = (tid & 31) * 4;

    const float* Ap = A + (size_t)(m0 + arow) * lda + acol;
    const float* Bp = B + (size_t)brow * ldb + n0 + bcol;

    float acc[8][8];
#pragma unroll
    for (int i = 0; i < 8; ++i)
#pragma unroll
        for (int j = 0; j < 8; ++j) acc[i][j] = 0.f;

    for (int k0 = 0; k0 < K; k0 += BKG) {
        float4 av = *(const float4*)(Ap + k0);
        float4 bv = *(const float4*)(Bp + (size_t)k0 * ldb);
        __syncthreads();
        As[acol + 0][arow] = av.x;
        As[acol + 1][arow] = av.y;
        As[acol + 2][arow] = av.z;
        As[acol + 3][arow] = av.w;
        *(float4*)&Bs[brow][bcol] = bv;
        __syncthreads();
#pragma unroll
        for (int kk = 0; kk < BKG; ++kk) {
            float a[8], b[8];
            *(float4*)&a[0] = *(const float4*)&As[kk][ty * 4];
            *(float4*)&a[4] = *(const float4*)&As[kk][64 + ty * 4];
            *(float4*)&b[0] = *(const float4*)&Bs[kk][tx * 4];
            *(float4*)&b[4] = *(const float4*)&Bs[kk][64 + tx * 4];
#pragma unroll
            for (int i = 0; i < 8; ++i)
#pragma unroll
                for (int j = 0; j < 8; ++j)
                    acc[i][j] = fmaf(a[i], b[j], acc[i][j]);
        }
    }

#pragma unroll
    for (int ih = 0; ih < 2; ++ih)
#pragma unroll
    for (int i = 0; i < 4; ++i) {
        const int m = m0 + ih * 64 + ty * 4 + i;
#pragma unroll
        for (int jh = 0; jh < 2; ++jh) {
            const int n = n0 + jh * 64 + tx * 4;
            float4 o;
            o.x = acc[ih*4+i][jh*4+0] + bias[n+0];
            o.y = acc[ih*4+i][jh*4+1] + bias[n+1];
            o.z = acc[ih*4+i][jh*4+2] + bias[n+2];
            o.w = acc[ih*4+i][jh*4+3] + bias[n+3];
            *(float4*)(C + (size_t)m * ldc + n) = o;
        }
    }
}

// ---------------------------------------------------------------------------
// Per-head RMS norm of q and k
// ---------------------------------------------------------------------------
__global__ __launch_bounds__(256)
void rmsnorm_qk(float* __restrict__ qkv,
                const float* __restrict__ gq, const float* __restrict__ gk)
{
    const int gt    = blockIdx.x * 256 + threadIdx.x;
    const int lane  = gt & 63;
    const int wave  = gt >> 6;
    const int which = wave & 1;
    const int h     = (wave >> 1) & (HH - 1);
    const int bl    = wave >> 5;

    float* p = qkv + (size_t)bl * (3 * CC) + which * CC + h * DD + lane;
    float v = *p;
    float ss = v * v;
#pragma unroll
    for (int off = 32; off; off >>= 1) ss += __shfl_xor(ss, off);
    float nrm = fmaxf(sqrtf(ss), 1e-12f);
    const float* g = which ? gk : gq;
    *p = v * (8.0f / nrm) * g[h * DD + lane];
}

// ---------------------------------------------------------------------------
// Flash attention, bf16 MFMA with hi/lo split (fp32-accurate).
// 1 block = 4 waves = (b, h, 64-row Q tile). KV tile = 64.
// Wave w owns S/O rows [16w, 16w+16).
// K LDS: bf16 hi/lo, row-major [k][d], elem-swizzle ^((row&7)<<3)
// V LDS: bf16 hi/lo, transposed [d][k], elem-swizzle ^(((d&7)^(d>>3))<<3)
// P LDS: f32 per-wave [q][k],            elem-swizzle ^((q&15)<<2)
// ---------------------------------------------------------------------------
__global__ __launch_bounds__(256)
void flash_attn_mfma(float* __restrict__ qkv)
{
    __shared__ unsigned short sKh[64 * 64];
    __shared__ unsigned short sKl[64 * 64];
    __shared__ unsigned short sVh[64 * 64];
    __shared__ unsigned short sVl[64 * 64];
    __shared__ float sP[4][16 * 64];

    const int tid  = threadIdx.x;
    const int lane = tid & 63;
    const int wv   = tid >> 6;
    const int l4   = lane >> 4;   // 0..3
    const int l16  = lane & 15;   // 0..15

    const int qt = blockIdx.x, hh = blockIdx.y, bb = blockIdx.z;
    const size_t rs_ = 3 * CC;

    // ---- Q fragments (scaled by 1/sqrt(D)=0.125), hi/lo split, in registers
    short8 qh[2], ql[2];
    {
        const int qrow = bb * LL + qt * 64 + wv * 16 + l16;
        const float* qp = qkv + (size_t)qrow * rs_ + hh * DD + 8 * l4;
#pragma unroll
        for (int sl = 0; sl < 2; ++sl) {
            f32x4 a = *(const f32x4*)(qp + 32 * sl);
            f32x4 b = *(const f32x4*)(qp + 32 * sl + 4);
#pragma unroll
            for (int j = 0; j < 4; ++j) {
                float x = a[j] * 0.125f;
                unsigned short h = f2bf(x);
                qh[sl][j] = (short)h;
                ql[sl][j] = (short)f2bf(x - bf2f(h));
            }
#pragma unroll
            for (int j = 0; j < 4; ++j) {
                float x = b[j] * 0.125f;
                unsigned short h = f2bf(x);
                qh[sl][4 + j] = (short)h;
                ql[sl][4 + j] = (short)f2bf(x - bf2f(h));
            }
        }
    }

    f32x4 O[4];
    float mrow[4], lrow[4];
#pragma unroll
    for (int i = 0; i < 4; ++i) { O[i] = 0.f; mrow[i] = -INFINITY; lrow[i] = 0.f; }

    const int r_ = tid >> 2;          // 0..63 staging row
    const int c_ = (tid & 3) * 16;    // 0,16,32,48 staging col

    for (int kt = 0; kt < LL / 64; ++kt) {
        __syncthreads(); // previous tile fully consumed
        // ---- stage K (row-major) and V (transposed), bf16 hi/lo
        {
            const float* kg = qkv + (size_t)(bb * LL + kt * 64 + r_) * rs_ + CC + hh * DD + c_;
            const float* vg = kg + CC;
            f32x4 kv[4], vv[4];
#pragma unroll
            for (int u = 0; u < 4; ++u) {
                kv[u] = *(const f32x4*)(kg + 4 * u);
                vv[u] = *(const f32x4*)(vg + 4 * u);
            }
            // K: two 8-elem vector stores for hi and lo
            short8 ha, hb, la, lb;
#pragma unroll
            for (int j = 0; j < 8; ++j) {
                float x0 = kv[j >> 2][j & 3];
                unsigned short h0 = f2bf(x0);
                ha[j] = (short)h0; la[j] = (short)f2bf(x0 - bf2f(h0));
                float x1 = kv[2 + (j >> 2)][j & 3];
                unsigned short h1 = f2bf(x1);
                hb[j] = (short)h1; lb[j] = (short)f2bf(x1 - bf2f(h1));
            }
            const int kbase = r_ * 64 + c_;
            const int ksw   = (r_ & 7) << 3;
            *(short8*)&sKh[(kbase) ^ ksw]     = ha;
            *(short8*)&sKh[(kbase + 8) ^ ksw] = hb;
            *(short8*)&sKl[(kbase) ^ ksw]     = la;
            *(short8*)&sKl[(kbase + 8) ^ ksw] = lb;
            // V: scatter transposed
#pragma unroll
            for (int u = 0; u < 16; ++u) {
                const int d = c_ + u;
                const int idx = (d * 64 + r_) ^ ((((d & 7) ^ (d >> 3)) & 7) << 3);
                float x = vv[u >> 2][u & 3];
                unsigned short h = f2bf(x);
                sVh[idx] = h;
                sVl[idx] = f2bf(x - bf2f(h));
            }
        }
        __syncthreads();

        // ---- S = Q K^T (3-term hi/lo split)
        f32x4 S[4];
#pragma unroll
        for (int t = 0; t < 4; ++t) S[t] = 0.f;
#pragma unroll
        for (int t = 0; t < 4; ++t) {
            const int row = 16 * t + l16;
            const int sw  = (row & 7) << 3;
#pragma unroll
            for (int sl = 0; sl < 2; ++sl) {
                const int idx = (row * 64 + 32 * sl + 8 * l4) ^ sw;
                short8 kh = *(const short8*)&sKh[idx];
                short8 kl = *(const short8*)&sKl[idx];
                S[t] = MFMA_BF16(qh[sl], kh, S[t]);
                S[t] = MFMA_BF16(ql[sl], kh, S[t]);
                S[t] = MFMA_BF16(qh[sl], kl, S[t]);
            }
        }

        // ---- online softmax (rows q = 4*l4 + r, cols across 16-lane group)
#pragma unroll
        for (int r = 0; r < 4; ++r) {
            float pm = fmaxf(fmaxf(S[0][r], S[1][r]), fmaxf(S[2][r], S[3][r]));
#pragma unroll
            for (int off = 1; off < 16; off <<= 1) pm = fmaxf(pm, __shfl_xor(pm, off));
            const float mnew = fmaxf(mrow[r], pm);
            const float corr = __expf(mrow[r] - mnew);
            mrow[r] = mnew;
            float rs = 0.f;
#pragma unroll
            for (int t = 0; t < 4; ++t) {
                float p = __expf(S[t][r] - mnew);
                S[t][r] = p;
                rs += p;
            }
#pragma unroll
            for (int off = 1; off < 16; off <<= 1) rs += __shfl_xor(rs, off);
            lrow[r] = lrow[r] * corr + rs;
#pragma unroll
            for (int dt = 0; dt < 4; ++dt) O[dt][r] *= corr;
        }

        // ---- P -> per-wave LDS (f32, swizzled)
#pragma unroll
        for (int r = 0; r < 4; ++r) {
            const int q  = 4 * l4 + r;
            const int sw = (q & 15) << 2;
#pragma unroll
            for (int t = 0; t < 4; ++t)
                sP[wv][(q * 64 + 16 * t + l16) ^ sw] = S[t][r];
        }
        asm volatile("s_waitcnt lgkmcnt(0)" ::: "memory");
        __builtin_amdgcn_sched_barrier(0);

        // ---- P fragments (hi/lo from f32)
        short8 ph[2], pl[2];
        {
            const int swp = (l16 & 15) << 2;
#pragma unroll
            for (int sl = 0; sl < 2; ++sl) {
                const int e0 = (l16 * 64 + 32 * sl + 8 * l4) ^ swp;
                const int e1 = (l16 * 64 + 32 * sl + 8 * l4 + 4) ^ swp;
                f32x4 pa = *(const f32x4*)&sP[wv][e0];
                f32x4 pb = *(const f32x4*)&sP[wv][e1];
#pragma unroll
                for (int j = 0; j < 4; ++j) {
                    unsigned short h = f2bf(pa[j]);
                    ph[sl][j] = (short)h;
                    pl[sl][j] = (short)f2bf(pa[j] - bf2f(h));
                }
#pragma unroll
                for (int j = 0; j < 4; ++j) {
                    unsigned short h = f2bf(pb[j]);
                    ph[sl][4 + j] = (short)h;
                    pl[sl][4 + j] = (short)f2bf(pb[j] - bf2f(h));
                }
            }
        }

        // ---- O += P V (3-term hi/lo split)
#pragma unroll
        for (int dt = 0; dt < 4; ++dt) {
            const int row = 16 * dt + l16;
            const int sw  = (((row & 7) ^ (row >> 3)) & 7) << 3;
#pragma unroll
            for (int sl = 0; sl < 2; ++sl) {
                const int idx = (row * 64 + 32 * sl + 8 * l4) ^ sw;
                short8 vh = *(const short8*)&sVh[idx];
                short8 vl = *(const short8*)&sVl[idx];
                O[dt] = MFMA_BF16(ph[sl], vh, O[dt]);
                O[dt] = MFMA_BF16(pl[sl], vh, O[dt]);
                O[dt] = MFMA_BF16(ph[sl], vl, O[dt]);
            }
        }
    }

    // ---- epilogue: h = O / l, overwrite q slots of qkv (unique owner)
    const int qrow0 = bb * LL + qt * 64 + wv * 16;
#pragma unroll
    for (int r = 0; r < 4; ++r) {
        const float inv = 1.0f / lrow[r];
        const int q = 4 * l4 + r;
        float* op = qkv + (size_t)(qrow0 + q) * rs_ + hh * DD + l16;
#pragma unroll
        for (int dt = 0; dt < 4; ++dt)
            op[16 * dt] = O[dt][r] * inv;
    }
}

// ---------------------------------------------------------------------------
extern "C" void kernel_launch(void* const* d_in, const int* in_sizes, int n_in,
                              void* d_out, int out_size, void* d_ws, size_t ws_size,
                              hipStream_t stream)
{
    const float* x    = (const float*)d_in[0];
    const float* Wqkv = (const float*)d_in[1];
    const float* bqkv = (const float*)d_in[2];
    const float* gq   = (const float*)d_in[3];
    const float* gk   = (const float*)d_in[4];
    const float* Wout = (const float*)d_in[5];
    const float* bout = (const float*)d_in[6];
    float* out = (float*)d_out;
    float* qkv = (float*)d_ws; // [MM, 3C] fp32 = 96 MB

    gemm_bias<<<dim3((3 * CC) / BN, MM / BM), 256, 0, stream>>>(
        x, Wqkv, bqkv, qkv, MM, 3 * CC, CC, CC, 3 * CC, 3 * CC);

    rmsnorm_qk<<<dim3((MM * HH * 2 * 64) / 256), 256, 0, stream>>>(qkv, gq, gk);

    flash_attn_mfma<<<dim3(LL / 64, HH, BB), 256, 0, stream>>>(qkv);

    gemm_bias<<<dim3(CC / BN, MM / BM), 256, 0, stream>>>(
        qkv, Wout, bout, out, MM, CC, CC, 3 * CC, CC, CC);
}

// Round 3
// 727.167 us; speedup vs baseline: 2.6164x; 1.7911x over previous
//
#include <hip/hip_runtime.h>
#include <math.h>

// Problem constants (B=4, L=2048, C=1024, H=16, D=64)
#define BB 4
#define LL 2048
#define CC 1024
#define HH 16
#define DD 64
#define MM (BB * LL) // 8192 rows

typedef float f32x4 __attribute__((ext_vector_type(4)));
typedef short short8 __attribute__((ext_vector_type(8))); // 8 bf16 (4 VGPRs)
typedef unsigned short ushort_t;

#define MFMA_BF16(A, B, C) __builtin_amdgcn_mfma_f32_16x16x32_bf16(A, B, C, 0, 0, 0)

__device__ __forceinline__ unsigned short f2bf(float x) {
    unsigned int u = __float_as_uint(x);
    u += 0x7fffu + ((u >> 16) & 1u); // RTN-even
    return (unsigned short)(u >> 16);
}
__device__ __forceinline__ float bf2f(unsigned short h) {
    return __uint_as_float(((unsigned int)h) << 16);
}

// ---------------------------------------------------------------------------
// Elementwise f32 -> bf16 hi/lo split (for x).
// ---------------------------------------------------------------------------
__global__ __launch_bounds__(256)
void split_bf16(const float* __restrict__ src, ushort_t* __restrict__ hi,
                ushort_t* __restrict__ lo, int n)
{
    const int i = (blockIdx.x * 256 + threadIdx.x) * 8;
    if (i >= n) return;
    f32x4 a = *(const f32x4*)(src + i);
    f32x4 b = *(const f32x4*)(src + i + 4);
    short8 h, l;
#pragma unroll
    for (int j = 0; j < 4; ++j) {
        unsigned short hh = f2bf(a[j]);
        h[j] = (short)hh; l[j] = (short)f2bf(a[j] - bf2f(hh));
        unsigned short hb = f2bf(b[j]);
        h[4 + j] = (short)hb; l[4 + j] = (short)f2bf(b[j] - bf2f(hb));
    }
    *(short8*)(hi + i) = h;
    *(short8*)(lo + i) = l;
}

// ---------------------------------------------------------------------------
// Transpose + hi/lo split: W[K][N] f32 row-major -> WT[N][K] bf16 hi & lo.
// 64x64 tiles, LDS staging.
// ---------------------------------------------------------------------------
__global__ __launch_bounds__(256)
void transp_split(const float* __restrict__ W, ushort_t* __restrict__ Th,
                  ushort_t* __restrict__ Tl, int K, int N)
{
    __shared__ float sT[64][65];
    const int k0 = blockIdx.y * 64, n0 = blockIdx.x * 64;
    const int tid = threadIdx.x;
    const int r = tid >> 2, c0 = (tid & 3) * 16;

    const float* wp = W + (size_t)(k0 + r) * N + n0 + c0;
#pragma unroll
    for (int u = 0; u < 4; ++u) {
        f32x4 v = *(const f32x4*)(wp + 4 * u);
        sT[r][c0 + 4 * u + 0] = v[0];
        sT[r][c0 + 4 * u + 1] = v[1];
        sT[r][c0 + 4 * u + 2] = v[2];
        sT[r][c0 + 4 * u + 3] = v[3];
    }
    __syncthreads();

    const int nn = tid >> 2, kk0 = (tid & 3) * 16;
    short8 h0, h1, l0, l1;
#pragma unroll
    for (int u = 0; u < 8; ++u) {
        float x = sT[kk0 + u][nn];
        unsigned short hh = f2bf(x);
        h0[u] = (short)hh; l0[u] = (short)f2bf(x - bf2f(hh));
        float y = sT[kk0 + 8 + u][nn];
        unsigned short hy = f2bf(y);
        h1[u] = (short)hy; l1[u] = (short)f2bf(y - bf2f(hy));
    }
    ushort_t* oh = Th + (size_t)(n0 + nn) * K + k0 + kk0;
    ushort_t* ol = Tl + (size_t)(n0 + nn) * K + k0 + kk0;
    *(short8*)oh = h0; *(short8*)(oh + 8) = h1;
    *(short8*)ol = l0; *(short8*)(ol + 8) = l1;
}

// ---------------------------------------------------------------------------
// MFMA GEMM with bf16 hi/lo split (fp32-accurate):
//   C[M][N] = A[M][K] @ B[K][N] + bias
// A: either f32 (AF32=1, stride lda) or pre-split bf16 hi/lo (AF32=0).
// B: pre-transposed bf16 hi/lo, [N][K] row-major.
// 128x128 tile, BK=64, 4 waves (2x2), per-wave 64x64 = 4x4 16x16 fragments.
// LDS tiles [row][chunk^(row&7)] swizzled (chunk = 8 bf16 = 16B).
// ---------------------------------------------------------------------------
template<int AF32>
__global__ __launch_bounds__(256, 2)
void gemm_mfma(const float* __restrict__ Af,
               const ushort_t* __restrict__ Agh, const ushort_t* __restrict__ Agl,
               const ushort_t* __restrict__ Bh, const ushort_t* __restrict__ Bl,
               const float* __restrict__ bias, float* __restrict__ Cg,
               int K, int lda, int ldc, int nbx)
{
    __shared__ ushort_t sAh[128 * 64];
    __shared__ ushort_t sAl[128 * 64];
    __shared__ ushort_t sBh[128 * 64];
    __shared__ ushort_t sBl[128 * 64];

    // XCD-aware bijective swizzle (gridDim.x % 8 == 0 guaranteed by launch)
    const int nwg = gridDim.x;
    const int cpx = nwg >> 3;
    const int id  = blockIdx.x;
    const int sw  = (id & 7) * cpx + (id >> 3);
    const int bx = sw % nbx, by = sw / nbx;
    const int m0 = by * 128, n0 = bx * 128;

    const int tid  = threadIdx.x;
    const int lane = tid & 63;
    const int wv   = tid >> 6;
    const int l4   = lane >> 4, l16 = lane & 15;
    const int wm   = wv >> 1,  wn  = wv & 1;

    const int r0  = tid >> 2;         // 0..63 staging row
    const int c0  = (tid & 3) * 16;   // 0,16,32,48 staging k
    const int ch0 = c0 >> 3;          // 0,2,4,6

    f32x4 acc[4][4];
#pragma unroll
    for (int i = 0; i < 4; ++i)
#pragma unroll
        for (int j = 0; j < 4; ++j) acc[i][j] = 0.f;

    for (int kt = 0; kt < K; kt += 64) {
        __syncthreads();
#pragma unroll
        for (int it = 0; it < 2; ++it) {
            const int row  = r0 + 64 * it;
            const int sA   = row & 7;
            const int base = row * 64;
            const int cA = ((ch0) ^ sA) * 8, cB = ((ch0 + 1) ^ sA) * 8;

            if constexpr (AF32) {
                const float* ap = Af + (size_t)(m0 + row) * lda + kt + c0;
                f32x4 v0 = *(const f32x4*)(ap);
                f32x4 v1 = *(const f32x4*)(ap + 4);
                f32x4 v2 = *(const f32x4*)(ap + 8);
                f32x4 v3 = *(const f32x4*)(ap + 12);
                short8 h0, l0, h1, l1;
#pragma unroll
                for (int j = 0; j < 4; ++j) {
                    unsigned short a0 = f2bf(v0[j]);
                    h0[j] = (short)a0; l0[j] = (short)f2bf(v0[j] - bf2f(a0));
                    unsigned short a1 = f2bf(v1[j]);
                    h0[4+j] = (short)a1; l0[4+j] = (short)f2bf(v1[j] - bf2f(a1));
                    unsigned short a2 = f2bf(v2[j]);
                    h1[j] = (short)a2; l1[j] = (short)f2bf(v2[j] - bf2f(a2));
                    unsigned short a3 = f2bf(v3[j]);
                    h1[4+j] = (short)a3; l1[4+j] = (short)f2bf(v3[j] - bf2f(a3));
                }
                *(short8*)&sAh[base + cA] = h0;
                *(short8*)&sAh[base + cB] = h1;
                *(short8*)&sAl[base + cA] = l0;
                *(short8*)&sAl[base + cB] = l1;
            } else {
                const ushort_t* ahp = Agh + (size_t)(m0 + row) * lda + kt + c0;
                const ushort_t* alp = Agl + (size_t)(m0 + row) * lda + kt + c0;
                *(short8*)&sAh[base + cA] = *(const short8*)(ahp);
                *(short8*)&sAh[base + cB] = *(const short8*)(ahp + 8);
                *(short8*)&sAl[base + cA] = *(const short8*)(alp);
                *(short8*)&sAl[base + cB] = *(const short8*)(alp + 8);
            }
            const ushort_t* bhp = Bh + (size_t)(n0 + row) * K + kt + c0;
            const ushort_t* blp = Bl + (size_t)(n0 + row) * K + kt + c0;
            *(short8*)&sBh[base + cA] = *(const short8*)(bhp);
            *(short8*)&sBh[base + cB] = *(const short8*)(bhp + 8);
            *(short8*)&sBl[base + cA] = *(const short8*)(blp);
            *(short8*)&sBl[base + cB] = *(const short8*)(blp + 8);
        }
        __syncthreads();

#pragma unroll
        for (int ks = 0; ks < 2; ++ks) {
            const int chf = (((ks << 2) | l4) ^ (l16 & 7)) * 8;
            short8 fbh[4], fbl[4];
#pragma unroll
            for (int j = 0; j < 4; ++j) {
                const int idx = (64 * wn + 16 * j + l16) * 64 + chf;
                fbh[j] = *(const short8*)&sBh[idx];
                fbl[j] = *(const short8*)&sBl[idx];
            }
#pragma unroll
            for (int i = 0; i < 4; ++i) {
                const int idx = (64 * wm + 16 * i + l16) * 64 + chf;
                short8 fah = *(const short8*)&sAh[idx];
                short8 fal = *(const short8*)&sAl[idx];
#pragma unroll
                for (int j = 0; j < 4; ++j) {
                    acc[i][j] = MFMA_BF16(fah, fbh[j], acc[i][j]);
                    acc[i][j] = MFMA_BF16(fal, fbh[j], acc[i][j]);
                    acc[i][j] = MFMA_BF16(fah, fbl[j], acc[i][j]);
                }
            }
        }
    }

    float bv[4];
#pragma unroll
    for (int j = 0; j < 4; ++j) bv[j] = bias[n0 + 64 * wn + 16 * j + l16];
#pragma unroll
    for (int i = 0; i < 4; ++i)
#pragma unroll
    for (int r = 0; r < 4; ++r) {
        const int row = m0 + 64 * wm + 16 * i + 4 * l4 + r;
        float* cp = Cg + (size_t)row * ldc + n0 + 64 * wn + l16;
#pragma unroll
        for (int j = 0; j < 4; ++j) cp[16 * j] = acc[i][j][r] + bv[j];
    }
}

// ---------------------------------------------------------------------------
// Fallback fp32 GEMM (only used if ws_size is too small)
// ---------------------------------------------------------------------------
#define BM 128
#define BN 128
#define BKG 8

__global__ __launch_bounds__(256)
void gemm_bias(const float* __restrict__ A, const float* __restrict__ B,
               const float* __restrict__ bias, float* __restrict__ C,
               int M, int N, int K, int lda, int ldb, int ldc)
{
    __shared__ float As[BKG][BM];
    __shared__ float Bs[BKG][BN];

    const int tid = threadIdx.x;
    const int m0 = blockIdx.y * BM;
    const int n0 = blockIdx.x * BN;
    const int ty = tid >> 4, tx = tid & 15;
    const int arow = tid >> 1, acol = (tid & 1) * 4;
    const int brow = tid >> 5, bcol = (tid & 31) * 4;

    const float* Ap = A + (size_t)(m0 + arow) * lda + acol;
    const float* Bp = B + (size_t)brow * ldb + n0 + bcol;

    float acc[8][8];
#pragma unroll
    for (int i = 0; i < 8; ++i)
#pragma unroll
        for (int j = 0; j < 8; ++j) acc[i][j] = 0.f;

    for (int k0 = 0; k0 < K; k0 += BKG) {
        float4 av = *(const float4*)(Ap + k0);
        float4 bv = *(const float4*)(Bp + (size_t)k0 * ldb);
        __syncthreads();
        As[acol + 0][arow] = av.x;
        As[acol + 1][arow] = av.y;
        As[acol + 2][arow] = av.z;
        As[acol + 3][arow] = av.w;
        *(float4*)&Bs[brow][bcol] = bv;
        __syncthreads();
#pragma unroll
        for (int kk = 0; kk < BKG; ++kk) {
            float a[8], b[8];
            *(float4*)&a[0] = *(const float4*)&As[kk][ty * 4];
            *(float4*)&a[4] = *(const float4*)&As[kk][64 + ty * 4];
            *(float4*)&b[0] = *(const float4*)&Bs[kk][tx * 4];
            *(float4*)&b[4] = *(const float4*)&Bs[kk][64 + tx * 4];
#pragma unroll
            for (int i = 0; i < 8; ++i)
#pragma unroll
                for (int j = 0; j < 8; ++j)
                    acc[i][j] = fmaf(a[i], b[j], acc[i][j]);
        }
    }
#pragma unroll
    for (int ih = 0; ih < 2; ++ih)
#pragma unroll
    for (int i = 0; i < 4; ++i) {
        const int m = m0 + ih * 64 + ty * 4 + i;
#pragma unroll
        for (int jh = 0; jh < 2; ++jh) {
            const int n = n0 + jh * 64 + tx * 4;
            float4 o;
            o.x = acc[ih*4+i][jh*4+0] + bias[n+0];
            o.y = acc[ih*4+i][jh*4+1] + bias[n+1];
            o.z = acc[ih*4+i][jh*4+2] + bias[n+2];
            o.w = acc[ih*4+i][jh*4+3] + bias[n+3];
            *(float4*)(C + (size_t)m * ldc + n) = o;
        }
    }
}

// ---------------------------------------------------------------------------
// Per-head RMS norm of q and k
// ---------------------------------------------------------------------------
__global__ __launch_bounds__(256)
void rmsnorm_qk(float* __restrict__ qkv,
                const float* __restrict__ gq, const float* __restrict__ gk)
{
    const int gt    = blockIdx.x * 256 + threadIdx.x;
    const int lane  = gt & 63;
    const int wave  = gt >> 6;
    const int which = wave & 1;
    const int h     = (wave >> 1) & (HH - 1);
    const int bl    = wave >> 5;

    float* p = qkv + (size_t)bl * (3 * CC) + which * CC + h * DD + lane;
    float v = *p;
    float ss = v * v;
#pragma unroll
    for (int off = 32; off; off >>= 1) ss += __shfl_xor(ss, off);
    float nrm = fmaxf(sqrtf(ss), 1e-12f);
    const float* g = which ? gk : gq;
    *p = v * (8.0f / nrm) * g[h * DD + lane];
}

// ---------------------------------------------------------------------------
// Flash attention, bf16 MFMA with hi/lo split (unchanged from round 2)
// ---------------------------------------------------------------------------
__global__ __launch_bounds__(256)
void flash_attn_mfma(float* __restrict__ qkv)
{
    __shared__ unsigned short sKh[64 * 64];
    __shared__ unsigned short sKl[64 * 64];
    __shared__ unsigned short sVh[64 * 64];
    __shared__ unsigned short sVl[64 * 64];
    __shared__ float sP[4][16 * 64];

    const int tid  = threadIdx.x;
    const int lane = tid & 63;
    const int wv   = tid >> 6;
    const int l4   = lane >> 4;
    const int l16  = lane & 15;

    const int qt = blockIdx.x, hh = blockIdx.y, bb = blockIdx.z;
    const size_t rs_ = 3 * CC;

    short8 qh[2], ql[2];
    {
        const int qrow = bb * LL + qt * 64 + wv * 16 + l16;
        const float* qp = qkv + (size_t)qrow * rs_ + hh * DD + 8 * l4;
#pragma unroll
        for (int sl = 0; sl < 2; ++sl) {
            f32x4 a = *(const f32x4*)(qp + 32 * sl);
            f32x4 b = *(const f32x4*)(qp + 32 * sl + 4);
#pragma unroll
            for (int j = 0; j < 4; ++j) {
                float x = a[j] * 0.125f;
                unsigned short h = f2bf(x);
                qh[sl][j] = (short)h;
                ql[sl][j] = (short)f2bf(x - bf2f(h));
            }
#pragma unroll
            for (int j = 0; j < 4; ++j) {
                float x = b[j] * 0.125f;
                unsigned short h = f2bf(x);
                qh[sl][4 + j] = (short)h;
                ql[sl][4 + j] = (short)f2bf(x - bf2f(h));
            }
        }
    }

    f32x4 O[4];
    float mrow[4], lrow[4];
#pragma unroll
    for (int i = 0; i < 4; ++i) { O[i] = 0.f; mrow[i] = -INFINITY; lrow[i] = 0.f; }

    const int r_ = tid >> 2;
    const int c_ = (tid & 3) * 16;

    for (int kt = 0; kt < LL / 64; ++kt) {
        __syncthreads();
        {
            const float* kg = qkv + (size_t)(bb * LL + kt * 64 + r_) * rs_ + CC + hh * DD + c_;
            const float* vg = kg + CC;
            f32x4 kv[4], vv[4];
#pragma unroll
            for (int u = 0; u < 4; ++u) {
                kv[u] = *(const f32x4*)(kg + 4 * u);
                vv[u] = *(const f32x4*)(vg + 4 * u);
            }
            short8 ha, hb, la, lb;
#pragma unroll
            for (int j = 0; j < 8; ++j) {
                float x0 = kv[j >> 2][j & 3];
                unsigned short h0 = f2bf(x0);
                ha[j] = (short)h0; la[j] = (short)f2bf(x0 - bf2f(h0));
                float x1 = kv[2 + (j >> 2)][j & 3];
                unsigned short h1 = f2bf(x1);
                hb[j] = (short)h1; lb[j] = (short)f2bf(x1 - bf2f(h1));
            }
            const int kbase = r_ * 64 + c_;
            const int ksw   = (r_ & 7) << 3;
            *(short8*)&sKh[(kbase) ^ ksw]     = ha;
            *(short8*)&sKh[(kbase + 8) ^ ksw] = hb;
            *(short8*)&sKl[(kbase) ^ ksw]     = la;
            *(short8*)&sKl[(kbase + 8) ^ ksw] = lb;
#pragma unroll
            for (int u = 0; u < 16; ++u) {
                const int d = c_ + u;
                const int idx = (d * 64 + r_) ^ ((((d & 7) ^ (d >> 3)) & 7) << 3);
                float x = vv[u >> 2][u & 3];
                unsigned short h = f2bf(x);
                sVh[idx] = h;
                sVl[idx] = f2bf(x - bf2f(h));
            }
        }
        __syncthreads();

        f32x4 S[4];
#pragma unroll
        for (int t = 0; t < 4; ++t) S[t] = 0.f;
#pragma unroll
        for (int t = 0; t < 4; ++t) {
            const int row = 16 * t + l16;
            const int sw  = (row & 7) << 3;
#pragma unroll
            for (int sl = 0; sl < 2; ++sl) {
                const int idx = (row * 64 + 32 * sl + 8 * l4) ^ sw;
                short8 kh = *(const short8*)&sKh[idx];
                short8 kl = *(const short8*)&sKl[idx];
                S[t] = MFMA_BF16(qh[sl], kh, S[t]);
                S[t] = MFMA_BF16(ql[sl], kh, S[t]);
                S[t] = MFMA_BF16(qh[sl], kl, S[t]);
            }
        }

#pragma unroll
        for (int r = 0; r < 4; ++r) {
            float pm = fmaxf(fmaxf(S[0][r], S[1][r]), fmaxf(S[2][r], S[3][r]));
#pragma unroll
            for (int off = 1; off < 16; off <<= 1) pm = fmaxf(pm, __shfl_xor(pm, off));
            const float mnew = fmaxf(mrow[r], pm);
            const float corr = __expf(mrow[r] - mnew);
            mrow[r] = mnew;
            float rs = 0.f;
#pragma unroll
            for (int t = 0; t < 4; ++t) {
                float p = __expf(S[t][r] - mnew);
                S[t][r] = p;
                rs += p;
            }
#pragma unroll
            for (int off = 1; off < 16; off <<= 1) rs += __shfl_xor(rs, off);
            lrow[r] = lrow[r] * corr + rs;
#pragma unroll
            for (int dt = 0; dt < 4; ++dt) O[dt][r] *= corr;
        }

#pragma unroll
        for (int r = 0; r < 4; ++r) {
            const int q  = 4 * l4 + r;
            const int sw = (q & 15) << 2;
#pragma unroll
            for (int t = 0; t < 4; ++t)
                sP[wv][(q * 64 + 16 * t + l16) ^ sw] = S[t][r];
        }
        asm volatile("s_waitcnt lgkmcnt(0)" ::: "memory");
        __builtin_amdgcn_sched_barrier(0);

        short8 ph[2], pl[2];
        {
            const int swp = (l16 & 15) << 2;
#pragma unroll
            for (int sl = 0; sl < 2; ++sl) {
                const int e0 = (l16 * 64 + 32 * sl + 8 * l4) ^ swp;
                const int e1 = (l16 * 64 + 32 * sl + 8 * l4 + 4) ^ swp;
                f32x4 pa = *(const f32x4*)&sP[wv][e0];
                f32x4 pb = *(const f32x4*)&sP[wv][e1];
#pragma unroll
                for (int j = 0; j < 4; ++j) {
                    unsigned short h = f2bf(pa[j]);
                    ph[sl][j] = (short)h;
                    pl[sl][j] = (short)f2bf(pa[j] - bf2f(h));
                }
#pragma unroll
                for (int j = 0; j < 4; ++j) {
                    unsigned short h = f2bf(pb[j]);
                    ph[sl][4 + j] = (short)h;
                    pl[sl][4 + j] = (short)f2bf(pb[j] - bf2f(h));
                }
            }
        }

#pragma unroll
        for (int dt = 0; dt < 4; ++dt) {
            const int row = 16 * dt + l16;
            const int sw  = (((row & 7) ^ (row >> 3)) & 7) << 3;
#pragma unroll
            for (int sl = 0; sl < 2; ++sl) {
                const int idx = (row * 64 + 32 * sl + 8 * l4) ^ sw;
                short8 vh = *(const short8*)&sVh[idx];
                short8 vl = *(const short8*)&sVl[idx];
                O[dt] = MFMA_BF16(ph[sl], vh, O[dt]);
                O[dt] = MFMA_BF16(pl[sl], vh, O[dt]);
                O[dt] = MFMA_BF16(ph[sl], vl, O[dt]);
            }
        }
    }

    const int qrow0 = bb * LL + qt * 64 + wv * 16;
#pragma unroll
    for (int r = 0; r < 4; ++r) {
        const float inv = 1.0f / lrow[r];
        const int q = 4 * l4 + r;
        float* op = qkv + (size_t)(qrow0 + q) * rs_ + hh * DD + l16;
#pragma unroll
        for (int dt = 0; dt < 4; ++dt)
            op[16 * dt] = O[dt][r] * inv;
    }
}

// ---------------------------------------------------------------------------
extern "C" void kernel_launch(void* const* d_in, const int* in_sizes, int n_in,
                              void* d_out, int out_size, void* d_ws, size_t ws_size,
                              hipStream_t stream)
{
    const float* x    = (const float*)d_in[0];
    const float* Wqkv = (const float*)d_in[1];
    const float* bqkv = (const float*)d_in[2];
    const float* gq   = (const float*)d_in[3];
    const float* gk   = (const float*)d_in[4];
    const float* Wout = (const float*)d_in[5];
    const float* bout = (const float*)d_in[6];
    float* out = (float*)d_out;

    float* qkv = (float*)d_ws; // [MM][3C] f32 = 96 MB

    const size_t QKV_E = (size_t)MM * 3 * CC;        // 25165824 f32
    const size_t XE    = (size_t)MM * CC;            // 8388608
    const size_t WQE   = (size_t)3 * CC * CC;        // 3145728
    const size_t WOE   = (size_t)CC * CC;            // 1048576

    const size_t TIER1 = 150994944ull; // qkv + x hi/lo + WqkvT hi/lo + WoutT hi/lo
    const size_t TIER2 = 117440512ull; // qkv + WqkvT hi/lo + WoutT hi/lo

    if (ws_size >= TIER2) {
        ushort_t* base = (ushort_t*)(qkv + QKV_E);
        ushort_t *xh = nullptr, *xl = nullptr, *wqh, *wql, *woh, *wol;
        const bool havex = (ws_size >= TIER1);
        if (havex) {
            xh = base;            xl = xh + XE;
            wqh = xl + XE;        wql = wqh + WQE;
            woh = wql + WQE;      wol = woh + WOE;
        } else {
            wqh = base;           wql = wqh + WQE;
            woh = wql + WQE;      wol = woh + WOE;
        }

        if (havex)
            split_bf16<<<dim3((int)(XE / 8 / 256)), 256, 0, stream>>>(x, xh, xl, (int)XE);
        transp_split<<<dim3(3 * CC / 64, CC / 64), 256, 0, stream>>>(Wqkv, wqh, wql, CC, 3 * CC);
        transp_split<<<dim3(CC / 64, CC / 64), 256, 0, stream>>>(Wout, woh, wol, CC, CC);

        // QKV projection: [8192 x 3072] = x @ Wqkv + bqkv
        if (havex)
            gemm_mfma<0><<<dim3((3 * CC / 128) * (MM / 128)), 256, 0, stream>>>(
                nullptr, xh, xl, wqh, wql, bqkv, qkv, CC, CC, 3 * CC, 3 * CC / 128);
        else
            gemm_mfma<1><<<dim3((3 * CC / 128) * (MM / 128)), 256, 0, stream>>>(
                x, nullptr, nullptr, wqh, wql, bqkv, qkv, CC, CC, 3 * CC, 3 * CC / 128);

        rmsnorm_qk<<<dim3((MM * HH * 2 * 64) / 256), 256, 0, stream>>>(qkv, gq, gk);
        flash_attn_mfma<<<dim3(LL / 64, HH, BB), 256, 0, stream>>>(qkv);

        // Output projection: A = h (q slots of qkv, f32, lda = 3C)
        gemm_mfma<1><<<dim3((CC / 128) * (MM / 128)), 256, 0, stream>>>(
            qkv, nullptr, nullptr, woh, wol, bout, out, CC, 3 * CC, CC, CC / 128);
    } else {
        // conservative fallback (fp32 vector GEMMs)
        gemm_bias<<<dim3((3 * CC) / BN, MM / BM), 256, 0, stream>>>(
            x, Wqkv, bqkv, qkv, MM, 3 * CC, CC, CC, 3 * CC, 3 * CC);
        rmsnorm_qk<<<dim3((MM * HH * 2 * 64) / 256), 256, 0, stream>>>(qkv, gq, gk);
        flash_attn_mfma<<<dim3(LL / 64, HH, BB), 256, 0, stream>>>(qkv);
        gemm_bias<<<dim3(CC / BN, MM / BM), 256, 0, stream>>>(
            qkv, Wout, bout, out, MM, CC, CC, 3 * CC, CC, CC);
    }
}

// Round 4
// 676.175 us; speedup vs baseline: 2.8137x; 1.0754x over previous
//
#include <hip/hip_runtime.h>
#include <math.h>

// Problem constants (B=4, L=2048, C=1024, H=16, D=64)
#define BB 4
#define LL 2048
#define CC 1024
#define HH 16
#define DD 64
#define MM (BB * LL) // 8192 rows

typedef float f32x4 __attribute__((ext_vector_type(4)));
typedef short short8 __attribute__((ext_vector_type(8))); // 8 bf16 (4 VGPRs)
typedef unsigned short ushort_t;

#define MFMA_BF16(A, B, C) __builtin_amdgcn_mfma_f32_16x16x32_bf16(A, B, C, 0, 0, 0)

__device__ __forceinline__ unsigned short f2bf(float x) {
    unsigned int u = __float_as_uint(x);
    u += 0x7fffu + ((u >> 16) & 1u); // RTN-even
    return (unsigned short)(u >> 16);
}
__device__ __forceinline__ float bf2f(unsigned short h) {
    return __uint_as_float(((unsigned int)h) << 16);
}
__device__ __forceinline__ void split8(const f32x4& a, const f32x4& b,
                                       short8& h, short8& l) {
#pragma unroll
    for (int j = 0; j < 4; ++j) {
        unsigned short ha = f2bf(a[j]);
        h[j] = (short)ha; l[j] = (short)f2bf(a[j] - bf2f(ha));
        unsigned short hb = f2bf(b[j]);
        h[4 + j] = (short)hb; l[4 + j] = (short)f2bf(b[j] - bf2f(hb));
    }
}

// ---------------------------------------------------------------------------
// Elementwise f32 -> bf16 hi/lo split (for x).
// ---------------------------------------------------------------------------
__global__ __launch_bounds__(256)
void split_bf16(const float* __restrict__ src, ushort_t* __restrict__ hi,
                ushort_t* __restrict__ lo, int n)
{
    const int i = (blockIdx.x * 256 + threadIdx.x) * 8;
    if (i >= n) return;
    f32x4 a = *(const f32x4*)(src + i);
    f32x4 b = *(const f32x4*)(src + i + 4);
    short8 h, l;
    split8(a, b, h, l);
    *(short8*)(hi + i) = h;
    *(short8*)(lo + i) = l;
}

// ---------------------------------------------------------------------------
// Transpose + hi/lo split: W[K][N] f32 row-major -> WT[N][K] bf16 hi & lo.
// ---------------------------------------------------------------------------
__global__ __launch_bounds__(256)
void transp_split(const float* __restrict__ W, ushort_t* __restrict__ Th,
                  ushort_t* __restrict__ Tl, int K, int N)
{
    __shared__ float sT[64][65];
    const int k0 = blockIdx.y * 64, n0 = blockIdx.x * 64;
    const int tid = threadIdx.x;
    const int r = tid >> 2, c0 = (tid & 3) * 16;

    const float* wp = W + (size_t)(k0 + r) * N + n0 + c0;
#pragma unroll
    for (int u = 0; u < 4; ++u) {
        f32x4 v = *(const f32x4*)(wp + 4 * u);
        sT[r][c0 + 4 * u + 0] = v[0];
        sT[r][c0 + 4 * u + 1] = v[1];
        sT[r][c0 + 4 * u + 2] = v[2];
        sT[r][c0 + 4 * u + 3] = v[3];
    }
    __syncthreads();

    const int nn = tid >> 2, kk0 = (tid & 3) * 16;
    short8 h0, h1, l0, l1;
#pragma unroll
    for (int u = 0; u < 8; ++u) {
        float x = sT[kk0 + u][nn];
        unsigned short hh = f2bf(x);
        h0[u] = (short)hh; l0[u] = (short)f2bf(x - bf2f(hh));
        float y = sT[kk0 + 8 + u][nn];
        unsigned short hy = f2bf(y);
        h1[u] = (short)hy; l1[u] = (short)f2bf(y - bf2f(hy));
    }
    ushort_t* oh = Th + (size_t)(n0 + nn) * K + k0 + kk0;
    ushort_t* ol = Tl + (size_t)(n0 + nn) * K + k0 + kk0;
    *(short8*)oh = h0; *(short8*)(oh + 8) = h1;
    *(short8*)ol = l0; *(short8*)(ol + 8) = l1;
}

// ---------------------------------------------------------------------------
// Fused QKV GEMM: qkv = x @ Wqkv + bqkv, with epilogue per column region:
//   q cols: rmsnorm(gq) -> f32 Qbuf[M][C]
//   k cols: rmsnorm(gk) -> bf16 hi/lo Kh/Kl [b][h][l][d]
//   v cols: bf16 hi/lo, LDS-transposed -> Vth/Vtl [b][h][d][l]
// 128x128 tile, BK=64, 4 waves (2x2), LDS chunk-swizzled.
// ---------------------------------------------------------------------------
template<int AF32>
__global__ __launch_bounds__(256, 2)
void gemm_qkv(const float* __restrict__ Af,
              const ushort_t* __restrict__ Agh, const ushort_t* __restrict__ Agl,
              const ushort_t* __restrict__ Bh, const ushort_t* __restrict__ Bl,
              const float* __restrict__ bias,
              const float* __restrict__ gq, const float* __restrict__ gk,
              float* __restrict__ Qb,
              ushort_t* __restrict__ Kh, ushort_t* __restrict__ Kl,
              ushort_t* __restrict__ Vth, ushort_t* __restrict__ Vtl)
{
    __shared__ ushort_t smem[32768]; // 64 KB
    ushort_t* sAh = smem;
    ushort_t* sAl = smem + 8192;
    ushort_t* sBh = smem + 16384;
    ushort_t* sBl = smem + 24576;

    const int K = CC, lda = CC, nbx = (3 * CC) / 128; // 24

    const int nwg = gridDim.x;
    const int cpx = nwg >> 3;
    const int id  = blockIdx.x;
    const int swz = (id & 7) * cpx + (id >> 3);
    const int bx = swz % nbx, by = swz / nbx;
    const int m0 = by * 128, n0 = bx * 128;

    const int tid  = threadIdx.x;
    const int lane = tid & 63;
    const int wv   = tid >> 6;
    const int l4   = lane >> 4, l16 = lane & 15;
    const int wm   = wv >> 1,  wn  = wv & 1;

    const int r0  = tid >> 2;
    const int c0  = (tid & 3) * 16;
    const int ch0 = c0 >> 3;

    f32x4 acc[4][4];
#pragma unroll
    for (int i = 0; i < 4; ++i)
#pragma unroll
        for (int j = 0; j < 4; ++j) acc[i][j] = 0.f;

    for (int kt = 0; kt < K; kt += 64) {
        __syncthreads();
#pragma unroll
        for (int it = 0; it < 2; ++it) {
            const int row  = r0 + 64 * it;
            const int sA   = row & 7;
            const int base = row * 64;
            const int cA = ((ch0) ^ sA) * 8, cB = ((ch0 + 1) ^ sA) * 8;

            if constexpr (AF32) {
                const float* ap = Af + (size_t)(m0 + row) * lda + kt + c0;
                f32x4 v0 = *(const f32x4*)(ap);
                f32x4 v1 = *(const f32x4*)(ap + 4);
                f32x4 v2 = *(const f32x4*)(ap + 8);
                f32x4 v3 = *(const f32x4*)(ap + 12);
                short8 h0, l0, h1, l1;
                split8(v0, v1, h0, l0);
                split8(v2, v3, h1, l1);
                *(short8*)&sAh[base + cA] = h0;
                *(short8*)&sAh[base + cB] = h1;
                *(short8*)&sAl[base + cA] = l0;
                *(short8*)&sAl[base + cB] = l1;
            } else {
                const ushort_t* ahp = Agh + (size_t)(m0 + row) * lda + kt + c0;
                const ushort_t* alp = Agl + (size_t)(m0 + row) * lda + kt + c0;
                *(short8*)&sAh[base + cA] = *(const short8*)(ahp);
                *(short8*)&sAh[base + cB] = *(const short8*)(ahp + 8);
                *(short8*)&sAl[base + cA] = *(const short8*)(alp);
                *(short8*)&sAl[base + cB] = *(const short8*)(alp + 8);
            }
            const ushort_t* bhp = Bh + (size_t)(n0 + row) * K + kt + c0;
            const ushort_t* blp = Bl + (size_t)(n0 + row) * K + kt + c0;
            *(short8*)&sBh[base + cA] = *(const short8*)(bhp);
            *(short8*)&sBh[base + cB] = *(const short8*)(bhp + 8);
            *(short8*)&sBl[base + cA] = *(const short8*)(blp);
            *(short8*)&sBl[base + cB] = *(const short8*)(blp + 8);
        }
        __syncthreads();

#pragma unroll
        for (int ks = 0; ks < 2; ++ks) {
            const int chf = (((ks << 2) | l4) ^ (l16 & 7)) * 8;
            short8 fbh[4], fbl[4];
#pragma unroll
            for (int j = 0; j < 4; ++j) {
                const int idx = (64 * wn + 16 * j + l16) * 64 + chf;
                fbh[j] = *(const short8*)&sBh[idx];
                fbl[j] = *(const short8*)&sBl[idx];
            }
#pragma unroll
            for (int i = 0; i < 4; ++i) {
                const int idx = (64 * wm + 16 * i + l16) * 64 + chf;
                short8 fah = *(const short8*)&sAh[idx];
                short8 fal = *(const short8*)&sAl[idx];
#pragma unroll
                for (int j = 0; j < 4; ++j) {
                    acc[i][j] = MFMA_BF16(fah, fbh[j], acc[i][j]);
                    acc[i][j] = MFMA_BF16(fal, fbh[j], acc[i][j]);
                    acc[i][j] = MFMA_BF16(fah, fbl[j], acc[i][j]);
                }
            }
        }
    }

    // ---- epilogue -------------------------------------------------------
    const int region = n0 >> 10; // 0=q, 1=k, 2=v (128 | 1024 boundaries)
    float bv[4];
#pragma unroll
    for (int j = 0; j < 4; ++j) bv[j] = bias[n0 + 64 * wn + 16 * j + l16];
#pragma unroll
    for (int i = 0; i < 4; ++i)
#pragma unroll
        for (int j = 0; j < 4; ++j)
#pragma unroll
            for (int r = 0; r < 4; ++r) acc[i][j][r] += bv[j];

    const int b = m0 >> 11;

    if (region < 2) {
        const int hloc = ((n0 & 1023) >> 6) + wn;
        const float* g = (region == 0 ? gq : gk) + hloc * DD;
        float gv[4];
#pragma unroll
        for (int j = 0; j < 4; ++j) gv[j] = g[16 * j + l16];
#pragma unroll
        for (int i = 0; i < 4; ++i)
#pragma unroll
        for (int r = 0; r < 4; ++r) {
            float ss = 0.f;
#pragma unroll
            for (int j = 0; j < 4; ++j) ss += acc[i][j][r] * acc[i][j][r];
#pragma unroll
            for (int off = 1; off < 16; off <<= 1) ss += __shfl_xor(ss, off);
            const float s = 8.0f / fmaxf(sqrtf(ss), 1e-12f);
#pragma unroll
            for (int j = 0; j < 4; ++j) acc[i][j][r] *= s * gv[j];
        }

        if (region == 0) {
#pragma unroll
            for (int i = 0; i < 4; ++i)
#pragma unroll
            for (int r = 0; r < 4; ++r) {
                const int row = m0 + 64 * wm + 16 * i + 4 * l4 + r;
                float* op = Qb + (size_t)row * CC + n0 + 64 * wn + l16;
#pragma unroll
                for (int j = 0; j < 4; ++j) op[16 * j] = acc[i][j][r];
            }
        } else {
            const int hk = ((n0 - 1024) >> 6) + wn;
#pragma unroll
            for (int i = 0; i < 4; ++i)
#pragma unroll
            for (int r = 0; r < 4; ++r) {
                const int l = (m0 & 2047) + 64 * wm + 16 * i + 4 * l4 + r;
                const size_t base = ((size_t)(b * HH + hk) * LL + l) * DD + l16;
#pragma unroll
                for (int j = 0; j < 4; ++j) {
                    float v = acc[i][j][r];
                    unsigned short hh = f2bf(v);
                    Kh[base + 16 * j] = hh;
                    Kl[base + 16 * j] = f2bf(v - bf2f(hh));
                }
            }
        }
    } else {
        // V: split + 128x128 LDS transpose + vector store to [b][h][d][l]
        __syncthreads(); // all waves done with GEMM tiles
        ushort_t* vh = smem;          // [128][128]
        ushort_t* vl = smem + 16384;
#pragma unroll
        for (int i = 0; i < 4; ++i)
#pragma unroll
        for (int r = 0; r < 4; ++r) {
            const int lr = 64 * wm + 16 * i + 4 * l4 + r;
#pragma unroll
            for (int j = 0; j < 4; ++j) {
                const int c = 64 * wn + 16 * j + l16;
                float v = acc[i][j][r];
                unsigned short hh = f2bf(v);
                vh[lr * 128 + c] = hh;
                vl[lr * 128 + c] = f2bf(v - bf2f(hh));
            }
        }
        __syncthreads();
        const int c    = tid & 127;
        const int half = tid >> 7;
        const int hv   = ((n0 - 2048) >> 6) + (c >> 6);
        const int d    = c & 63;
        ushort_t* oh = Vth + ((size_t)(b * HH + hv) * DD + d) * LL + (m0 & 2047) + half * 64;
        ushort_t* ol = Vtl + ((size_t)(b * HH + hv) * DD + d) * LL + (m0 & 2047) + half * 64;
#pragma unroll
        for (int u = 0; u < 8; ++u) {
            const int l0 = half * 64 + u * 8;
            short8 hv8, lv8;
#pragma unroll
            for (int e = 0; e < 8; ++e) {
                hv8[e] = (short)vh[(l0 + e) * 128 + c];
                lv8[e] = (short)vl[(l0 + e) * 128 + c];
            }
            *(short8*)&oh[u * 8] = hv8;
            *(short8*)&ol[u * 8] = lv8;
        }
    }
}

// ---------------------------------------------------------------------------
// MFMA GEMM (plain bias epilogue) — used for the output projection.
// ---------------------------------------------------------------------------
template<int AF32>
__global__ __launch_bounds__(256, 2)
void gemm_mfma(const float* __restrict__ Af,
               const ushort_t* __restrict__ Agh, const ushort_t* __restrict__ Agl,
               const ushort_t* __restrict__ Bh, const ushort_t* __restrict__ Bl,
               const float* __restrict__ bias, float* __restrict__ Cg,
               int K, int lda, int ldc, int nbx)
{
    __shared__ ushort_t sAh[128 * 64];
    __shared__ ushort_t sAl[128 * 64];
    __shared__ ushort_t sBh[128 * 64];
    __shared__ ushort_t sBl[128 * 64];

    const int nwg = gridDim.x;
    const int cpx = nwg >> 3;
    const int id  = blockIdx.x;
    const int sw  = (id & 7) * cpx + (id >> 3);
    const int bx = sw % nbx, by = sw / nbx;
    const int m0 = by * 128, n0 = bx * 128;

    const int tid  = threadIdx.x;
    const int lane = tid & 63;
    const int wv   = tid >> 6;
    const int l4   = lane >> 4, l16 = lane & 15;
    const int wm   = wv >> 1,  wn  = wv & 1;

    const int r0  = tid >> 2;
    const int c0  = (tid & 3) * 16;
    const int ch0 = c0 >> 3;

    f32x4 acc[4][4];
#pragma unroll
    for (int i = 0; i < 4; ++i)
#pragma unroll
        for (int j = 0; j < 4; ++j) acc[i][j] = 0.f;

    for (int kt = 0; kt < K; kt += 64) {
        __syncthreads();
#pragma unroll
        for (int it = 0; it < 2; ++it) {
            const int row  = r0 + 64 * it;
            const int sA   = row & 7;
            const int base = row * 64;
            const int cA = ((ch0) ^ sA) * 8, cB = ((ch0 + 1) ^ sA) * 8;

            if constexpr (AF32) {
                const float* ap = Af + (size_t)(m0 + row) * lda + kt + c0;
                f32x4 v0 = *(const f32x4*)(ap);
                f32x4 v1 = *(const f32x4*)(ap + 4);
                f32x4 v2 = *(const f32x4*)(ap + 8);
                f32x4 v3 = *(const f32x4*)(ap + 12);
                short8 h0, l0, h1, l1;
                split8(v0, v1, h0, l0);
                split8(v2, v3, h1, l1);
                *(short8*)&sAh[base + cA] = h0;
                *(short8*)&sAh[base + cB] = h1;
                *(short8*)&sAl[base + cA] = l0;
                *(short8*)&sAl[base + cB] = l1;
            } else {
                const ushort_t* ahp = Agh + (size_t)(m0 + row) * lda + kt + c0;
                const ushort_t* alp = Agl + (size_t)(m0 + row) * lda + kt + c0;
                *(short8*)&sAh[base + cA] = *(const short8*)(ahp);
                *(short8*)&sAh[base + cB] = *(const short8*)(ahp + 8);
                *(short8*)&sAl[base + cA] = *(const short8*)(alp);
                *(short8*)&sAl[base + cB] = *(const short8*)(alp + 8);
            }
            const ushort_t* bhp = Bh + (size_t)(n0 + row) * K + kt + c0;
            const ushort_t* blp = Bl + (size_t)(n0 + row) * K + kt + c0;
            *(short8*)&sBh[base + cA] = *(const short8*)(bhp);
            *(short8*)&sBh[base + cB] = *(const short8*)(bhp + 8);
            *(short8*)&sBl[base + cA] = *(const short8*)(blp);
            *(short8*)&sBl[base + cB] = *(const short8*)(blp + 8);
        }
        __syncthreads();

#pragma unroll
        for (int ks = 0; ks < 2; ++ks) {
            const int chf = (((ks << 2) | l4) ^ (l16 & 7)) * 8;
            short8 fbh[4], fbl[4];
#pragma unroll
            for (int j = 0; j < 4; ++j) {
                const int idx = (64 * wn + 16 * j + l16) * 64 + chf;
                fbh[j] = *(const short8*)&sBh[idx];
                fbl[j] = *(const short8*)&sBl[idx];
            }
#pragma unroll
            for (int i = 0; i < 4; ++i) {
                const int idx = (64 * wm + 16 * i + l16) * 64 + chf;
                short8 fah = *(const short8*)&sAh[idx];
                short8 fal = *(const short8*)&sAl[idx];
#pragma unroll
                for (int j = 0; j < 4; ++j) {
                    acc[i][j] = MFMA_BF16(fah, fbh[j], acc[i][j]);
                    acc[i][j] = MFMA_BF16(fal, fbh[j], acc[i][j]);
                    acc[i][j] = MFMA_BF16(fah, fbl[j], acc[i][j]);
                }
            }
        }
    }

    float bv[4];
#pragma unroll
    for (int j = 0; j < 4; ++j) bv[j] = bias[n0 + 64 * wn + 16 * j + l16];
#pragma unroll
    for (int i = 0; i < 4; ++i)
#pragma unroll
    for (int r = 0; r < 4; ++r) {
        const int row = m0 + 64 * wm + 16 * i + 4 * l4 + r;
        float* cp = Cg + (size_t)row * ldc + n0 + 64 * wn + l16;
#pragma unroll
        for (int j = 0; j < 4; ++j) cp[16 * j] = acc[i][j][r] + bv[j];
    }
}

// ---------------------------------------------------------------------------
// Flash attention v2: pre-split bf16 K/V from global, 4 waves x 32 q-rows,
// BQ=128, KV tile 64. h overwrites Qbuf rows.
// ---------------------------------------------------------------------------
__global__ __launch_bounds__(256)
void flash2(float* __restrict__ Qb,
            const ushort_t* __restrict__ Kh, const ushort_t* __restrict__ Kl,
            const ushort_t* __restrict__ Vth, const ushort_t* __restrict__ Vtl)
{
    __shared__ ushort_t sKh[4096], sKl[4096], sVh[4096], sVl[4096]; // 8KB each
    __shared__ float sP[4][32 * 64]; // 32KB

    const int i    = blockIdx.x;
    const int xcd  = i & 7;
    const int slot = i >> 3;
    const int qt   = slot & 15;
    const int bh   = ((slot >> 4) << 3) | xcd;
    const int b    = bh >> 4, h = bh & 15;

    const int tid  = threadIdx.x;
    const int lane = tid & 63;
    const int wv   = tid >> 6;
    const int l4   = lane >> 4, l16 = lane & 15;

    // ---- Q fragments (x 1/sqrt(D)), 2 q-frags per wave
    short8 qh[2][2], ql[2][2];
    const int qr0 = qt * 128 + wv * 32;
#pragma unroll
    for (int qf = 0; qf < 2; ++qf)
#pragma unroll
    for (int sl = 0; sl < 2; ++sl) {
        const float* qp = Qb + (size_t)(b * LL + qr0 + qf * 16 + l16) * CC
                             + h * DD + sl * 32 + l4 * 8;
        f32x4 a = *(const f32x4*)qp;
        f32x4 c = *(const f32x4*)(qp + 4);
#pragma unroll
        for (int j = 0; j < 4; ++j) { a[j] *= 0.125f; c[j] *= 0.125f; }
        split8(a, c, qh[qf][sl], ql[qf][sl]);
    }

    f32x4 O[2][4];
    float mrow[2][4], lrow[2][4];
#pragma unroll
    for (int qf = 0; qf < 2; ++qf)
#pragma unroll
    for (int t = 0; t < 4; ++t) { O[qf][t] = 0.f; mrow[qf][t] = -INFINITY; lrow[qf][t] = 0.f; }

    const int r_ = tid >> 2;          // staging row 0..63
    const int c2 = (tid & 3) * 2;     // chunk pair

    short8 stg[8];
    {
        const size_t kgb = ((size_t)bh * LL + r_) * DD + c2 * 8;
        const size_t vgb = ((size_t)bh * DD + r_) * LL + c2 * 8;
        stg[0] = *(const short8*)&Kh[kgb];  stg[1] = *(const short8*)&Kh[kgb + 8];
        stg[2] = *(const short8*)&Kl[kgb];  stg[3] = *(const short8*)&Kl[kgb + 8];
        stg[4] = *(const short8*)&Vth[vgb]; stg[5] = *(const short8*)&Vth[vgb + 8];
        stg[6] = *(const short8*)&Vtl[vgb]; stg[7] = *(const short8*)&Vtl[vgb + 8];
    }

    for (int kt = 0; kt < LL / 64; ++kt) {
        __syncthreads(); // previous tile fully consumed
        {
            const int wr = r_ * 64, s = r_ & 7;
            const int cA = ((c2) ^ s) * 8, cB = ((c2 + 1) ^ s) * 8;
            *(short8*)&sKh[wr + cA] = stg[0];
            *(short8*)&sKh[wr + cB] = stg[1];
            *(short8*)&sKl[wr + cA] = stg[2];
            *(short8*)&sKl[wr + cB] = stg[3];
            *(short8*)&sVh[wr + cA] = stg[4];
            *(short8*)&sVh[wr + cB] = stg[5];
            *(short8*)&sVl[wr + cA] = stg[6];
            *(short8*)&sVl[wr + cB] = stg[7];
        }
        __syncthreads();
        if (kt + 1 < LL / 64) { // prefetch next tile into regs (latency hidden)
            const size_t kgb = ((size_t)bh * LL + (kt + 1) * 64 + r_) * DD + c2 * 8;
            const size_t vgb = ((size_t)bh * DD + r_) * LL + (kt + 1) * 64 + c2 * 8;
            stg[0] = *(const short8*)&Kh[kgb];  stg[1] = *(const short8*)&Kh[kgb + 8];
            stg[2] = *(const short8*)&Kl[kgb];  stg[3] = *(const short8*)&Kl[kgb + 8];
            stg[4] = *(const short8*)&Vth[vgb]; stg[5] = *(const short8*)&Vth[vgb + 8];
            stg[6] = *(const short8*)&Vtl[vgb]; stg[7] = *(const short8*)&Vtl[vgb + 8];
        }

        // ---- S = Q K^T
        f32x4 S[2][4];
#pragma unroll
        for (int qf = 0; qf < 2; ++qf)
#pragma unroll
        for (int t = 0; t < 4; ++t) S[qf][t] = 0.f;

        __builtin_amdgcn_s_setprio(1);
#pragma unroll
        for (int t = 0; t < 4; ++t) {
            const int row = 16 * t + l16;
            const int swr = row & 7;
#pragma unroll
            for (int sl = 0; sl < 2; ++sl) {
                const int idx = row * 64 + (((sl << 2) | l4) ^ swr) * 8;
                short8 kh = *(const short8*)&sKh[idx];
                short8 kl = *(const short8*)&sKl[idx];
#pragma unroll
                for (int qf = 0; qf < 2; ++qf) {
                    S[qf][t] = MFMA_BF16(qh[qf][sl], kh, S[qf][t]);
                    S[qf][t] = MFMA_BF16(ql[qf][sl], kh, S[qf][t]);
                    S[qf][t] = MFMA_BF16(qh[qf][sl], kl, S[qf][t]);
                }
            }
        }
        __builtin_amdgcn_s_setprio(0);

        // ---- online softmax (rows q = qf*16 + 4*l4 + r)
#pragma unroll
        for (int qf = 0; qf < 2; ++qf)
#pragma unroll
        for (int r = 0; r < 4; ++r) {
            float pm = fmaxf(fmaxf(S[qf][0][r], S[qf][1][r]),
                             fmaxf(S[qf][2][r], S[qf][3][r]));
#pragma unroll
            for (int off = 1; off < 16; off <<= 1) pm = fmaxf(pm, __shfl_xor(pm, off));
            const float mnew = fmaxf(mrow[qf][r], pm);
            const float corr = __expf(mrow[qf][r] - mnew);
            mrow[qf][r] = mnew;
            float rs = 0.f;
#pragma unroll
            for (int t = 0; t < 4; ++t) {
                float p = __expf(S[qf][t][r] - mnew);
                S[qf][t][r] = p;
                rs += p;
            }
#pragma unroll
            for (int off = 1; off < 16; off <<= 1) rs += __shfl_xor(rs, off);
            lrow[qf][r] = lrow[qf][r] * corr + rs;
#pragma unroll
            for (int dt = 0; dt < 4; ++dt) O[qf][dt][r] *= corr;
        }

        // ---- P -> per-wave LDS (f32, swizzled)
#pragma unroll
        for (int qf = 0; qf < 2; ++qf)
#pragma unroll
        for (int r = 0; r < 4; ++r) {
            const int q  = qf * 16 + 4 * l4 + r;
            const int sw = (q & 15) << 2;
#pragma unroll
            for (int t = 0; t < 4; ++t)
                sP[wv][(q * 64 + 16 * t + l16) ^ sw] = S[qf][t][r];
        }
        asm volatile("s_waitcnt lgkmcnt(0)" ::: "memory");
        __builtin_amdgcn_sched_barrier(0);

        // ---- P fragments
        short8 ph[2][2], pl[2][2];
#pragma unroll
        for (int qf = 0; qf < 2; ++qf)
#pragma unroll
        for (int sl = 0; sl < 2; ++sl) {
            const int q  = qf * 16 + l16;
            const int sw = (q & 15) << 2;
            const int e0 = (q * 64 + sl * 32 + l4 * 8) ^ sw;
            const int e1 = (q * 64 + sl * 32 + l4 * 8 + 4) ^ sw;
            f32x4 pa = *(const f32x4*)&sP[wv][e0];
            f32x4 pb = *(const f32x4*)&sP[wv][e1];
            split8(pa, pb, ph[qf][sl], pl[qf][sl]);
        }

        // ---- O += P V
        __builtin_amdgcn_s_setprio(1);
#pragma unroll
        for (int dt = 0; dt < 4; ++dt) {
            const int row = 16 * dt + l16;
            const int swr = row & 7;
#pragma unroll
            for (int sl = 0; sl < 2; ++sl) {
                const int idx = row * 64 + (((sl << 2) | l4) ^ swr) * 8;
                short8 vh = *(const short8*)&sVh[idx];
                short8 vl = *(const short8*)&sVl[idx];
#pragma unroll
                for (int qf = 0; qf < 2; ++qf) {
                    O[qf][dt] = MFMA_BF16(ph[qf][sl], vh, O[qf][dt]);
                    O[qf][dt] = MFMA_BF16(pl[qf][sl], vh, O[qf][dt]);
                    O[qf][dt] = MFMA_BF16(ph[qf][sl], vl, O[qf][dt]);
                }
            }
        }
        __builtin_amdgcn_s_setprio(0);
    }

    // ---- epilogue: h = O / l over Qbuf rows (unique owner)
#pragma unroll
    for (int qf = 0; qf < 2; ++qf)
#pragma unroll
    for (int r = 0; r < 4; ++r) {
        const float inv = 1.0f / lrow[qf][r];
        const int q = qr0 + qf * 16 + 4 * l4 + r;
        float* op = Qb + (size_t)(b * LL + q) * CC + h * DD + l16;
#pragma unroll
        for (int dt = 0; dt < 4; ++dt)
            op[16 * dt] = O[qf][dt][r] * inv;
    }
}

// ---------------------------------------------------------------------------
// Legacy fp32 fallback kernels (only if ws_size is too small; never expected)
// ---------------------------------------------------------------------------
#define Bb 128
#define Bn 128
#define BKG 8

__global__ __launch_bounds__(256)
void gemm_bias(const float* __restrict__ A, const float* __restrict__ B,
               const float* __restrict__ bias, float* __restrict__ C,
               int M, int N, int K, int lda, int ldb, int ldc)
{
    __shared__ float As[BKG][Bb];
    __shared__ float Bs[BKG][Bn];

    const int tid = threadIdx.x;
    const int m0 = blockIdx.y * Bb;
    const int n0 = blockIdx.x * Bn;
    const int ty = tid >> 4, tx = tid & 15;
    const int arow = tid >> 1, acol = (tid & 1) * 4;
    const int brow = tid >> 5, bcol = (tid & 31) * 4;

    const float* Ap = A + (size_t)(m0 + arow) * lda + acol;
    const float* Bp = B + (size_t)brow * ldb + n0 + bcol;

    float acc[8][8];
#pragma unroll
    for (int i = 0; i < 8; ++i)
#pragma unroll
        for (int j = 0; j < 8; ++j) acc[i][j] = 0.f;

    for (int k0 = 0; k0 < K; k0 += BKG) {
        float4 av = *(const float4*)(Ap + k0);
        float4 bv = *(const float4*)(Bp + (size_t)k0 * ldb);
        __syncthreads();
        As[acol + 0][arow] = av.x;
        As[acol + 1][arow] = av.y;
        As[acol + 2][arow] = av.z;
        As[acol + 3][arow] = av.w;
        *(float4*)&Bs[brow][bcol] = bv;
        __syncthreads();
#pragma unroll
        for (int kk = 0; kk < BKG; ++kk) {
            float a[8], b[8];
            *(float4*)&a[0] = *(const float4*)&As[kk][ty * 4];
            *(float4*)&a[4] = *(const float4*)&As[kk][64 + ty * 4];
            *(float4*)&b[0] = *(const float4*)&Bs[kk][tx * 4];
            *(float4*)&b[4] = *(const float4*)&Bs[kk][64 + tx * 4];
#pragma unroll
            for (int i = 0; i < 8; ++i)
#pragma unroll
                for (int j = 0; j < 8; ++j)
                    acc[i][j] = fmaf(a[i], b[j], acc[i][j]);
        }
    }
#pragma unroll
    for (int ih = 0; ih < 2; ++ih)
#pragma unroll
    for (int i = 0; i < 4; ++i) {
        const int m = m0 + ih * 64 + ty * 4 + i;
#pragma unroll
        for (int jh = 0; jh < 2; ++jh) {
            const int n = n0 + jh * 64 + tx * 4;
            float4 o;
            o.x = acc[ih*4+i][jh*4+0] + bias[n+0];
            o.y = acc[ih*4+i][jh*4+1] + bias[n+1];
            o.z = acc[ih*4+i][jh*4+2] + bias[n+2];
            o.w = acc[ih*4+i][jh*4+3] + bias[n+3];
            *(float4*)(C + (size_t)m * ldc + n) = o;
        }
    }
}

__global__ __launch_bounds__(256)
void rmsnorm_qk(float* __restrict__ qkv,
                const float* __restrict__ gq, const float* __restrict__ gk)
{
    const int gt    = blockIdx.x * 256 + threadIdx.x;
    const int lane  = gt & 63;
    const int wave  = gt >> 6;
    const int which = wave & 1;
    const int h     = (wave >> 1) & (HH - 1);
    const int bl    = wave >> 5;

    float* p = qkv + (size_t)bl * (3 * CC) + which * CC + h * DD + lane;
    float v = *p;
    float ss = v * v;
#pragma unroll
    for (int off = 32; off; off >>= 1) ss += __shfl_xor(ss, off);
    float nrm = fmaxf(sqrtf(ss), 1e-12f);
    const float* g = which ? gk : gq;
    *p = v * (8.0f / nrm) * g[h * DD + lane];
}

__global__ __launch_bounds__(256)
void flash_fp32(float* __restrict__ qkv)
{
    const int qt = blockIdx.x, hh = blockIdx.y, bb = blockIdx.z;

    __shared__ float Qt[DD][64];
    __shared__ float Kt[DD][64];
    __shared__ float Vs[64][DD];
    __shared__ float Ps[64][64 + 4];

    const int tid = threadIdx.x;
    const int ty = tid >> 4, tx = tid & 15;
    const size_t rs_ = 3 * CC;
    const float* qbase = qkv + ((size_t)bb * LL + (size_t)qt * 64) * rs_ + hh * DD;
    const float* kbase = qkv + (size_t)bb * LL * rs_ + CC + hh * DD;
    const float* vbase = kbase + CC;

    {
        const int r = tid >> 2, c0 = (tid & 3) * 16;
#pragma unroll
        for (int u = 0; u < 4; ++u) {
            float4 v = *(const float4*)(qbase + (size_t)r * rs_ + c0 + u * 4);
            Qt[c0 + u*4 + 0][r] = v.x; Qt[c0 + u*4 + 1][r] = v.y;
            Qt[c0 + u*4 + 2][r] = v.z; Qt[c0 + u*4 + 3][r] = v.w;
        }
    }

    float mrow[4], lrow[4], O[4][4];
#pragma unroll
    for (int i = 0; i < 4; ++i) {
        mrow[i] = -INFINITY; lrow[i] = 0.f;
#pragma unroll
        for (int j = 0; j < 4; ++j) O[i][j] = 0.f;
    }

    for (int kt = 0; kt < LL / 64; ++kt) {
        __syncthreads();
        {
            const int r = tid >> 2, c0 = (tid & 3) * 16;
            const float* kr = kbase + ((size_t)kt * 64 + r) * rs_;
            const float* vr = vbase + ((size_t)kt * 64 + r) * rs_;
#pragma unroll
            for (int u = 0; u < 4; ++u) {
                float4 kv = *(const float4*)(kr + c0 + u * 4);
                Kt[c0 + u*4 + 0][r] = kv.x; Kt[c0 + u*4 + 1][r] = kv.y;
                Kt[c0 + u*4 + 2][r] = kv.z; Kt[c0 + u*4 + 3][r] = kv.w;
                *(float4*)&Vs[r][c0 + u*4] = *(const float4*)(vr + c0 + u * 4);
            }
        }
        __syncthreads();

        float S[4][4];
#pragma unroll
        for (int i = 0; i < 4; ++i)
#pragma unroll
            for (int j = 0; j < 4; ++j) S[i][j] = 0.f;
#pragma unroll 8
        for (int d = 0; d < DD; ++d) {
            float a[4], b[4];
            *(float4*)a = *(const float4*)&Qt[d][ty * 4];
            *(float4*)b = *(const float4*)&Kt[d][tx * 4];
#pragma unroll
            for (int i = 0; i < 4; ++i)
#pragma unroll
                for (int j = 0; j < 4; ++j) S[i][j] = fmaf(a[i], b[j], S[i][j]);
        }
#pragma unroll
        for (int i = 0; i < 4; ++i) {
#pragma unroll
            for (int j = 0; j < 4; ++j) S[i][j] *= 0.125f;
            float pm = fmaxf(fmaxf(S[i][0], S[i][1]), fmaxf(S[i][2], S[i][3]));
#pragma unroll
            for (int off = 1; off < 16; off <<= 1) pm = fmaxf(pm, __shfl_xor(pm, off));
            const float mnew = fmaxf(mrow[i], pm);
            const float corr = __expf(mrow[i] - mnew);
            float rsum = 0.f;
#pragma unroll
            for (int j = 0; j < 4; ++j) { S[i][j] = __expf(S[i][j] - mnew); rsum += S[i][j]; }
#pragma unroll
            for (int off = 1; off < 16; off <<= 1) rsum += __shfl_xor(rsum, off);
            mrow[i] = mnew;
            lrow[i] = lrow[i] * corr + rsum;
#pragma unroll
            for (int j = 0; j < 4; ++j) O[i][j] *= corr;
        }
#pragma unroll
        for (int i = 0; i < 4; ++i)
            *(float4*)&Ps[ty * 4 + i][tx * 4] = *(float4*)&S[i][0];
        __syncthreads();
#pragma unroll 4
        for (int k = 0; k < 64; k += 4) {
            float a[4][4];
#pragma unroll
            for (int i = 0; i < 4; ++i)
                *(float4*)&a[i][0] = *(const float4*)&Ps[ty * 4 + i][k];
#pragma unroll
            for (int kk = 0; kk < 4; ++kk) {
                float b[4];
                *(float4*)b = *(const float4*)&Vs[k + kk][tx * 4];
#pragma unroll
                for (int i = 0; i < 4; ++i)
#pragma unroll
                    for (int j = 0; j < 4; ++j)
                        O[i][j] = fmaf(a[i][kk], b[j], O[i][j]);
            }
        }
    }

    float* obase = qkv + ((size_t)bb * LL + (size_t)qt * 64) * rs_ + hh * DD;
#pragma unroll
    for (int i = 0; i < 4; ++i) {
        const float inv = 1.f / lrow[i];
        float4 o;
        o.x = O[i][0] * inv; o.y = O[i][1] * inv;
        o.z = O[i][2] * inv; o.w = O[i][3] * inv;
        *(float4*)(obase + (size_t)(ty * 4 + i) * rs_ + tx * 4) = o;
    }
}

// ---------------------------------------------------------------------------
extern "C" void kernel_launch(void* const* d_in, const int* in_sizes, int n_in,
                              void* d_out, int out_size, void* d_ws, size_t ws_size,
                              hipStream_t stream)
{
    const float* x    = (const float*)d_in[0];
    const float* Wqkv = (const float*)d_in[1];
    const float* bqkv = (const float*)d_in[2];
    const float* gq   = (const float*)d_in[3];
    const float* gk   = (const float*)d_in[4];
    const float* Wout = (const float*)d_in[5];
    const float* bout = (const float*)d_in[6];
    float* out = (float*)d_out;

    const size_t T_A = 150994944ull; // + x hi/lo split
    const size_t T_B = 117440512ull; // Qbuf + K/V splits + W splits (known-good size)

    if (ws_size >= T_B) {
        char* wsb = (char*)d_ws;
        float*    Qb  = (float*)wsb;                      // 32 MiB
        ushort_t* Kh  = (ushort_t*)(wsb + 33554432);      // 16 MiB
        ushort_t* Kl  = (ushort_t*)(wsb + 50331648);
        ushort_t* Vth = (ushort_t*)(wsb + 67108864);
        ushort_t* Vtl = (ushort_t*)(wsb + 83886080);
        ushort_t* wqh = (ushort_t*)(wsb + 100663296);     // 6 MiB
        ushort_t* wql = (ushort_t*)(wsb + 106954752);
        ushort_t* woh = (ushort_t*)(wsb + 113246208);     // 2 MiB
        ushort_t* wol = (ushort_t*)(wsb + 115343360);

        transp_split<<<dim3(3 * CC / 64, CC / 64), 256, 0, stream>>>(Wqkv, wqh, wql, CC, 3 * CC);
        transp_split<<<dim3(CC / 64, CC / 64), 256, 0, stream>>>(Wout, woh, wol, CC, CC);

        if (ws_size >= T_A) {
            ushort_t* xh = (ushort_t*)(wsb + 117440512);
            ushort_t* xl = (ushort_t*)(wsb + 134217728);
            split_bf16<<<dim3(MM * CC / 8 / 256), 256, 0, stream>>>(x, xh, xl, MM * CC);
            gemm_qkv<0><<<dim3(24 * 64), 256, 0, stream>>>(
                nullptr, xh, xl, wqh, wql, bqkv, gq, gk, Qb, Kh, Kl, Vth, Vtl);
        } else {
            gemm_qkv<1><<<dim3(24 * 64), 256, 0, stream>>>(
                x, nullptr, nullptr, wqh, wql, bqkv, gq, gk, Qb, Kh, Kl, Vth, Vtl);
        }

        flash2<<<dim3(1024), 256, 0, stream>>>(Qb, Kh, Kl, Vth, Vtl);

        gemm_mfma<1><<<dim3(8 * 64), 256, 0, stream>>>(
            Qb, nullptr, nullptr, woh, wol, bout, out, CC, CC, CC, CC / 128);
    } else {
        // legacy fp32 path (needs 96 MiB): never expected on this harness
        float* qkv = (float*)d_ws;
        gemm_bias<<<dim3((3 * CC) / Bn, MM / Bb), 256, 0, stream>>>(
            x, Wqkv, bqkv, qkv, MM, 3 * CC, CC, CC, 3 * CC, 3 * CC);
        rmsnorm_qk<<<dim3((MM * HH * 2 * 64) / 256), 256, 0, stream>>>(qkv, gq, gk);
        flash_fp32<<<dim3(LL / 64, HH, BB), 256, 0, stream>>>(qkv);
        gemm_bias<<<dim3(CC / Bn, MM / Bb), 256, 0, stream>>>(
            qkv, Wout, bout, out, MM, CC, CC, 3 * CC, CC, CC);
    }
}

// Round 5
// 434.065 us; speedup vs baseline: 4.3832x; 1.5578x over previous
//
#include <hip/hip_runtime.h>
#include <math.h>

// Problem constants (B=4, L=2048, C=1024, H=16, D=64)
#define BB 4
#define LL 2048
#define CC 1024
#define HH 16
#define DD 64
#define MM (BB * LL) // 8192 rows

typedef float f32x4 __attribute__((ext_vector_type(4)));
typedef short short8 __attribute__((ext_vector_type(8))); // 8 bf16 (4 VGPRs)
typedef unsigned short ushort_t;
typedef unsigned long long u64_t;

#define MFMA_BF16(A, B, C) __builtin_amdgcn_mfma_f32_16x16x32_bf16(A, B, C, 0, 0, 0)

__device__ __forceinline__ unsigned short f2bf(float x) {
    unsigned int u = __float_as_uint(x);
    u += 0x7fffu + ((u >> 16) & 1u); // RTN-even
    return (unsigned short)(u >> 16);
}
__device__ __forceinline__ float bf2f(unsigned short h) {
    return __uint_as_float(((unsigned int)h) << 16);
}
__device__ __forceinline__ void split8(const f32x4& a, const f32x4& b,
                                       short8& h, short8& l) {
#pragma unroll
    for (int j = 0; j < 4; ++j) {
        unsigned short ha = f2bf(a[j]);
        h[j] = (short)ha; l[j] = (short)f2bf(a[j] - bf2f(ha));
        unsigned short hb = f2bf(b[j]);
        h[4 + j] = (short)hb; l[4 + j] = (short)f2bf(b[j] - bf2f(hb));
    }
}

// ---------------------------------------------------------------------------
// Elementwise f32 -> bf16 hi/lo split (for x).
// ---------------------------------------------------------------------------
__global__ __launch_bounds__(256)
void split_bf16(const float* __restrict__ src, ushort_t* __restrict__ hi,
                ushort_t* __restrict__ lo, int n)
{
    const int i = (blockIdx.x * 256 + threadIdx.x) * 8;
    if (i >= n) return;
    f32x4 a = *(const f32x4*)(src + i);
    f32x4 b = *(const f32x4*)(src + i + 4);
    short8 h, l;
    split8(a, b, h, l);
    *(short8*)(hi + i) = h;
    *(short8*)(lo + i) = l;
}

// ---------------------------------------------------------------------------
// Transpose + hi/lo split: W[K][N] f32 row-major -> WT[N][K] bf16 hi & lo.
// ---------------------------------------------------------------------------
__global__ __launch_bounds__(256)
void transp_split(const float* __restrict__ W, ushort_t* __restrict__ Th,
                  ushort_t* __restrict__ Tl, int K, int N)
{
    __shared__ float sT[64][65];
    const int k0 = blockIdx.y * 64, n0 = blockIdx.x * 64;
    const int tid = threadIdx.x;
    const int r = tid >> 2, c0 = (tid & 3) * 16;

    const float* wp = W + (size_t)(k0 + r) * N + n0 + c0;
#pragma unroll
    for (int u = 0; u < 4; ++u) {
        f32x4 v = *(const f32x4*)(wp + 4 * u);
        sT[r][c0 + 4 * u + 0] = v[0];
        sT[r][c0 + 4 * u + 1] = v[1];
        sT[r][c0 + 4 * u + 2] = v[2];
        sT[r][c0 + 4 * u + 3] = v[3];
    }
    __syncthreads();

    const int nn = tid >> 2, kk0 = (tid & 3) * 16;
    short8 h0, h1, l0, l1;
#pragma unroll
    for (int u = 0; u < 8; ++u) {
        float x = sT[kk0 + u][nn];
        unsigned short hh = f2bf(x);
        h0[u] = (short)hh; l0[u] = (short)f2bf(x - bf2f(hh));
        float y = sT[kk0 + 8 + u][nn];
        unsigned short hy = f2bf(y);
        h1[u] = (short)hy; l1[u] = (short)f2bf(y - bf2f(hy));
    }
    ushort_t* oh = Th + (size_t)(n0 + nn) * K + k0 + kk0;
    ushort_t* ol = Tl + (size_t)(n0 + nn) * K + k0 + kk0;
    *(short8*)oh = h0; *(short8*)(oh + 8) = h1;
    *(short8*)ol = l0; *(short8*)(ol + 8) = l1;
}

// ---------------------------------------------------------------------------
// Fused QKV GEMM: qkv = x @ Wqkv + bqkv, epilogue: rmsnorm q->Qb f32,
// rmsnorm k->bf16 hi/lo [b][h][l][d], v->bf16 hi/lo transposed [b][h][d][l].
// ---------------------------------------------------------------------------
template<int AF32>
__global__ __launch_bounds__(256, 2)
void gemm_qkv(const float* __restrict__ Af,
              const ushort_t* __restrict__ Agh, const ushort_t* __restrict__ Agl,
              const ushort_t* __restrict__ Bh, const ushort_t* __restrict__ Bl,
              const float* __restrict__ bias,
              const float* __restrict__ gq, const float* __restrict__ gk,
              float* __restrict__ Qb,
              ushort_t* __restrict__ Kh, ushort_t* __restrict__ Kl,
              ushort_t* __restrict__ Vth, ushort_t* __restrict__ Vtl)
{
    __shared__ ushort_t smem[32768]; // 64 KB
    ushort_t* sAh = smem;
    ushort_t* sAl = smem + 8192;
    ushort_t* sBh = smem + 16384;
    ushort_t* sBl = smem + 24576;

    const int K = CC, lda = CC, nbx = (3 * CC) / 128; // 24

    const int nwg = gridDim.x;
    const int cpx = nwg >> 3;
    const int id  = blockIdx.x;
    const int swz = (id & 7) * cpx + (id >> 3);
    const int bx = swz % nbx, by = swz / nbx;
    const int m0 = by * 128, n0 = bx * 128;

    const int tid  = threadIdx.x;
    const int lane = tid & 63;
    const int wv   = tid >> 6;
    const int l4   = lane >> 4, l16 = lane & 15;
    const int wm   = wv >> 1,  wn  = wv & 1;

    const int r0  = tid >> 2;
    const int c0  = (tid & 3) * 16;
    const int ch0 = c0 >> 3;

    f32x4 acc[4][4];
#pragma unroll
    for (int i = 0; i < 4; ++i)
#pragma unroll
        for (int j = 0; j < 4; ++j) acc[i][j] = 0.f;

    for (int kt = 0; kt < K; kt += 64) {
        __syncthreads();
#pragma unroll
        for (int it = 0; it < 2; ++it) {
            const int row  = r0 + 64 * it;
            const int sA   = row & 7;
            const int base = row * 64;
            const int cA = ((ch0) ^ sA) * 8, cB = ((ch0 + 1) ^ sA) * 8;

            if constexpr (AF32) {
                const float* ap = Af + (size_t)(m0 + row) * lda + kt + c0;
                f32x4 v0 = *(const f32x4*)(ap);
                f32x4 v1 = *(const f32x4*)(ap + 4);
                f32x4 v2 = *(const f32x4*)(ap + 8);
                f32x4 v3 = *(const f32x4*)(ap + 12);
                short8 h0, l0, h1, l1;
                split8(v0, v1, h0, l0);
                split8(v2, v3, h1, l1);
                *(short8*)&sAh[base + cA] = h0;
                *(short8*)&sAh[base + cB] = h1;
                *(short8*)&sAl[base + cA] = l0;
                *(short8*)&sAl[base + cB] = l1;
            } else {
                const ushort_t* ahp = Agh + (size_t)(m0 + row) * lda + kt + c0;
                const ushort_t* alp = Agl + (size_t)(m0 + row) * lda + kt + c0;
                *(short8*)&sAh[base + cA] = *(const short8*)(ahp);
                *(short8*)&sAh[base + cB] = *(const short8*)(ahp + 8);
                *(short8*)&sAl[base + cA] = *(const short8*)(alp);
                *(short8*)&sAl[base + cB] = *(const short8*)(alp + 8);
            }
            const ushort_t* bhp = Bh + (size_t)(n0 + row) * K + kt + c0;
            const ushort_t* blp = Bl + (size_t)(n0 + row) * K + kt + c0;
            *(short8*)&sBh[base + cA] = *(const short8*)(bhp);
            *(short8*)&sBh[base + cB] = *(const short8*)(bhp + 8);
            *(short8*)&sBl[base + cA] = *(const short8*)(blp);
            *(short8*)&sBl[base + cB] = *(const short8*)(blp + 8);
        }
        __syncthreads();

#pragma unroll
        for (int ks = 0; ks < 2; ++ks) {
            const int chf = (((ks << 2) | l4) ^ (l16 & 7)) * 8;
            short8 fbh[4], fbl[4];
#pragma unroll
            for (int j = 0; j < 4; ++j) {
                const int idx = (64 * wn + 16 * j + l16) * 64 + chf;
                fbh[j] = *(const short8*)&sBh[idx];
                fbl[j] = *(const short8*)&sBl[idx];
            }
#pragma unroll
            for (int i = 0; i < 4; ++i) {
                const int idx = (64 * wm + 16 * i + l16) * 64 + chf;
                short8 fah = *(const short8*)&sAh[idx];
                short8 fal = *(const short8*)&sAl[idx];
#pragma unroll
                for (int j = 0; j < 4; ++j) {
                    acc[i][j] = MFMA_BF16(fah, fbh[j], acc[i][j]);
                    acc[i][j] = MFMA_BF16(fal, fbh[j], acc[i][j]);
                    acc[i][j] = MFMA_BF16(fah, fbl[j], acc[i][j]);
                }
            }
        }
    }

    // ---- epilogue -------------------------------------------------------
    const int region = n0 >> 10; // 0=q, 1=k, 2=v
    float bv[4];
#pragma unroll
    for (int j = 0; j < 4; ++j) bv[j] = bias[n0 + 64 * wn + 16 * j + l16];
#pragma unroll
    for (int i = 0; i < 4; ++i)
#pragma unroll
        for (int j = 0; j < 4; ++j)
#pragma unroll
            for (int r = 0; r < 4; ++r) acc[i][j][r] += bv[j];

    const int b = m0 >> 11;

    if (region < 2) {
        const int hloc = ((n0 & 1023) >> 6) + wn;
        const float* g = (region == 0 ? gq : gk) + hloc * DD;
        float gv[4];
#pragma unroll
        for (int j = 0; j < 4; ++j) gv[j] = g[16 * j + l16];
#pragma unroll
        for (int i = 0; i < 4; ++i)
#pragma unroll
        for (int r = 0; r < 4; ++r) {
            float ss = 0.f;
#pragma unroll
            for (int j = 0; j < 4; ++j) ss += acc[i][j][r] * acc[i][j][r];
#pragma unroll
            for (int off = 1; off < 16; off <<= 1) ss += __shfl_xor(ss, off);
            const float s = 8.0f / fmaxf(sqrtf(ss), 1e-12f);
#pragma unroll
            for (int j = 0; j < 4; ++j) acc[i][j][r] *= s * gv[j];
        }

        if (region == 0) {
#pragma unroll
            for (int i = 0; i < 4; ++i)
#pragma unroll
            for (int r = 0; r < 4; ++r) {
                const int row = m0 + 64 * wm + 16 * i + 4 * l4 + r;
                float* op = Qb + (size_t)row * CC + n0 + 64 * wn + l16;
#pragma unroll
                for (int j = 0; j < 4; ++j) op[16 * j] = acc[i][j][r];
            }
        } else {
            const int hk = ((n0 - 1024) >> 6) + wn;
#pragma unroll
            for (int i = 0; i < 4; ++i)
#pragma unroll
            for (int r = 0; r < 4; ++r) {
                const int l = (m0 & 2047) + 64 * wm + 16 * i + 4 * l4 + r;
                const size_t base = ((size_t)(b * HH + hk) * LL + l) * DD + l16;
#pragma unroll
                for (int j = 0; j < 4; ++j) {
                    float v = acc[i][j][r];
                    unsigned short hh = f2bf(v);
                    Kh[base + 16 * j] = hh;
                    Kl[base + 16 * j] = f2bf(v - bf2f(hh));
                }
            }
        }
    } else {
        // V: split + 128x128 LDS transpose + vector store to [b][h][d][l]
        __syncthreads();
        ushort_t* vh = smem;
        ushort_t* vl = smem + 16384;
#pragma unroll
        for (int i = 0; i < 4; ++i)
#pragma unroll
        for (int r = 0; r < 4; ++r) {
            const int lr = 64 * wm + 16 * i + 4 * l4 + r;
#pragma unroll
            for (int j = 0; j < 4; ++j) {
                const int c = 64 * wn + 16 * j + l16;
                float v = acc[i][j][r];
                unsigned short hh = f2bf(v);
                vh[lr * 128 + c] = hh;
                vl[lr * 128 + c] = f2bf(v - bf2f(hh));
            }
        }
        __syncthreads();
        const int c    = tid & 127;
        const int half = tid >> 7;
        const int hv   = ((n0 - 2048) >> 6) + (c >> 6);
        const int d    = c & 63;
        ushort_t* oh = Vth + ((size_t)(b * HH + hv) * DD + d) * LL + (m0 & 2047) + half * 64;
        ushort_t* ol = Vtl + ((size_t)(b * HH + hv) * DD + d) * LL + (m0 & 2047) + half * 64;
#pragma unroll
        for (int u = 0; u < 8; ++u) {
            const int l0 = half * 64 + u * 8;
            short8 hv8, lv8;
#pragma unroll
            for (int e = 0; e < 8; ++e) {
                hv8[e] = (short)vh[(l0 + e) * 128 + c];
                lv8[e] = (short)vl[(l0 + e) * 128 + c];
            }
            *(short8*)&oh[u * 8] = hv8;
            *(short8*)&ol[u * 8] = lv8;
        }
    }
}

// ---------------------------------------------------------------------------
// MFMA GEMM (plain bias epilogue) — output projection.
// ---------------------------------------------------------------------------
template<int AF32>
__global__ __launch_bounds__(256, 2)
void gemm_mfma(const float* __restrict__ Af,
               const ushort_t* __restrict__ Agh, const ushort_t* __restrict__ Agl,
               const ushort_t* __restrict__ Bh, const ushort_t* __restrict__ Bl,
               const float* __restrict__ bias, float* __restrict__ Cg,
               int K, int lda, int ldc, int nbx)
{
    __shared__ ushort_t sAh[128 * 64];
    __shared__ ushort_t sAl[128 * 64];
    __shared__ ushort_t sBh[128 * 64];
    __shared__ ushort_t sBl[128 * 64];

    const int nwg = gridDim.x;
    const int cpx = nwg >> 3;
    const int id  = blockIdx.x;
    const int sw  = (id & 7) * cpx + (id >> 3);
    const int bx = sw % nbx, by = sw / nbx;
    const int m0 = by * 128, n0 = bx * 128;

    const int tid  = threadIdx.x;
    const int lane = tid & 63;
    const int wv   = tid >> 6;
    const int l4   = lane >> 4, l16 = lane & 15;
    const int wm   = wv >> 1,  wn  = wv & 1;

    const int r0  = tid >> 2;
    const int c0  = (tid & 3) * 16;
    const int ch0 = c0 >> 3;

    f32x4 acc[4][4];
#pragma unroll
    for (int i = 0; i < 4; ++i)
#pragma unroll
        for (int j = 0; j < 4; ++j) acc[i][j] = 0.f;

    for (int kt = 0; kt < K; kt += 64) {
        __syncthreads();
#pragma unroll
        for (int it = 0; it < 2; ++it) {
            const int row  = r0 + 64 * it;
            const int sA   = row & 7;
            const int base = row * 64;
            const int cA = ((ch0) ^ sA) * 8, cB = ((ch0 + 1) ^ sA) * 8;

            if constexpr (AF32) {
                const float* ap = Af + (size_t)(m0 + row) * lda + kt + c0;
                f32x4 v0 = *(const f32x4*)(ap);
                f32x4 v1 = *(const f32x4*)(ap + 4);
                f32x4 v2 = *(const f32x4*)(ap + 8);
                f32x4 v3 = *(const f32x4*)(ap + 12);
                short8 h0, l0, h1, l1;
                split8(v0, v1, h0, l0);
                split8(v2, v3, h1, l1);
                *(short8*)&sAh[base + cA] = h0;
                *(short8*)&sAh[base + cB] = h1;
                *(short8*)&sAl[base + cA] = l0;
                *(short8*)&sAl[base + cB] = l1;
            } else {
                const ushort_t* ahp = Agh + (size_t)(m0 + row) * lda + kt + c0;
                const ushort_t* alp = Agl + (size_t)(m0 + row) * lda + kt + c0;
                *(short8*)&sAh[base + cA] = *(const short8*)(ahp);
                *(short8*)&sAh[base + cB] = *(const short8*)(ahp + 8);
                *(short8*)&sAl[base + cA] = *(const short8*)(alp);
                *(short8*)&sAl[base + cB] = *(const short8*)(alp + 8);
            }
            const ushort_t* bhp = Bh + (size_t)(n0 + row) * K + kt + c0;
            const ushort_t* blp = Bl + (size_t)(n0 + row) * K + kt + c0;
            *(short8*)&sBh[base + cA] = *(const short8*)(bhp);
            *(short8*)&sBh[base + cB] = *(const short8*)(bhp + 8);
            *(short8*)&sBl[base + cA] = *(const short8*)(blp);
            *(short8*)&sBl[base + cB] = *(const short8*)(blp + 8);
        }
        __syncthreads();

#pragma unroll
        for (int ks = 0; ks < 2; ++ks) {
            const int chf = (((ks << 2) | l4) ^ (l16 & 7)) * 8;
            short8 fbh[4], fbl[4];
#pragma unroll
            for (int j = 0; j < 4; ++j) {
                const int idx = (64 * wn + 16 * j + l16) * 64 + chf;
                fbh[j] = *(const short8*)&sBh[idx];
                fbl[j] = *(const short8*)&sBl[idx];
            }
#pragma unroll
            for (int i = 0; i < 4; ++i) {
                const int idx = (64 * wm + 16 * i + l16) * 64 + chf;
                short8 fah = *(const short8*)&sAh[idx];
                short8 fal = *(const short8*)&sAl[idx];
#pragma unroll
                for (int j = 0; j < 4; ++j) {
                    acc[i][j] = MFMA_BF16(fah, fbh[j], acc[i][j]);
                    acc[i][j] = MFMA_BF16(fal, fbh[j], acc[i][j]);
                    acc[i][j] = MFMA_BF16(fah, fbl[j], acc[i][j]);
                }
            }
        }
    }

    float bv[4];
#pragma unroll
    for (int j = 0; j < 4; ++j) bv[j] = bias[n0 + 64 * wn + 16 * j + l16];
#pragma unroll
    for (int i = 0; i < 4; ++i)
#pragma unroll
    for (int r = 0; r < 4; ++r) {
        const int row = m0 + 64 * wm + 16 * i + 4 * l4 + r;
        float* cp = Cg + (size_t)row * ldc + n0 + 64 * wn + l16;
#pragma unroll
        for (int j = 0; j < 4; ++j) cp[16 * j] = acc[i][j][r] + bv[j];
    }
}

// ---------------------------------------------------------------------------
// Flash attention v3: swapped QK^T (S^T = K·Q) -> lane-local softmax rows,
// P stored hi-only bf16 via vector b64 writes. 4 waves x 32 q-rows, KV=64.
// LDS 49 KB -> 3 blocks/CU. Defer-max rescale (THR=8).
// ---------------------------------------------------------------------------
__global__ __launch_bounds__(256, 3)
void flash3(float* __restrict__ Qb,
            const ushort_t* __restrict__ Kh, const ushort_t* __restrict__ Kl,
            const ushort_t* __restrict__ Vth, const ushort_t* __restrict__ Vtl)
{
    __shared__ ushort_t sKh[4096], sKl[4096], sVh[4096], sVl[4096]; // 32 KB
    __shared__ ushort_t sP[4][32 * 68];                             // 17 KB

    const int i    = blockIdx.x;
    const int xcd  = i & 7;
    const int slot = i >> 3;
    const int qt   = slot & 15;
    const int bh   = ((slot >> 4) << 3) | xcd;
    const int b    = bh >> 4, h = bh & 15;

    const int tid  = threadIdx.x;
    const int lane = tid & 63;
    const int wv   = tid >> 6;
    const int l4   = lane >> 4, l16 = lane & 15;

    // ---- Q fragments (x 1/sqrt(D)), 2 q-frags per wave (B-operand)
    short8 qh[2][2], ql[2][2];
    const int qr0 = qt * 128 + wv * 32;
#pragma unroll
    for (int qf = 0; qf < 2; ++qf)
#pragma unroll
    for (int sl = 0; sl < 2; ++sl) {
        const float* qp = Qb + (size_t)(b * LL + qr0 + qf * 16 + l16) * CC
                             + h * DD + sl * 32 + l4 * 8;
        f32x4 a = *(const f32x4*)qp;
        f32x4 c = *(const f32x4*)(qp + 4);
#pragma unroll
        for (int j = 0; j < 4; ++j) { a[j] *= 0.125f; c[j] *= 0.125f; }
        split8(a, c, qh[qf][sl], ql[qf][sl]);
    }

    f32x4 O[2][4];
    float mrow[2], lrow[2]; // state for q-row (qf*16 + l16), replicated over l4
#pragma unroll
    for (int qf = 0; qf < 2; ++qf) {
        mrow[qf] = -INFINITY; lrow[qf] = 0.f;
#pragma unroll
        for (int t = 0; t < 4; ++t) O[qf][t] = 0.f;
    }

    const int r_ = tid >> 2;          // staging row 0..63
    const int c2 = (tid & 3) * 2;     // chunk pair

    short8 stg[8];
    {
        const size_t kgb = ((size_t)bh * LL + r_) * DD + c2 * 8;
        const size_t vgb = ((size_t)bh * DD + r_) * LL + c2 * 8;
        stg[0] = *(const short8*)&Kh[kgb];  stg[1] = *(const short8*)&Kh[kgb + 8];
        stg[2] = *(const short8*)&Kl[kgb];  stg[3] = *(const short8*)&Kl[kgb + 8];
        stg[4] = *(const short8*)&Vth[vgb]; stg[5] = *(const short8*)&Vth[vgb + 8];
        stg[6] = *(const short8*)&Vtl[vgb]; stg[7] = *(const short8*)&Vtl[vgb + 8];
    }

    for (int kt = 0; kt < LL / 64; ++kt) {
        __syncthreads(); // previous tile fully consumed
        {
            const int wr = r_ * 64, s = r_ & 7;
            const int cA = ((c2) ^ s) * 8, cB = ((c2 + 1) ^ s) * 8;
            *(short8*)&sKh[wr + cA] = stg[0];
            *(short8*)&sKh[wr + cB] = stg[1];
            *(short8*)&sKl[wr + cA] = stg[2];
            *(short8*)&sKl[wr + cB] = stg[3];
            *(short8*)&sVh[wr + cA] = stg[4];
            *(short8*)&sVh[wr + cB] = stg[5];
            *(short8*)&sVl[wr + cA] = stg[6];
            *(short8*)&sVl[wr + cB] = stg[7];
        }
        __syncthreads();
        if (kt + 1 < LL / 64) { // prefetch next tile into regs
            const size_t kgb = ((size_t)bh * LL + (kt + 1) * 64 + r_) * DD + c2 * 8;
            const size_t vgb = ((size_t)bh * DD + r_) * LL + (kt + 1) * 64 + c2 * 8;
            stg[0] = *(const short8*)&Kh[kgb];  stg[1] = *(const short8*)&Kh[kgb + 8];
            stg[2] = *(const short8*)&Kl[kgb];  stg[3] = *(const short8*)&Kl[kgb + 8];
            stg[4] = *(const short8*)&Vth[vgb]; stg[5] = *(const short8*)&Vth[vgb + 8];
            stg[6] = *(const short8*)&Vtl[vgb]; stg[7] = *(const short8*)&Vtl[vgb + 8];
        }

        // ---- S^T = K Q : rows k (4*l4+r per tile t), cols q (l16)
        f32x4 S[2][4];
#pragma unroll
        for (int qf = 0; qf < 2; ++qf)
#pragma unroll
        for (int t = 0; t < 4; ++t) S[qf][t] = 0.f;

        __builtin_amdgcn_s_setprio(1);
#pragma unroll
        for (int t = 0; t < 4; ++t) {
            const int row = 16 * t + l16;
            const int swr = row & 7;
#pragma unroll
            for (int sl = 0; sl < 2; ++sl) {
                const int idx = row * 64 + (((sl << 2) | l4) ^ swr) * 8;
                short8 kh8 = *(const short8*)&sKh[idx];
                short8 kl8 = *(const short8*)&sKl[idx];
#pragma unroll
                for (int qf = 0; qf < 2; ++qf) {
                    S[qf][t] = MFMA_BF16(kh8, qh[qf][sl], S[qf][t]);
                    S[qf][t] = MFMA_BF16(kh8, ql[qf][sl], S[qf][t]);
                    S[qf][t] = MFMA_BF16(kl8, qh[qf][sl], S[qf][t]);
                }
            }
        }
        __builtin_amdgcn_s_setprio(0);

        // ---- lane-local softmax (each lane owns row q = qf*16+l16, 16 ks)
#pragma unroll
        for (int qf = 0; qf < 2; ++qf) {
            float pm = S[qf][0][0];
#pragma unroll
            for (int t = 0; t < 4; ++t)
#pragma unroll
                for (int r = 0; r < 4; ++r) pm = fmaxf(pm, S[qf][t][r]);
            pm = fmaxf(pm, __shfl_xor(pm, 16));
            pm = fmaxf(pm, __shfl_xor(pm, 32));

            if (__any(pm > mrow[qf] + 8.f)) { // rescale (rare after tile 0)
                const float mnew = fmaxf(mrow[qf], pm);
                const float corr = __expf(mrow[qf] - mnew);
                mrow[qf] = mnew;
                lrow[qf] *= corr;
                float c0 = __shfl(corr, 4 * l4 + 0);
                float c1 = __shfl(corr, 4 * l4 + 1);
                float c2v = __shfl(corr, 4 * l4 + 2);
                float c3 = __shfl(corr, 4 * l4 + 3);
#pragma unroll
                for (int dt = 0; dt < 4; ++dt) {
                    O[qf][dt][0] *= c0; O[qf][dt][1] *= c1;
                    O[qf][dt][2] *= c2v; O[qf][dt][3] *= c3;
                }
            }
            float rs = 0.f;
#pragma unroll
            for (int t = 0; t < 4; ++t)
#pragma unroll
                for (int r = 0; r < 4; ++r) {
                    float p = __expf(S[qf][t][r] - mrow[qf]);
                    S[qf][t][r] = p;
                    rs += p;
                }
            rs += __shfl_xor(rs, 16);
            rs += __shfl_xor(rs, 32);
            lrow[qf] += rs;
        }

        // ---- P -> per-wave LDS (bf16 hi-only), vector b64 writes
#pragma unroll
        for (int qf = 0; qf < 2; ++qf)
#pragma unroll
        for (int t = 0; t < 4; ++t) {
            unsigned lo = (unsigned)f2bf(S[qf][t][0]) | ((unsigned)f2bf(S[qf][t][1]) << 16);
            unsigned hi = (unsigned)f2bf(S[qf][t][2]) | ((unsigned)f2bf(S[qf][t][3]) << 16);
            const int widx = (qf * 16 + l16) * 68 + 16 * t + 4 * l4;
            *(u64_t*)&sP[wv][widx] = (u64_t)lo | ((u64_t)hi << 32);
        }
        asm volatile("s_waitcnt lgkmcnt(0)" ::: "memory");
        __builtin_amdgcn_sched_barrier(0);

        // ---- P A-fragments: row q = l16, k = sl*32 + 8*l4 + j
        short8 pa[2][2];
#pragma unroll
        for (int qf = 0; qf < 2; ++qf)
#pragma unroll
        for (int sl = 0; sl < 2; ++sl) {
            const int ridx = (qf * 16 + l16) * 68 + sl * 32 + 8 * l4;
            union { u64_t q[2]; short8 s8; } u;
            u.q[0] = *(const u64_t*)&sP[wv][ridx];
            u.q[1] = *(const u64_t*)&sP[wv][ridx + 4];
            pa[qf][sl] = u.s8;
        }

        // ---- O += P V (P hi-only; V hi/lo)
        __builtin_amdgcn_s_setprio(1);
#pragma unroll
        for (int dt = 0; dt < 4; ++dt) {
            const int row = 16 * dt + l16;
            const int swr = row & 7;
#pragma unroll
            for (int sl = 0; sl < 2; ++sl) {
                const int idx = row * 64 + (((sl << 2) | l4) ^ swr) * 8;
                short8 vh8 = *(const short8*)&sVh[idx];
                short8 vl8 = *(const short8*)&sVl[idx];
#pragma unroll
                for (int qf = 0; qf < 2; ++qf) {
                    O[qf][dt] = MFMA_BF16(pa[qf][sl], vh8, O[qf][dt]);
                    O[qf][dt] = MFMA_BF16(pa[qf][sl], vl8, O[qf][dt]);
                }
            }
        }
        __builtin_amdgcn_s_setprio(0);
    }

    // ---- epilogue: h = O / l over Qbuf rows (unique owner)
#pragma unroll
    for (int qf = 0; qf < 2; ++qf) {
        const float inv = 1.0f / lrow[qf];
        float i0 = __shfl(inv, 4 * l4 + 0);
        float i1 = __shfl(inv, 4 * l4 + 1);
        float i2 = __shfl(inv, 4 * l4 + 2);
        float i3 = __shfl(inv, 4 * l4 + 3);
        f32x4 iv; iv[0] = i0; iv[1] = i1; iv[2] = i2; iv[3] = i3;
#pragma unroll
        for (int r = 0; r < 4; ++r) {
            const int q = qr0 + qf * 16 + 4 * l4 + r;
            float* op = Qb + (size_t)(b * LL + q) * CC + h * DD + l16;
#pragma unroll
            for (int dt = 0; dt < 4; ++dt)
                op[16 * dt] = O[qf][dt][r] * iv[r];
        }
    }
}

// ---------------------------------------------------------------------------
// Legacy fp32 fallback kernels (only if ws_size is too small; never expected)
// ---------------------------------------------------------------------------
#define Bb 128
#define Bn 128
#define BKG 8

__global__ __launch_bounds__(256)
void gemm_bias(const float* __restrict__ A, const float* __restrict__ B,
               const float* __restrict__ bias, float* __restrict__ C,
               int M, int N, int K, int lda, int ldb, int ldc)
{
    __shared__ float As[BKG][Bb];
    __shared__ float Bs[BKG][Bn];

    const int tid = threadIdx.x;
    const int m0 = blockIdx.y * Bb;
    const int n0 = blockIdx.x * Bn;
    const int ty = tid >> 4, tx = tid & 15;
    const int arow = tid >> 1, acol = (tid & 1) * 4;
    const int brow = tid >> 5, bcol = (tid & 31) * 4;

    const float* Ap = A + (size_t)(m0 + arow) * lda + acol;
    const float* Bp = B + (size_t)brow * ldb + n0 + bcol;

    float acc[8][8];
#pragma unroll
    for (int i = 0; i < 8; ++i)
#pragma unroll
        for (int j = 0; j < 8; ++j) acc[i][j] = 0.f;

    for (int k0 = 0; k0 < K; k0 += BKG) {
        float4 av = *(const float4*)(Ap + k0);
        float4 bv = *(const float4*)(Bp + (size_t)k0 * ldb);
        __syncthreads();
        As[acol + 0][arow] = av.x;
        As[acol + 1][arow] = av.y;
        As[acol + 2][arow] = av.z;
        As[acol + 3][arow] = av.w;
        *(float4*)&Bs[brow][bcol] = bv;
        __syncthreads();
#pragma unroll
        for (int kk = 0; kk < BKG; ++kk) {
            float a[8], bvv[8];
            *(float4*)&a[0] = *(const float4*)&As[kk][ty * 4];
            *(float4*)&a[4] = *(const float4*)&As[kk][64 + ty * 4];
            *(float4*)&bvv[0] = *(const float4*)&Bs[kk][tx * 4];
            *(float4*)&bvv[4] = *(const float4*)&Bs[kk][64 + tx * 4];
#pragma unroll
            for (int i = 0; i < 8; ++i)
#pragma unroll
                for (int j = 0; j < 8; ++j)
                    acc[i][j] = fmaf(a[i], bvv[j], acc[i][j]);
        }
    }
#pragma unroll
    for (int ih = 0; ih < 2; ++ih)
#pragma unroll
    for (int i = 0; i < 4; ++i) {
        const int m = m0 + ih * 64 + ty * 4 + i;
#pragma unroll
        for (int jh = 0; jh < 2; ++jh) {
            const int n = n0 + jh * 64 + tx * 4;
            float4 o;
            o.x = acc[ih*4+i][jh*4+0] + bias[n+0];
            o.y = acc[ih*4+i][jh*4+1] + bias[n+1];
            o.z = acc[ih*4+i][jh*4+2] + bias[n+2];
            o.w = acc[ih*4+i][jh*4+3] + bias[n+3];
            *(float4*)(C + (size_t)m * ldc + n) = o;
        }
    }
}

__global__ __launch_bounds__(256)
void rmsnorm_qk(float* __restrict__ qkv,
                const float* __restrict__ gq, const float* __restrict__ gk)
{
    const int gt    = blockIdx.x * 256 + threadIdx.x;
    const int lane  = gt & 63;
    const int wave  = gt >> 6;
    const int which = wave & 1;
    const int h     = (wave >> 1) & (HH - 1);
    const int bl    = wave >> 5;

    float* p = qkv + (size_t)bl * (3 * CC) + which * CC + h * DD + lane;
    float v = *p;
    float ss = v * v;
#pragma unroll
    for (int off = 32; off; off >>= 1) ss += __shfl_xor(ss, off);
    float nrm = fmaxf(sqrtf(ss), 1e-12f);
    const float* g = which ? gk : gq;
    *p = v * (8.0f / nrm) * g[h * DD + lane];
}

__global__ __launch_bounds__(256)
void flash_fp32(float* __restrict__ qkv)
{
    const int qt = blockIdx.x, hh = blockIdx.y, bb = blockIdx.z;

    __shared__ float Qt[DD][64];
    __shared__ float Kt[DD][64];
    __shared__ float Vs[64][DD];
    __shared__ float Ps[64][64 + 4];

    const int tid = threadIdx.x;
    const int ty = tid >> 4, tx = tid & 15;
    const size_t rs_ = 3 * CC;
    const float* qbase = qkv + ((size_t)bb * LL + (size_t)qt * 64) * rs_ + hh * DD;
    const float* kbase = qkv + (size_t)bb * LL * rs_ + CC + hh * DD;
    const float* vbase = kbase + CC;

    {
        const int r = tid >> 2, c0 = (tid & 3) * 16;
#pragma unroll
        for (int u = 0; u < 4; ++u) {
            float4 v = *(const float4*)(qbase + (size_t)r * rs_ + c0 + u * 4);
            Qt[c0 + u*4 + 0][r] = v.x; Qt[c0 + u*4 + 1][r] = v.y;
            Qt[c0 + u*4 + 2][r] = v.z; Qt[c0 + u*4 + 3][r] = v.w;
        }
    }

    float mrow[4], lrow[4], O[4][4];
#pragma unroll
    for (int i = 0; i < 4; ++i) {
        mrow[i] = -INFINITY; lrow[i] = 0.f;
#pragma unroll
        for (int j = 0; j < 4; ++j) O[i][j] = 0.f;
    }

    for (int kt = 0; kt < LL / 64; ++kt) {
        __syncthreads();
        {
            const int r = tid >> 2, c0 = (tid & 3) * 16;
            const float* kr = kbase + ((size_t)kt * 64 + r) * rs_;
            const float* vr = vbase + ((size_t)kt * 64 + r) * rs_;
#pragma unroll
            for (int u = 0; u < 4; ++u) {
                float4 kv = *(const float4*)(kr + c0 + u * 4);
                Kt[c0 + u*4 + 0][r] = kv.x; Kt[c0 + u*4 + 1][r] = kv.y;
                Kt[c0 + u*4 + 2][r] = kv.z; Kt[c0 + u*4 + 3][r] = kv.w;
                *(float4*)&Vs[r][c0 + u*4] = *(const float4*)(vr + c0 + u * 4);
            }
        }
        __syncthreads();

        float S[4][4];
#pragma unroll
        for (int i = 0; i < 4; ++i)
#pragma unroll
            for (int j = 0; j < 4; ++j) S[i][j] = 0.f;
#pragma unroll 8
        for (int d = 0; d < DD; ++d) {
            float a[4], b[4];
            *(float4*)a = *(const float4*)&Qt[d][ty * 4];
            *(float4*)b = *(const float4*)&Kt[d][tx * 4];
#pragma unroll
            for (int i = 0; i < 4; ++i)
#pragma unroll
                for (int j = 0; j < 4; ++j) S[i][j] = fmaf(a[i], b[j], S[i][j]);
        }
#pragma unroll
        for (int i = 0; i < 4; ++i) {
#pragma unroll
            for (int j = 0; j < 4; ++j) S[i][j] *= 0.125f;
            float pm = fmaxf(fmaxf(S[i][0], S[i][1]), fmaxf(S[i][2], S[i][3]));
#pragma unroll
            for (int off = 1; off < 16; off <<= 1) pm = fmaxf(pm, __shfl_xor(pm, off));
            const float mnew = fmaxf(mrow[i], pm);
            const float corr = __expf(mrow[i] - mnew);
            float rsum = 0.f;
#pragma unroll
            for (int j = 0; j < 4; ++j) { S[i][j] = __expf(S[i][j] - mnew); rsum += S[i][j]; }
#pragma unroll
            for (int off = 1; off < 16; off <<= 1) rsum += __shfl_xor(rsum, off);
            mrow[i] = mnew;
            lrow[i] = lrow[i] * corr + rsum;
#pragma unroll
            for (int j = 0; j < 4; ++j) O[i][j] *= corr;
        }
#pragma unroll
        for (int i = 0; i < 4; ++i)
            *(float4*)&Ps[ty * 4 + i][tx * 4] = *(float4*)&S[i][0];
        __syncthreads();
#pragma unroll 4
        for (int k = 0; k < 64; k += 4) {
            float a[4][4];
#pragma unroll
            for (int i = 0; i < 4; ++i)
                *(float4*)&a[i][0] = *(const float4*)&Ps[ty * 4 + i][k];
#pragma unroll
            for (int kk = 0; kk < 4; ++kk) {
                float bv[4];
                *(float4*)bv = *(const float4*)&Vs[k + kk][tx * 4];
#pragma unroll
                for (int i = 0; i < 4; ++i)
#pragma unroll
                    for (int j = 0; j < 4; ++j)
                        O[i][j] = fmaf(a[i][kk], bv[j], O[i][j]);
            }
        }
    }

    float* obase = qkv + ((size_t)bb * LL + (size_t)qt * 64) * rs_ + hh * DD;
#pragma unroll
    for (int i = 0; i < 4; ++i) {
        const float inv = 1.f / lrow[i];
        float4 o;
        o.x = O[i][0] * inv; o.y = O[i][1] * inv;
        o.z = O[i][2] * inv; o.w = O[i][3] * inv;
        *(float4*)(obase + (size_t)(ty * 4 + i) * rs_ + tx * 4) = o;
    }
}

// ---------------------------------------------------------------------------
extern "C" void kernel_launch(void* const* d_in, const int* in_sizes, int n_in,
                              void* d_out, int out_size, void* d_ws, size_t ws_size,
                              hipStream_t stream)
{
    const float* x    = (const float*)d_in[0];
    const float* Wqkv = (const float*)d_in[1];
    const float* bqkv = (const float*)d_in[2];
    const float* gq   = (const float*)d_in[3];
    const float* gk   = (const float*)d_in[4];
    const float* Wout = (const float*)d_in[5];
    const float* bout = (const float*)d_in[6];
    float* out = (float*)d_out;

    const size_t T_A = 150994944ull; // + x hi/lo split
    const size_t T_B = 117440512ull; // known-good workspace size

    if (ws_size >= T_B) {
        char* wsb = (char*)d_ws;
        float*    Qb  = (float*)wsb;                      // 32 MiB
        ushort_t* Kh  = (ushort_t*)(wsb + 33554432);      // 16 MiB
        ushort_t* Kl  = (ushort_t*)(wsb + 50331648);
        ushort_t* Vth = (ushort_t*)(wsb + 67108864);
        ushort_t* Vtl = (ushort_t*)(wsb + 83886080);
        ushort_t* wqh = (ushort_t*)(wsb + 100663296);     // 6 MiB
        ushort_t* wql = (ushort_t*)(wsb + 106954752);
        ushort_t* woh = (ushort_t*)(wsb + 113246208);     // 2 MiB
        ushort_t* wol = (ushort_t*)(wsb + 115343360);

        transp_split<<<dim3(3 * CC / 64, CC / 64), 256, 0, stream>>>(Wqkv, wqh, wql, CC, 3 * CC);
        transp_split<<<dim3(CC / 64, CC / 64), 256, 0, stream>>>(Wout, woh, wol, CC, CC);

        if (ws_size >= T_A) {
            ushort_t* xh = (ushort_t*)(wsb + 117440512);
            ushort_t* xl = (ushort_t*)(wsb + 134217728);
            split_bf16<<<dim3(MM * CC / 8 / 256), 256, 0, stream>>>(x, xh, xl, MM * CC);
            gemm_qkv<0><<<dim3(24 * 64), 256, 0, stream>>>(
                nullptr, xh, xl, wqh, wql, bqkv, gq, gk, Qb, Kh, Kl, Vth, Vtl);
        } else {
            gemm_qkv<1><<<dim3(24 * 64), 256, 0, stream>>>(
                x, nullptr, nullptr, wqh, wql, bqkv, gq, gk, Qb, Kh, Kl, Vth, Vtl);
        }

        flash3<<<dim3(1024), 256, 0, stream>>>(Qb, Kh, Kl, Vth, Vtl);

        gemm_mfma<1><<<dim3(8 * 64), 256, 0, stream>>>(
            Qb, nullptr, nullptr, woh, wol, bout, out, CC, CC, CC, CC / 128);
    } else {
        // legacy fp32 path
        float* qkv = (float*)d_ws;
        gemm_bias<<<dim3((3 * CC) / Bn, MM / Bb), 256, 0, stream>>>(
            x, Wqkv, bqkv, qkv, MM, 3 * CC, CC, CC, 3 * CC, 3 * CC);
        rmsnorm_qk<<<dim3((MM * HH * 2 * 64) / 256), 256, 0, stream>>>(qkv, gq, gk);
        flash_fp32<<<dim3(LL / 64, HH, BB), 256, 0, stream>>>(qkv);
        gemm_bias<<<dim3(CC / Bn, MM / Bb), 256, 0, stream>>>(
            qkv, Wout, bout, out, MM, CC, CC, 3 * CC, CC, CC);
    }
}

// Round 6
// 393.646 us; speedup vs baseline: 4.8332x; 1.1027x over previous
//
#include <hip/hip_runtime.h>
#include <math.h>

// Problem constants (B=4, L=2048, C=1024, H=16, D=64)
#define BB 4
#define LL 2048
#define CC 1024
#define HH 16
#define DD 64
#define MM (BB * LL) // 8192 rows

typedef float f32x4 __attribute__((ext_vector_type(4)));
typedef short short8 __attribute__((ext_vector_type(8))); // 8 bf16 (4 VGPRs)
typedef unsigned short ushort_t;
typedef unsigned long long u64_t;

#define MFMA_BF16(A, B, C) __builtin_amdgcn_mfma_f32_16x16x32_bf16(A, B, C, 0, 0, 0)

__device__ __forceinline__ unsigned short f2bf(float x) {
    unsigned int u = __float_as_uint(x);
    u += 0x7fffu + ((u >> 16) & 1u); // RTN-even
    return (unsigned short)(u >> 16);
}
__device__ __forceinline__ float bf2f(unsigned short h) {
    return __uint_as_float(((unsigned int)h) << 16);
}
__device__ __forceinline__ void split8(const f32x4& a, const f32x4& b,
                                       short8& h, short8& l) {
#pragma unroll
    for (int j = 0; j < 4; ++j) {
        unsigned short ha = f2bf(a[j]);
        h[j] = (short)ha; l[j] = (short)f2bf(a[j] - bf2f(ha));
        unsigned short hb = f2bf(b[j]);
        h[4 + j] = (short)hb; l[4 + j] = (short)f2bf(b[j] - bf2f(hb));
    }
}

// ---------------------------------------------------------------------------
// Elementwise f32 -> bf16 hi/lo split (for x).
// ---------------------------------------------------------------------------
__global__ __launch_bounds__(256)
void split_bf16(const float* __restrict__ src, ushort_t* __restrict__ hi,
                ushort_t* __restrict__ lo, int n)
{
    const int i = (blockIdx.x * 256 + threadIdx.x) * 8;
    if (i >= n) return;
    f32x4 a = *(const f32x4*)(src + i);
    f32x4 b = *(const f32x4*)(src + i + 4);
    short8 h, l;
    split8(a, b, h, l);
    *(short8*)(hi + i) = h;
    *(short8*)(lo + i) = l;
}

// ---------------------------------------------------------------------------
// Transpose + hi/lo split: W[K][N] f32 row-major -> WT[N][K] bf16 hi & lo.
// ---------------------------------------------------------------------------
__global__ __launch_bounds__(256)
void transp_split(const float* __restrict__ W, ushort_t* __restrict__ Th,
                  ushort_t* __restrict__ Tl, int K, int N)
{
    __shared__ float sT[64][65];
    const int k0 = blockIdx.y * 64, n0 = blockIdx.x * 64;
    const int tid = threadIdx.x;
    const int r = tid >> 2, c0 = (tid & 3) * 16;

    const float* wp = W + (size_t)(k0 + r) * N + n0 + c0;
#pragma unroll
    for (int u = 0; u < 4; ++u) {
        f32x4 v = *(const f32x4*)(wp + 4 * u);
        sT[r][c0 + 4 * u + 0] = v[0];
        sT[r][c0 + 4 * u + 1] = v[1];
        sT[r][c0 + 4 * u + 2] = v[2];
        sT[r][c0 + 4 * u + 3] = v[3];
    }
    __syncthreads();

    const int nn = tid >> 2, kk0 = (tid & 3) * 16;
    short8 h0, h1, l0, l1;
#pragma unroll
    for (int u = 0; u < 8; ++u) {
        float x = sT[kk0 + u][nn];
        unsigned short hh = f2bf(x);
        h0[u] = (short)hh; l0[u] = (short)f2bf(x - bf2f(hh));
        float y = sT[kk0 + 8 + u][nn];
        unsigned short hy = f2bf(y);
        h1[u] = (short)hy; l1[u] = (short)f2bf(y - bf2f(hy));
    }
    ushort_t* oh = Th + (size_t)(n0 + nn) * K + k0 + kk0;
    ushort_t* ol = Tl + (size_t)(n0 + nn) * K + k0 + kk0;
    *(short8*)oh = h0; *(short8*)(oh + 8) = h1;
    *(short8*)ol = l0; *(short8*)(ol + 8) = l1;
}

// ---------------------------------------------------------------------------
// Fused QKV GEMM: qkv = x @ Wqkv + bqkv, epilogue: rmsnorm q->Qb f32,
// rmsnorm k->bf16 hi/lo [b][h][l][d], v->bf16 hi only, transposed [b][h][d][l].
// ---------------------------------------------------------------------------
template<int AF32>
__global__ __launch_bounds__(256, 2)
void gemm_qkv(const float* __restrict__ Af,
              const ushort_t* __restrict__ Agh, const ushort_t* __restrict__ Agl,
              const ushort_t* __restrict__ Bh, const ushort_t* __restrict__ Bl,
              const float* __restrict__ bias,
              const float* __restrict__ gq, const float* __restrict__ gk,
              float* __restrict__ Qb,
              ushort_t* __restrict__ Kh, ushort_t* __restrict__ Kl,
              ushort_t* __restrict__ Vth)
{
    __shared__ ushort_t smem[32768]; // 64 KB
    ushort_t* sAh = smem;
    ushort_t* sAl = smem + 8192;
    ushort_t* sBh = smem + 16384;
    ushort_t* sBl = smem + 24576;

    const int K = CC, lda = CC, nbx = (3 * CC) / 128; // 24

    const int nwg = gridDim.x;
    const int cpx = nwg >> 3;
    const int id  = blockIdx.x;
    const int swz = (id & 7) * cpx + (id >> 3);
    const int bx = swz % nbx, by = swz / nbx;
    const int m0 = by * 128, n0 = bx * 128;

    const int tid  = threadIdx.x;
    const int lane = tid & 63;
    const int wv   = tid >> 6;
    const int l4   = lane >> 4, l16 = lane & 15;
    const int wm   = wv >> 1,  wn  = wv & 1;

    const int r0  = tid >> 2;
    const int c0  = (tid & 3) * 16;
    const int ch0 = c0 >> 3;

    f32x4 acc[4][4];
#pragma unroll
    for (int i = 0; i < 4; ++i)
#pragma unroll
        for (int j = 0; j < 4; ++j) acc[i][j] = 0.f;

    for (int kt = 0; kt < K; kt += 64) {
        __syncthreads();
#pragma unroll
        for (int it = 0; it < 2; ++it) {
            const int row  = r0 + 64 * it;
            const int sA   = row & 7;
            const int base = row * 64;
            const int cA = ((ch0) ^ sA) * 8, cB = ((ch0 + 1) ^ sA) * 8;

            if constexpr (AF32) {
                const float* ap = Af + (size_t)(m0 + row) * lda + kt + c0;
                f32x4 v0 = *(const f32x4*)(ap);
                f32x4 v1 = *(const f32x4*)(ap + 4);
                f32x4 v2 = *(const f32x4*)(ap + 8);
                f32x4 v3 = *(const f32x4*)(ap + 12);
                short8 h0, l0, h1, l1;
                split8(v0, v1, h0, l0);
                split8(v2, v3, h1, l1);
                *(short8*)&sAh[base + cA] = h0;
                *(short8*)&sAh[base + cB] = h1;
                *(short8*)&sAl[base + cA] = l0;
                *(short8*)&sAl[base + cB] = l1;
            } else {
                const ushort_t* ahp = Agh + (size_t)(m0 + row) * lda + kt + c0;
                const ushort_t* alp = Agl + (size_t)(m0 + row) * lda + kt + c0;
                *(short8*)&sAh[base + cA] = *(const short8*)(ahp);
                *(short8*)&sAh[base + cB] = *(const short8*)(ahp + 8);
                *(short8*)&sAl[base + cA] = *(const short8*)(alp);
                *(short8*)&sAl[base + cB] = *(const short8*)(alp + 8);
            }
            const ushort_t* bhp = Bh + (size_t)(n0 + row) * K + kt + c0;
            const ushort_t* blp = Bl + (size_t)(n0 + row) * K + kt + c0;
            *(short8*)&sBh[base + cA] = *(const short8*)(bhp);
            *(short8*)&sBh[base + cB] = *(const short8*)(bhp + 8);
            *(short8*)&sBl[base + cA] = *(const short8*)(blp);
            *(short8*)&sBl[base + cB] = *(const short8*)(blp + 8);
        }
        __syncthreads();

#pragma unroll
        for (int ks = 0; ks < 2; ++ks) {
            const int chf = (((ks << 2) | l4) ^ (l16 & 7)) * 8;
            short8 fbh[4], fbl[4];
#pragma unroll
            for (int j = 0; j < 4; ++j) {
                const int idx = (64 * wn + 16 * j + l16) * 64 + chf;
                fbh[j] = *(const short8*)&sBh[idx];
                fbl[j] = *(const short8*)&sBl[idx];
            }
#pragma unroll
            for (int i = 0; i < 4; ++i) {
                const int idx = (64 * wm + 16 * i + l16) * 64 + chf;
                short8 fah = *(const short8*)&sAh[idx];
                short8 fal = *(const short8*)&sAl[idx];
#pragma unroll
                for (int j = 0; j < 4; ++j) {
                    acc[i][j] = MFMA_BF16(fah, fbh[j], acc[i][j]);
                    acc[i][j] = MFMA_BF16(fal, fbh[j], acc[i][j]);
                    acc[i][j] = MFMA_BF16(fah, fbl[j], acc[i][j]);
                }
            }
        }
    }

    // ---- epilogue -------------------------------------------------------
    const int region = n0 >> 10; // 0=q, 1=k, 2=v
    float bv[4];
#pragma unroll
    for (int j = 0; j < 4; ++j) bv[j] = bias[n0 + 64 * wn + 16 * j + l16];
#pragma unroll
    for (int i = 0; i < 4; ++i)
#pragma unroll
        for (int j = 0; j < 4; ++j)
#pragma unroll
            for (int r = 0; r < 4; ++r) acc[i][j][r] += bv[j];

    const int b = m0 >> 11;

    if (region < 2) {
        const int hloc = ((n0 & 1023) >> 6) + wn;
        const float* g = (region == 0 ? gq : gk) + hloc * DD;
        float gv[4];
#pragma unroll
        for (int j = 0; j < 4; ++j) gv[j] = g[16 * j + l16];
#pragma unroll
        for (int i = 0; i < 4; ++i)
#pragma unroll
        for (int r = 0; r < 4; ++r) {
            float ss = 0.f;
#pragma unroll
            for (int j = 0; j < 4; ++j) ss += acc[i][j][r] * acc[i][j][r];
#pragma unroll
            for (int off = 1; off < 16; off <<= 1) ss += __shfl_xor(ss, off);
            const float s = 8.0f / fmaxf(sqrtf(ss), 1e-12f);
#pragma unroll
            for (int j = 0; j < 4; ++j) acc[i][j][r] *= s * gv[j];
        }

        if (region == 0) {
#pragma unroll
            for (int i = 0; i < 4; ++i)
#pragma unroll
            for (int r = 0; r < 4; ++r) {
                const int row = m0 + 64 * wm + 16 * i + 4 * l4 + r;
                float* op = Qb + (size_t)row * CC + n0 + 64 * wn + l16;
#pragma unroll
                for (int j = 0; j < 4; ++j) op[16 * j] = acc[i][j][r];
            }
        } else {
            const int hk = ((n0 - 1024) >> 6) + wn;
#pragma unroll
            for (int i = 0; i < 4; ++i)
#pragma unroll
            for (int r = 0; r < 4; ++r) {
                const int l = (m0 & 2047) + 64 * wm + 16 * i + 4 * l4 + r;
                const size_t base = ((size_t)(b * HH + hk) * LL + l) * DD + l16;
#pragma unroll
                for (int j = 0; j < 4; ++j) {
                    float v = acc[i][j][r];
                    unsigned short hh = f2bf(v);
                    Kh[base + 16 * j] = hh;
                    Kl[base + 16 * j] = f2bf(v - bf2f(hh));
                }
            }
        }
    } else {
        // V: bf16 hi-only + 128x128 LDS transpose + vector store to [b][h][d][l]
        __syncthreads();
        ushort_t* vh = smem; // [128][128] = 32 KB
#pragma unroll
        for (int i = 0; i < 4; ++i)
#pragma unroll
        for (int r = 0; r < 4; ++r) {
            const int lr = 64 * wm + 16 * i + 4 * l4 + r;
#pragma unroll
            for (int j = 0; j < 4; ++j) {
                const int c = 64 * wn + 16 * j + l16;
                vh[lr * 128 + c] = f2bf(acc[i][j][r]);
            }
        }
        __syncthreads();
        const int c    = tid & 127;
        const int half = tid >> 7;
        const int hv   = ((n0 - 2048) >> 6) + (c >> 6);
        const int d    = c & 63;
        ushort_t* oh = Vth + ((size_t)(b * HH + hv) * DD + d) * LL + (m0 & 2047) + half * 64;
#pragma unroll
        for (int u = 0; u < 8; ++u) {
            const int l0 = half * 64 + u * 8;
            short8 hv8;
#pragma unroll
            for (int e = 0; e < 8; ++e)
                hv8[e] = (short)vh[(l0 + e) * 128 + c];
            *(short8*)&oh[u * 8] = hv8;
        }
    }
}

// ---------------------------------------------------------------------------
// MFMA GEMM (plain bias epilogue) — output projection.
// ---------------------------------------------------------------------------
template<int AF32>
__global__ __launch_bounds__(256, 2)
void gemm_mfma(const float* __restrict__ Af,
               const ushort_t* __restrict__ Agh, const ushort_t* __restrict__ Agl,
               const ushort_t* __restrict__ Bh, const ushort_t* __restrict__ Bl,
               const float* __restrict__ bias, float* __restrict__ Cg,
               int K, int lda, int ldc, int nbx)
{
    __shared__ ushort_t sAh[128 * 64];
    __shared__ ushort_t sAl[128 * 64];
    __shared__ ushort_t sBh[128 * 64];
    __shared__ ushort_t sBl[128 * 64];

    const int nwg = gridDim.x;
    const int cpx = nwg >> 3;
    const int id  = blockIdx.x;
    const int sw  = (id & 7) * cpx + (id >> 3);
    const int bx = sw % nbx, by = sw / nbx;
    const int m0 = by * 128, n0 = bx * 128;

    const int tid  = threadIdx.x;
    const int lane = tid & 63;
    const int wv   = tid >> 6;
    const int l4   = lane >> 4, l16 = lane & 15;
    const int wm   = wv >> 1,  wn  = wv & 1;

    const int r0  = tid >> 2;
    const int c0  = (tid & 3) * 16;
    const int ch0 = c0 >> 3;

    f32x4 acc[4][4];
#pragma unroll
    for (int i = 0; i < 4; ++i)
#pragma unroll
        for (int j = 0; j < 4; ++j) acc[i][j] = 0.f;

    for (int kt = 0; kt < K; kt += 64) {
        __syncthreads();
#pragma unroll
        for (int it = 0; it < 2; ++it) {
            const int row  = r0 + 64 * it;
            const int sA   = row & 7;
            const int base = row * 64;
            const int cA = ((ch0) ^ sA) * 8, cB = ((ch0 + 1) ^ sA) * 8;

            if constexpr (AF32) {
                const float* ap = Af + (size_t)(m0 + row) * lda + kt + c0;
                f32x4 v0 = *(const f32x4*)(ap);
                f32x4 v1 = *(const f32x4*)(ap + 4);
                f32x4 v2 = *(const f32x4*)(ap + 8);
                f32x4 v3 = *(const f32x4*)(ap + 12);
                short8 h0, l0, h1, l1;
                split8(v0, v1, h0, l0);
                split8(v2, v3, h1, l1);
                *(short8*)&sAh[base + cA] = h0;
                *(short8*)&sAh[base + cB] = h1;
                *(short8*)&sAl[base + cA] = l0;
                *(short8*)&sAl[base + cB] = l1;
            } else {
                const ushort_t* ahp = Agh + (size_t)(m0 + row) * lda + kt + c0;
                const ushort_t* alp = Agl + (size_t)(m0 + row) * lda + kt + c0;
                *(short8*)&sAh[base + cA] = *(const short8*)(ahp);
                *(short8*)&sAh[base + cB] = *(const short8*)(ahp + 8);
                *(short8*)&sAl[base + cA] = *(const short8*)(alp);
                *(short8*)&sAl[base + cB] = *(const short8*)(alp + 8);
            }
            const ushort_t* bhp = Bh + (size_t)(n0 + row) * K + kt + c0;
            const ushort_t* blp = Bl + (size_t)(n0 + row) * K + kt + c0;
            *(short8*)&sBh[base + cA] = *(const short8*)(bhp);
            *(short8*)&sBh[base + cB] = *(const short8*)(bhp + 8);
            *(short8*)&sBl[base + cA] = *(const short8*)(blp);
            *(short8*)&sBl[base + cB] = *(const short8*)(blp + 8);
        }
        __syncthreads();

#pragma unroll
        for (int ks = 0; ks < 2; ++ks) {
            const int chf = (((ks << 2) | l4) ^ (l16 & 7)) * 8;
            short8 fbh[4], fbl[4];
#pragma unroll
            for (int j = 0; j < 4; ++j) {
                const int idx = (64 * wn + 16 * j + l16) * 64 + chf;
                fbh[j] = *(const short8*)&sBh[idx];
                fbl[j] = *(const short8*)&sBl[idx];
            }
#pragma unroll
            for (int i = 0; i < 4; ++i) {
                const int idx = (64 * wm + 16 * i + l16) * 64 + chf;
                short8 fah = *(const short8*)&sAh[idx];
                short8 fal = *(const short8*)&sAl[idx];
#pragma unroll
                for (int j = 0; j < 4; ++j) {
                    acc[i][j] = MFMA_BF16(fah, fbh[j], acc[i][j]);
                    acc[i][j] = MFMA_BF16(fal, fbh[j], acc[i][j]);
                    acc[i][j] = MFMA_BF16(fah, fbl[j], acc[i][j]);
                }
            }
        }
    }

    float bv[4];
#pragma unroll
    for (int j = 0; j < 4; ++j) bv[j] = bias[n0 + 64 * wn + 16 * j + l16];
#pragma unroll
    for (int i = 0; i < 4; ++i)
#pragma unroll
    for (int r = 0; r < 4; ++r) {
        const int row = m0 + 64 * wm + 16 * i + 4 * l4 + r;
        float* cp = Cg + (size_t)row * ldc + n0 + 64 * wn + l16;
#pragma unroll
        for (int j = 0; j < 4; ++j) cp[16 * j] = acc[i][j][r] + bv[j];
    }
}

// ---------------------------------------------------------------------------
// Flash attention v4: swapped QK^T, lane-local softmax, P hi-only bf16,
// V hi-only (PV 1-term). LDS 41 KB -> 3 blocks/CU. Defer-max (THR=8).
// ---------------------------------------------------------------------------
__global__ __launch_bounds__(256, 3)
void flash4(float* __restrict__ Qb,
            const ushort_t* __restrict__ Kh, const ushort_t* __restrict__ Kl,
            const ushort_t* __restrict__ Vth)
{
    __shared__ ushort_t sKh[4096], sKl[4096], sVh[4096]; // 24 KB
    __shared__ ushort_t sP[4][32 * 68];                  // 17 KB

    const int i    = blockIdx.x;
    const int xcd  = i & 7;
    const int slot = i >> 3;
    const int qt   = slot & 15;
    const int bh   = ((slot >> 4) << 3) | xcd;
    const int b    = bh >> 4, h = bh & 15;

    const int tid  = threadIdx.x;
    const int lane = tid & 63;
    const int wv   = tid >> 6;
    const int l4   = lane >> 4, l16 = lane & 15;

    // ---- Q fragments (x 1/sqrt(D)), 2 q-frags per wave (B-operand)
    short8 qh[2][2], ql[2][2];
    const int qr0 = qt * 128 + wv * 32;
#pragma unroll
    for (int qf = 0; qf < 2; ++qf)
#pragma unroll
    for (int sl = 0; sl < 2; ++sl) {
        const float* qp = Qb + (size_t)(b * LL + qr0 + qf * 16 + l16) * CC
                             + h * DD + sl * 32 + l4 * 8;
        f32x4 a = *(const f32x4*)qp;
        f32x4 c = *(const f32x4*)(qp + 4);
#pragma unroll
        for (int j = 0; j < 4; ++j) { a[j] *= 0.125f; c[j] *= 0.125f; }
        split8(a, c, qh[qf][sl], ql[qf][sl]);
    }

    f32x4 O[2][4];
    float mrow[2], lrow[2]; // state for q-row (qf*16 + l16), replicated over l4
#pragma unroll
    for (int qf = 0; qf < 2; ++qf) {
        mrow[qf] = -INFINITY; lrow[qf] = 0.f;
#pragma unroll
        for (int t = 0; t < 4; ++t) O[qf][t] = 0.f;
    }

    const int r_ = tid >> 2;          // staging row 0..63
    const int c2 = (tid & 3) * 2;     // chunk pair

    short8 stg[6];
    {
        const size_t kgb = ((size_t)bh * LL + r_) * DD + c2 * 8;
        const size_t vgb = ((size_t)bh * DD + r_) * LL + c2 * 8;
        stg[0] = *(const short8*)&Kh[kgb];  stg[1] = *(const short8*)&Kh[kgb + 8];
        stg[2] = *(const short8*)&Kl[kgb];  stg[3] = *(const short8*)&Kl[kgb + 8];
        stg[4] = *(const short8*)&Vth[vgb]; stg[5] = *(const short8*)&Vth[vgb + 8];
    }

    for (int kt = 0; kt < LL / 64; ++kt) {
        __syncthreads(); // previous tile fully consumed
        {
            const int wr = r_ * 64, s = r_ & 7;
            const int cA = ((c2) ^ s) * 8, cB = ((c2 + 1) ^ s) * 8;
            *(short8*)&sKh[wr + cA] = stg[0];
            *(short8*)&sKh[wr + cB] = stg[1];
            *(short8*)&sKl[wr + cA] = stg[2];
            *(short8*)&sKl[wr + cB] = stg[3];
            *(short8*)&sVh[wr + cA] = stg[4];
            *(short8*)&sVh[wr + cB] = stg[5];
        }
        __syncthreads();
        if (kt + 1 < LL / 64) { // prefetch next tile into regs
            const size_t kgb = ((size_t)bh * LL + (kt + 1) * 64 + r_) * DD + c2 * 8;
            const size_t vgb = ((size_t)bh * DD + r_) * LL + (kt + 1) * 64 + c2 * 8;
            stg[0] = *(const short8*)&Kh[kgb];  stg[1] = *(const short8*)&Kh[kgb + 8];
            stg[2] = *(const short8*)&Kl[kgb];  stg[3] = *(const short8*)&Kl[kgb + 8];
            stg[4] = *(const short8*)&Vth[vgb]; stg[5] = *(const short8*)&Vth[vgb + 8];
        }

        // ---- S^T = K Q : rows k (4*l4+r per tile t), cols q (l16)
        f32x4 S[2][4];
#pragma unroll
        for (int qf = 0; qf < 2; ++qf)
#pragma unroll
        for (int t = 0; t < 4; ++t) S[qf][t] = 0.f;

        __builtin_amdgcn_s_setprio(1);
#pragma unroll
        for (int t = 0; t < 4; ++t) {
            const int row = 16 * t + l16;
            const int swr = row & 7;
#pragma unroll
            for (int sl = 0; sl < 2; ++sl) {
                const int idx = row * 64 + (((sl << 2) | l4) ^ swr) * 8;
                short8 kh8 = *(const short8*)&sKh[idx];
                short8 kl8 = *(const short8*)&sKl[idx];
#pragma unroll
                for (int qf = 0; qf < 2; ++qf) {
                    S[qf][t] = MFMA_BF16(kh8, qh[qf][sl], S[qf][t]);
                    S[qf][t] = MFMA_BF16(kh8, ql[qf][sl], S[qf][t]);
                    S[qf][t] = MFMA_BF16(kl8, qh[qf][sl], S[qf][t]);
                }
            }
        }
        __builtin_amdgcn_s_setprio(0);

        // ---- lane-local softmax (each lane owns row q = qf*16+l16, 16 ks)
#pragma unroll
        for (int qf = 0; qf < 2; ++qf) {
            float pm = S[qf][0][0];
#pragma unroll
            for (int t = 0; t < 4; ++t)
#pragma unroll
                for (int r = 0; r < 4; ++r) pm = fmaxf(pm, S[qf][t][r]);
            pm = fmaxf(pm, __shfl_xor(pm, 16));
            pm = fmaxf(pm, __shfl_xor(pm, 32));

            if (__any(pm > mrow[qf] + 8.f)) { // rescale (rare after tile 0)
                const float mnew = fmaxf(mrow[qf], pm);
                const float corr = __expf(mrow[qf] - mnew);
                mrow[qf] = mnew;
                lrow[qf] *= corr;
                float c0 = __shfl(corr, 4 * l4 + 0);
                float c1 = __shfl(corr, 4 * l4 + 1);
                float c2v = __shfl(corr, 4 * l4 + 2);
                float c3 = __shfl(corr, 4 * l4 + 3);
#pragma unroll
                for (int dt = 0; dt < 4; ++dt) {
                    O[qf][dt][0] *= c0; O[qf][dt][1] *= c1;
                    O[qf][dt][2] *= c2v; O[qf][dt][3] *= c3;
                }
            }
            float rs = 0.f;
#pragma unroll
            for (int t = 0; t < 4; ++t)
#pragma unroll
                for (int r = 0; r < 4; ++r) {
                    float p = __expf(S[qf][t][r] - mrow[qf]);
                    S[qf][t][r] = p;
                    rs += p;
                }
            rs += __shfl_xor(rs, 16);
            rs += __shfl_xor(rs, 32);
            lrow[qf] += rs;
        }

        // ---- P -> per-wave LDS (bf16 hi-only), vector b64 writes
#pragma unroll
        for (int qf = 0; qf < 2; ++qf)
#pragma unroll
        for (int t = 0; t < 4; ++t) {
            unsigned lo = (unsigned)f2bf(S[qf][t][0]) | ((unsigned)f2bf(S[qf][t][1]) << 16);
            unsigned hi = (unsigned)f2bf(S[qf][t][2]) | ((unsigned)f2bf(S[qf][t][3]) << 16);
            const int widx = (qf * 16 + l16) * 68 + 16 * t + 4 * l4;
            *(u64_t*)&sP[wv][widx] = (u64_t)lo | ((u64_t)hi << 32);
        }
        asm volatile("s_waitcnt lgkmcnt(0)" ::: "memory");
        __builtin_amdgcn_sched_barrier(0);

        // ---- P A-fragments: row q = l16, k = sl*32 + 8*l4 + j
        short8 pa[2][2];
#pragma unroll
        for (int qf = 0; qf < 2; ++qf)
#pragma unroll
        for (int sl = 0; sl < 2; ++sl) {
            const int ridx = (qf * 16 + l16) * 68 + sl * 32 + 8 * l4;
            union { u64_t q[2]; short8 s8; } u;
            u.q[0] = *(const u64_t*)&sP[wv][ridx];
            u.q[1] = *(const u64_t*)&sP[wv][ridx + 4];
            pa[qf][sl] = u.s8;
        }

        // ---- O += P V (P hi-only; V hi-only)
        __builtin_amdgcn_s_setprio(1);
#pragma unroll
        for (int dt = 0; dt < 4; ++dt) {
            const int row = 16 * dt + l16;
            const int swr = row & 7;
#pragma unroll
            for (int sl = 0; sl < 2; ++sl) {
                const int idx = row * 64 + (((sl << 2) | l4) ^ swr) * 8;
                short8 vh8 = *(const short8*)&sVh[idx];
#pragma unroll
                for (int qf = 0; qf < 2; ++qf)
                    O[qf][dt] = MFMA_BF16(pa[qf][sl], vh8, O[qf][dt]);
            }
        }
        __builtin_amdgcn_s_setprio(0);
    }

    // ---- epilogue: h = O / l over Qbuf rows (unique owner)
#pragma unroll
    for (int qf = 0; qf < 2; ++qf) {
        const float inv = 1.0f / lrow[qf];
        float i0 = __shfl(inv, 4 * l4 + 0);
        float i1 = __shfl(inv, 4 * l4 + 1);
        float i2 = __shfl(inv, 4 * l4 + 2);
        float i3 = __shfl(inv, 4 * l4 + 3);
        f32x4 iv; iv[0] = i0; iv[1] = i1; iv[2] = i2; iv[3] = i3;
#pragma unroll
        for (int r = 0; r < 4; ++r) {
            const int q = qr0 + qf * 16 + 4 * l4 + r;
            float* op = Qb + (size_t)(b * LL + q) * CC + h * DD + l16;
#pragma unroll
            for (int dt = 0; dt < 4; ++dt)
                op[16 * dt] = O[qf][dt][r] * iv[r];
        }
    }
}

// ---------------------------------------------------------------------------
// Legacy fp32 fallback kernels (only if ws_size is too small; never expected)
// ---------------------------------------------------------------------------
#define Bb 128
#define Bn 128
#define BKG 8

__global__ __launch_bounds__(256)
void gemm_bias(const float* __restrict__ A, const float* __restrict__ B,
               const float* __restrict__ bias, float* __restrict__ C,
               int M, int N, int K, int lda, int ldb, int ldc)
{
    __shared__ float As[BKG][Bb];
    __shared__ float Bs[BKG][Bn];

    const int tid = threadIdx.x;
    const int m0 = blockIdx.y * Bb;
    const int n0 = blockIdx.x * Bn;
    const int ty = tid >> 4, tx = tid & 15;
    const int arow = tid >> 1, acol = (tid & 1) * 4;
    const int brow = tid >> 5, bcol = (tid & 31) * 4;

    const float* Ap = A + (size_t)(m0 + arow) * lda + acol;
    const float* Bp = B + (size_t)brow * ldb + n0 + bcol;

    float acc[8][8];
#pragma unroll
    for (int i = 0; i < 8; ++i)
#pragma unroll
        for (int j = 0; j < 8; ++j) acc[i][j] = 0.f;

    for (int k0 = 0; k0 < K; k0 += BKG) {
        float4 av = *(const float4*)(Ap + k0);
        float4 bv = *(const float4*)(Bp + (size_t)k0 * ldb);
        __syncthreads();
        As[acol + 0][arow] = av.x;
        As[acol + 1][arow] = av.y;
        As[acol + 2][arow] = av.z;
        As[acol + 3][arow] = av.w;
        *(float4*)&Bs[brow][bcol] = bv;
        __syncthreads();
#pragma unroll
        for (int kk = 0; kk < BKG; ++kk) {
            float a[8], bvv[8];
            *(float4*)&a[0] = *(const float4*)&As[kk][ty * 4];
            *(float4*)&a[4] = *(const float4*)&As[kk][64 + ty * 4];
            *(float4*)&bvv[0] = *(const float4*)&Bs[kk][tx * 4];
            *(float4*)&bvv[4] = *(const float4*)&Bs[kk][64 + tx * 4];
#pragma unroll
            for (int i = 0; i < 8; ++i)
#pragma unroll
                for (int j = 0; j < 8; ++j)
                    acc[i][j] = fmaf(a[i], bvv[j], acc[i][j]);
        }
    }
#pragma unroll
    for (int ih = 0; ih < 2; ++ih)
#pragma unroll
    for (int i = 0; i < 4; ++i) {
        const int m = m0 + ih * 64 + ty * 4 + i;
#pragma unroll
        for (int jh = 0; jh < 2; ++jh) {
            const int n = n0 + jh * 64 + tx * 4;
            float4 o;
            o.x = acc[ih*4+i][jh*4+0] + bias[n+0];
            o.y = acc[ih*4+i][jh*4+1] + bias[n+1];
            o.z = acc[ih*4+i][jh*4+2] + bias[n+2];
            o.w = acc[ih*4+i][jh*4+3] + bias[n+3];
            *(float4*)(C + (size_t)m * ldc + n) = o;
        }
    }
}

__global__ __launch_bounds__(256)
void rmsnorm_qk(float* __restrict__ qkv,
                const float* __restrict__ gq, const float* __restrict__ gk)
{
    const int gt    = blockIdx.x * 256 + threadIdx.x;
    const int lane  = gt & 63;
    const int wave  = gt >> 6;
    const int which = wave & 1;
    const int h     = (wave >> 1) & (HH - 1);
    const int bl    = wave >> 5;

    float* p = qkv + (size_t)bl * (3 * CC) + which * CC + h * DD + lane;
    float v = *p;
    float ss = v * v;
#pragma unroll
    for (int off = 32; off; off >>= 1) ss += __shfl_xor(ss, off);
    float nrm = fmaxf(sqrtf(ss), 1e-12f);
    const float* g = which ? gk : gq;
    *p = v * (8.0f / nrm) * g[h * DD + lane];
}

__global__ __launch_bounds__(256)
void flash_fp32(float* __restrict__ qkv)
{
    const int qt = blockIdx.x, hh = blockIdx.y, bb = blockIdx.z;

    __shared__ float Qt[DD][64];
    __shared__ float Kt[DD][64];
    __shared__ float Vs[64][DD];
    __shared__ float Ps[64][64 + 4];

    const int tid = threadIdx.x;
    const int ty = tid >> 4, tx = tid & 15;
    const size_t rs_ = 3 * CC;
    const float* qbase = qkv + ((size_t)bb * LL + (size_t)qt * 64) * rs_ + hh * DD;
    const float* kbase = qkv + (size_t)bb * LL * rs_ + CC + hh * DD;
    const float* vbase = kbase + CC;

    {
        const int r = tid >> 2, c0 = (tid & 3) * 16;
#pragma unroll
        for (int u = 0; u < 4; ++u) {
            float4 v = *(const float4*)(qbase + (size_t)r * rs_ + c0 + u * 4);
            Qt[c0 + u*4 + 0][r] = v.x; Qt[c0 + u*4 + 1][r] = v.y;
            Qt[c0 + u*4 + 2][r] = v.z; Qt[c0 + u*4 + 3][r] = v.w;
        }
    }

    float mrow[4], lrow[4], O[4][4];
#pragma unroll
    for (int i = 0; i < 4; ++i) {
        mrow[i] = -INFINITY; lrow[i] = 0.f;
#pragma unroll
        for (int j = 0; j < 4; ++j) O[i][j] = 0.f;
    }

    for (int kt = 0; kt < LL / 64; ++kt) {
        __syncthreads();
        {
            const int r = tid >> 2, c0 = (tid & 3) * 16;
            const float* kr = kbase + ((size_t)kt * 64 + r) * rs_;
            const float* vr = vbase + ((size_t)kt * 64 + r) * rs_;
#pragma unroll
            for (int u = 0; u < 4; ++u) {
                float4 kv = *(const float4*)(kr + c0 + u * 4);
                Kt[c0 + u*4 + 0][r] = kv.x; Kt[c0 + u*4 + 1][r] = kv.y;
                Kt[c0 + u*4 + 2][r] = kv.z; Kt[c0 + u*4 + 3][r] = kv.w;
                *(float4*)&Vs[r][c0 + u*4] = *(const float4*)(vr + c0 + u * 4);
            }
        }
        __syncthreads();

        float S[4][4];
#pragma unroll
        for (int i = 0; i < 4; ++i)
#pragma unroll
            for (int j = 0; j < 4; ++j) S[i][j] = 0.f;
#pragma unroll 8
        for (int d = 0; d < DD; ++d) {
            float a[4], b[4];
            *(float4*)a = *(const float4*)&Qt[d][ty * 4];
            *(float4*)b = *(const float4*)&Kt[d][tx * 4];
#pragma unroll
            for (int i = 0; i < 4; ++i)
#pragma unroll
                for (int j = 0; j < 4; ++j) S[i][j] = fmaf(a[i], b[j], S[i][j]);
        }
#pragma unroll
        for (int i = 0; i < 4; ++i) {
#pragma unroll
            for (int j = 0; j < 4; ++j) S[i][j] *= 0.125f;
            float pm = fmaxf(fmaxf(S[i][0], S[i][1]), fmaxf(S[i][2], S[i][3]));
#pragma unroll
            for (int off = 1; off < 16; off <<= 1) pm = fmaxf(pm, __shfl_xor(pm, off));
            const float mnew = fmaxf(mrow[i], pm);
            const float corr = __expf(mrow[i] - mnew);
            float rsum = 0.f;
#pragma unroll
            for (int j = 0; j < 4; ++j) { S[i][j] = __expf(S[i][j] - mnew); rsum += S[i][j]; }
#pragma unroll
            for (int off = 1; off < 16; off <<= 1) rsum += __shfl_xor(rsum, off);
            mrow[i] = mnew;
            lrow[i] = lrow[i] * corr + rsum;
#pragma unroll
            for (int j = 0; j < 4; ++j) O[i][j] *= corr;
        }
#pragma unroll
        for (int i = 0; i < 4; ++i)
            *(float4*)&Ps[ty * 4 + i][tx * 4] = *(float4*)&S[i][0];
        __syncthreads();
#pragma unroll 4
        for (int k = 0; k < 64; k += 4) {
            float a[4][4];
#pragma unroll
            for (int i = 0; i < 4; ++i)
                *(float4*)&a[i][0] = *(const float4*)&Ps[ty * 4 + i][k];
#pragma unroll
            for (int kk = 0; kk < 4; ++kk) {
                float bv[4];
                *(float4*)bv = *(const float4*)&Vs[k + kk][tx * 4];
#pragma unroll
                for (int i = 0; i < 4; ++i)
#pragma unroll
                    for (int j = 0; j < 4; ++j)
                        O[i][j] = fmaf(a[i][kk], bv[j], O[i][j]);
            }
        }
    }

    float* obase = qkv + ((size_t)bb * LL + (size_t)qt * 64) * rs_ + hh * DD;
#pragma unroll
    for (int i = 0; i < 4; ++i) {
        const float inv = 1.f / lrow[i];
        float4 o;
        o.x = O[i][0] * inv; o.y = O[i][1] * inv;
        o.z = O[i][2] * inv; o.w = O[i][3] * inv;
        *(float4*)(obase + (size_t)(ty * 4 + i) * rs_ + tx * 4) = o;
    }
}

// ---------------------------------------------------------------------------
extern "C" void kernel_launch(void* const* d_in, const int* in_sizes, int n_in,
                              void* d_out, int out_size, void* d_ws, size_t ws_size,
                              hipStream_t stream)
{
    const float* x    = (const float*)d_in[0];
    const float* Wqkv = (const float*)d_in[1];
    const float* bqkv = (const float*)d_in[2];
    const float* gq   = (const float*)d_in[3];
    const float* gk   = (const float*)d_in[4];
    const float* Wout = (const float*)d_in[5];
    const float* bout = (const float*)d_in[6];
    float* out = (float*)d_out;

    const size_t T_A = 150994944ull; // + x hi/lo split
    const size_t T_B = 117440512ull; // known-good workspace size

    if (ws_size >= T_B) {
        char* wsb = (char*)d_ws;
        float*    Qb  = (float*)wsb;                      // 32 MiB
        ushort_t* Kh  = (ushort_t*)(wsb + 33554432);      // 16 MiB
        ushort_t* Kl  = (ushort_t*)(wsb + 50331648);      // 16 MiB
        ushort_t* Vth = (ushort_t*)(wsb + 67108864);      // 16 MiB
        ushort_t* wqh = (ushort_t*)(wsb + 100663296);     // 6 MiB
        ushort_t* wql = (ushort_t*)(wsb + 106954752);
        ushort_t* woh = (ushort_t*)(wsb + 113246208);     // 2 MiB
        ushort_t* wol = (ushort_t*)(wsb + 115343360);

        transp_split<<<dim3(3 * CC / 64, CC / 64), 256, 0, stream>>>(Wqkv, wqh, wql, CC, 3 * CC);
        transp_split<<<dim3(CC / 64, CC / 64), 256, 0, stream>>>(Wout, woh, wol, CC, CC);

        if (ws_size >= T_A) {
            ushort_t* xh = (ushort_t*)(wsb + 117440512);
            ushort_t* xl = (ushort_t*)(wsb + 134217728);
            split_bf16<<<dim3(MM * CC / 8 / 256), 256, 0, stream>>>(x, xh, xl, MM * CC);
            gemm_qkv<0><<<dim3(24 * 64), 256, 0, stream>>>(
                nullptr, xh, xl, wqh, wql, bqkv, gq, gk, Qb, Kh, Kl, Vth);
        } else {
            gemm_qkv<1><<<dim3(24 * 64), 256, 0, stream>>>(
                x, nullptr, nullptr, wqh, wql, bqkv, gq, gk, Qb, Kh, Kl, Vth);
        }

        flash4<<<dim3(1024), 256, 0, stream>>>(Qb, Kh, Kl, Vth);

        gemm_mfma<1><<<dim3(8 * 64), 256, 0, stream>>>(
            Qb, nullptr, nullptr, woh, wol, bout, out, CC, CC, CC, CC / 128);
    } else {
        // legacy fp32 path
        float* qkv = (float*)d_ws;
        gemm_bias<<<dim3((3 * CC) / Bn, MM / Bb), 256, 0, stream>>>(
            x, Wqkv, bqkv, qkv, MM, 3 * CC, CC, CC, 3 * CC, 3 * CC);
        rmsnorm_qk<<<dim3((MM * HH * 2 * 64) / 256), 256, 0, stream>>>(qkv, gq, gk);
        flash_fp32<<<dim3(LL / 64, HH, BB), 256, 0, stream>>>(qkv);
        gemm_bias<<<dim3(CC / Bn, MM / Bb), 256, 0, stream>>>(
            qkv, Wout, bout, out, MM, CC, CC, 3 * CC, CC, CC);
    }
}

// Round 7
// 341.175 us; speedup vs baseline: 5.5766x; 1.1538x over previous
//
#include <hip/hip_runtime.h>
#include <math.h>

// Problem constants (B=4, L=2048, C=1024, H=16, D=64)
#define BB 4
#define LL 2048
#define CC 1024
#define HH 16
#define DD 64
#define MM (BB * LL) // 8192 rows

typedef float f32x4 __attribute__((ext_vector_type(4)));
typedef short short8 __attribute__((ext_vector_type(8))); // 8 bf16 (4 VGPRs)
typedef unsigned short ushort_t;
typedef unsigned long long u64_t;

#define MFMA_BF16(A, B, C) __builtin_amdgcn_mfma_f32_16x16x32_bf16(A, B, C, 0, 0, 0)

__device__ __forceinline__ unsigned short f2bf(float x) {
    unsigned int u = __float_as_uint(x);
    u += 0x7fffu + ((u >> 16) & 1u); // RTN-even
    return (unsigned short)(u >> 16);
}
__device__ __forceinline__ float bf2f(unsigned short h) {
    return __uint_as_float(((unsigned int)h) << 16);
}
__device__ __forceinline__ void split8(const f32x4& a, const f32x4& b,
                                       short8& h, short8& l) {
#pragma unroll
    for (int j = 0; j < 4; ++j) {
        unsigned short ha = f2bf(a[j]);
        h[j] = (short)ha; l[j] = (short)f2bf(a[j] - bf2f(ha));
        unsigned short hb = f2bf(b[j]);
        h[4 + j] = (short)hb; l[4 + j] = (short)f2bf(b[j] - bf2f(hb));
    }
}

// ---------------------------------------------------------------------------
// Elementwise f32 -> bf16 hi/lo split (for x).
// ---------------------------------------------------------------------------
__global__ __launch_bounds__(256)
void split_bf16(const float* __restrict__ src, ushort_t* __restrict__ hi,
                ushort_t* __restrict__ lo, int n)
{
    const int i = (blockIdx.x * 256 + threadIdx.x) * 8;
    if (i >= n) return;
    f32x4 a = *(const f32x4*)(src + i);
    f32x4 b = *(const f32x4*)(src + i + 4);
    short8 h, l;
    split8(a, b, h, l);
    *(short8*)(hi + i) = h;
    *(short8*)(lo + i) = l;
}

// ---------------------------------------------------------------------------
// Transpose + bf16 round (hi only): W[K][N] f32 row-major -> WT[N][K] bf16.
// ---------------------------------------------------------------------------
__global__ __launch_bounds__(256)
void transp_hi(const float* __restrict__ W, ushort_t* __restrict__ Th,
               int K, int N)
{
    __shared__ float sT[64][65];
    const int k0 = blockIdx.y * 64, n0 = blockIdx.x * 64;
    const int tid = threadIdx.x;
    const int r = tid >> 2, c0 = (tid & 3) * 16;

    const float* wp = W + (size_t)(k0 + r) * N + n0 + c0;
#pragma unroll
    for (int u = 0; u < 4; ++u) {
        f32x4 v = *(const f32x4*)(wp + 4 * u);
        sT[r][c0 + 4 * u + 0] = v[0];
        sT[r][c0 + 4 * u + 1] = v[1];
        sT[r][c0 + 4 * u + 2] = v[2];
        sT[r][c0 + 4 * u + 3] = v[3];
    }
    __syncthreads();

    const int nn = tid >> 2, kk0 = (tid & 3) * 16;
    short8 h0, h1;
#pragma unroll
    for (int u = 0; u < 8; ++u) {
        h0[u] = (short)f2bf(sT[kk0 + u][nn]);
        h1[u] = (short)f2bf(sT[kk0 + 8 + u][nn]);
    }
    ushort_t* oh = Th + (size_t)(n0 + nn) * K + k0 + kk0;
    *(short8*)oh = h0; *(short8*)(oh + 8) = h1;
}

// ---------------------------------------------------------------------------
// Fused QKV GEMM (2-term split: Ah*Bh + Al*Bh; B = bf16 weights).
// Epilogue: rmsnorm q->Qb f32, rmsnorm k->bf16 hi/lo [b][h][l][d],
// v->bf16 hi only, transposed [b][h][d][l].
// ---------------------------------------------------------------------------
template<int AF32>
__global__ __launch_bounds__(256, 3)
void gemm_qkv(const float* __restrict__ Af,
              const ushort_t* __restrict__ Agh, const ushort_t* __restrict__ Agl,
              const ushort_t* __restrict__ Bh,
              const float* __restrict__ bias,
              const float* __restrict__ gq, const float* __restrict__ gk,
              float* __restrict__ Qb,
              ushort_t* __restrict__ Kh, ushort_t* __restrict__ Kl,
              ushort_t* __restrict__ Vth)
{
    __shared__ ushort_t smem[24576]; // 48 KB
    ushort_t* sAh = smem;
    ushort_t* sAl = smem + 8192;
    ushort_t* sBh = smem + 16384;

    const int K = CC, lda = CC, nbx = (3 * CC) / 128; // 24

    const int nwg = gridDim.x;
    const int cpx = nwg >> 3;
    const int id  = blockIdx.x;
    const int swz = (id & 7) * cpx + (id >> 3);
    const int bx = swz % nbx, by = swz / nbx;
    const int m0 = by * 128, n0 = bx * 128;

    const int tid  = threadIdx.x;
    const int lane = tid & 63;
    const int wv   = tid >> 6;
    const int l4   = lane >> 4, l16 = lane & 15;
    const int wm   = wv >> 1,  wn  = wv & 1;

    const int r0  = tid >> 2;
    const int c0  = (tid & 3) * 16;
    const int ch0 = c0 >> 3;

    f32x4 acc[4][4];
#pragma unroll
    for (int i = 0; i < 4; ++i)
#pragma unroll
        for (int j = 0; j < 4; ++j) acc[i][j] = 0.f;

    for (int kt = 0; kt < K; kt += 64) {
        __syncthreads();
#pragma unroll
        for (int it = 0; it < 2; ++it) {
            const int row  = r0 + 64 * it;
            const int sA   = row & 7;
            const int base = row * 64;
            const int cA = ((ch0) ^ sA) * 8, cB = ((ch0 + 1) ^ sA) * 8;

            if constexpr (AF32) {
                const float* ap = Af + (size_t)(m0 + row) * lda + kt + c0;
                f32x4 v0 = *(const f32x4*)(ap);
                f32x4 v1 = *(const f32x4*)(ap + 4);
                f32x4 v2 = *(const f32x4*)(ap + 8);
                f32x4 v3 = *(const f32x4*)(ap + 12);
                short8 h0, l0, h1, l1;
                split8(v0, v1, h0, l0);
                split8(v2, v3, h1, l1);
                *(short8*)&sAh[base + cA] = h0;
                *(short8*)&sAh[base + cB] = h1;
                *(short8*)&sAl[base + cA] = l0;
                *(short8*)&sAl[base + cB] = l1;
            } else {
                const ushort_t* ahp = Agh + (size_t)(m0 + row) * lda + kt + c0;
                const ushort_t* alp = Agl + (size_t)(m0 + row) * lda + kt + c0;
                *(short8*)&sAh[base + cA] = *(const short8*)(ahp);
                *(short8*)&sAh[base + cB] = *(const short8*)(ahp + 8);
                *(short8*)&sAl[base + cA] = *(const short8*)(alp);
                *(short8*)&sAl[base + cB] = *(const short8*)(alp + 8);
            }
            const ushort_t* bhp = Bh + (size_t)(n0 + row) * K + kt + c0;
            *(short8*)&sBh[base + cA] = *(const short8*)(bhp);
            *(short8*)&sBh[base + cB] = *(const short8*)(bhp + 8);
        }
        __syncthreads();

#pragma unroll
        for (int ks = 0; ks < 2; ++ks) {
            const int chf = (((ks << 2) | l4) ^ (l16 & 7)) * 8;
            short8 fbh[4];
#pragma unroll
            for (int j = 0; j < 4; ++j) {
                const int idx = (64 * wn + 16 * j + l16) * 64 + chf;
                fbh[j] = *(const short8*)&sBh[idx];
            }
#pragma unroll
            for (int i = 0; i < 4; ++i) {
                const int idx = (64 * wm + 16 * i + l16) * 64 + chf;
                short8 fah = *(const short8*)&sAh[idx];
                short8 fal = *(const short8*)&sAl[idx];
#pragma unroll
                for (int j = 0; j < 4; ++j) {
                    acc[i][j] = MFMA_BF16(fah, fbh[j], acc[i][j]);
                    acc[i][j] = MFMA_BF16(fal, fbh[j], acc[i][j]);
                }
            }
        }
    }

    // ---- epilogue -------------------------------------------------------
    const int region = n0 >> 10; // 0=q, 1=k, 2=v
    float bv[4];
#pragma unroll
    for (int j = 0; j < 4; ++j) bv[j] = bias[n0 + 64 * wn + 16 * j + l16];
#pragma unroll
    for (int i = 0; i < 4; ++i)
#pragma unroll
        for (int j = 0; j < 4; ++j)
#pragma unroll
            for (int r = 0; r < 4; ++r) acc[i][j][r] += bv[j];

    const int b = m0 >> 11;

    if (region < 2) {
        const int hloc = ((n0 & 1023) >> 6) + wn;
        const float* g = (region == 0 ? gq : gk) + hloc * DD;
        float gv[4];
#pragma unroll
        for (int j = 0; j < 4; ++j) gv[j] = g[16 * j + l16];
#pragma unroll
        for (int i = 0; i < 4; ++i)
#pragma unroll
        for (int r = 0; r < 4; ++r) {
            float ss = 0.f;
#pragma unroll
            for (int j = 0; j < 4; ++j) ss += acc[i][j][r] * acc[i][j][r];
#pragma unroll
            for (int off = 1; off < 16; off <<= 1) ss += __shfl_xor(ss, off);
            const float s = 8.0f / fmaxf(sqrtf(ss), 1e-12f);
#pragma unroll
            for (int j = 0; j < 4; ++j) acc[i][j][r] *= s * gv[j];
        }

        if (region == 0) {
#pragma unroll
            for (int i = 0; i < 4; ++i)
#pragma unroll
            for (int r = 0; r < 4; ++r) {
                const int row = m0 + 64 * wm + 16 * i + 4 * l4 + r;
                float* op = Qb + (size_t)row * CC + n0 + 64 * wn + l16;
#pragma unroll
                for (int j = 0; j < 4; ++j) op[16 * j] = acc[i][j][r];
            }
        } else {
            const int hk = ((n0 - 1024) >> 6) + wn;
#pragma unroll
            for (int i = 0; i < 4; ++i)
#pragma unroll
            for (int r = 0; r < 4; ++r) {
                const int l = (m0 & 2047) + 64 * wm + 16 * i + 4 * l4 + r;
                const size_t base = ((size_t)(b * HH + hk) * LL + l) * DD + l16;
#pragma unroll
                for (int j = 0; j < 4; ++j) {
                    float v = acc[i][j][r];
                    unsigned short hh = f2bf(v);
                    Kh[base + 16 * j] = hh;
                    Kl[base + 16 * j] = f2bf(v - bf2f(hh));
                }
            }
        }
    } else {
        // V: bf16 hi-only + 128x128 LDS transpose + vector store to [b][h][d][l]
        __syncthreads();
        ushort_t* vh = smem; // [128][128] = 32 KB (fits in 48 KB smem)
#pragma unroll
        for (int i = 0; i < 4; ++i)
#pragma unroll
        for (int r = 0; r < 4; ++r) {
            const int lr = 64 * wm + 16 * i + 4 * l4 + r;
#pragma unroll
            for (int j = 0; j < 4; ++j) {
                const int c = 64 * wn + 16 * j + l16;
                vh[lr * 128 + c] = f2bf(acc[i][j][r]);
            }
        }
        __syncthreads();
        const int c    = tid & 127;
        const int half = tid >> 7;
        const int hv   = ((n0 - 2048) >> 6) + (c >> 6);
        const int d    = c & 63;
        ushort_t* oh = Vth + ((size_t)(b * HH + hv) * DD + d) * LL + (m0 & 2047) + half * 64;
#pragma unroll
        for (int u = 0; u < 8; ++u) {
            const int l0 = half * 64 + u * 8;
            short8 hv8;
#pragma unroll
            for (int e = 0; e < 8; ++e)
                hv8[e] = (short)vh[(l0 + e) * 128 + c];
            *(short8*)&oh[u * 8] = hv8;
        }
    }
}

// ---------------------------------------------------------------------------
// MFMA GEMM (2-term split, plain bias epilogue) — output projection.
// ---------------------------------------------------------------------------
template<int AF32>
__global__ __launch_bounds__(256, 3)
void gemm_mfma(const float* __restrict__ Af,
               const ushort_t* __restrict__ Agh, const ushort_t* __restrict__ Agl,
               const ushort_t* __restrict__ Bh,
               const float* __restrict__ bias, float* __restrict__ Cg,
               int K, int lda, int ldc, int nbx)
{
    __shared__ ushort_t sAh[128 * 64];
    __shared__ ushort_t sAl[128 * 64];
    __shared__ ushort_t sBh[128 * 64];

    const int nwg = gridDim.x;
    const int cpx = nwg >> 3;
    const int id  = blockIdx.x;
    const int sw  = (id & 7) * cpx + (id >> 3);
    const int bx = sw % nbx, by = sw / nbx;
    const int m0 = by * 128, n0 = bx * 128;

    const int tid  = threadIdx.x;
    const int lane = tid & 63;
    const int wv   = tid >> 6;
    const int l4   = lane >> 4, l16 = lane & 15;
    const int wm   = wv >> 1,  wn  = wv & 1;

    const int r0  = tid >> 2;
    const int c0  = (tid & 3) * 16;
    const int ch0 = c0 >> 3;

    f32x4 acc[4][4];
#pragma unroll
    for (int i = 0; i < 4; ++i)
#pragma unroll
        for (int j = 0; j < 4; ++j) acc[i][j] = 0.f;

    for (int kt = 0; kt < K; kt += 64) {
        __syncthreads();
#pragma unroll
        for (int it = 0; it < 2; ++it) {
            const int row  = r0 + 64 * it;
            const int sA   = row & 7;
            const int base = row * 64;
            const int cA = ((ch0) ^ sA) * 8, cB = ((ch0 + 1) ^ sA) * 8;

            if constexpr (AF32) {
                const float* ap = Af + (size_t)(m0 + row) * lda + kt + c0;
                f32x4 v0 = *(const f32x4*)(ap);
                f32x4 v1 = *(const f32x4*)(ap + 4);
                f32x4 v2 = *(const f32x4*)(ap + 8);
                f32x4 v3 = *(const f32x4*)(ap + 12);
                short8 h0, l0, h1, l1;
                split8(v0, v1, h0, l0);
                split8(v2, v3, h1, l1);
                *(short8*)&sAh[base + cA] = h0;
                *(short8*)&sAh[base + cB] = h1;
                *(short8*)&sAl[base + cA] = l0;
                *(short8*)&sAl[base + cB] = l1;
            } else {
                const ushort_t* ahp = Agh + (size_t)(m0 + row) * lda + kt + c0;
                const ushort_t* alp = Agl + (size_t)(m0 + row) * lda + kt + c0;
                *(short8*)&sAh[base + cA] = *(const short8*)(ahp);
                *(short8*)&sAh[base + cB] = *(const short8*)(ahp + 8);
                *(short8*)&sAl[base + cA] = *(const short8*)(alp);
                *(short8*)&sAl[base + cB] = *(const short8*)(alp + 8);
            }
            const ushort_t* bhp = Bh + (size_t)(n0 + row) * K + kt + c0;
            *(short8*)&sBh[base + cA] = *(const short8*)(bhp);
            *(short8*)&sBh[base + cB] = *(const short8*)(bhp + 8);
        }
        __syncthreads();

#pragma unroll
        for (int ks = 0; ks < 2; ++ks) {
            const int chf = (((ks << 2) | l4) ^ (l16 & 7)) * 8;
            short8 fbh[4];
#pragma unroll
            for (int j = 0; j < 4; ++j) {
                const int idx = (64 * wn + 16 * j + l16) * 64 + chf;
                fbh[j] = *(const short8*)&sBh[idx];
            }
#pragma unroll
            for (int i = 0; i < 4; ++i) {
                const int idx = (64 * wm + 16 * i + l16) * 64 + chf;
                short8 fah = *(const short8*)&sAh[idx];
                short8 fal = *(const short8*)&sAl[idx];
#pragma unroll
                for (int j = 0; j < 4; ++j) {
                    acc[i][j] = MFMA_BF16(fah, fbh[j], acc[i][j]);
                    acc[i][j] = MFMA_BF16(fal, fbh[j], acc[i][j]);
                }
            }
        }
    }

    float bv[4];
#pragma unroll
    for (int j = 0; j < 4; ++j) bv[j] = bias[n0 + 64 * wn + 16 * j + l16];
#pragma unroll
    for (int i = 0; i < 4; ++i)
#pragma unroll
    for (int r = 0; r < 4; ++r) {
        const int row = m0 + 64 * wm + 16 * i + 4 * l4 + r;
        float* cp = Cg + (size_t)row * ldc + n0 + 64 * wn + l16;
#pragma unroll
        for (int j = 0; j < 4; ++j) cp[16 * j] = acc[i][j][r] + bv[j];
    }
}

// ---------------------------------------------------------------------------
// Flash attention v4 (unchanged from round 6): swapped QK^T, lane-local
// softmax, P hi-only bf16, V hi-only. Defer-max (THR=8).
// ---------------------------------------------------------------------------
__global__ __launch_bounds__(256, 3)
void flash4(float* __restrict__ Qb,
            const ushort_t* __restrict__ Kh, const ushort_t* __restrict__ Kl,
            const ushort_t* __restrict__ Vth)
{
    __shared__ ushort_t sKh[4096], sKl[4096], sVh[4096]; // 24 KB
    __shared__ ushort_t sP[4][32 * 68];                  // 17 KB

    const int i    = blockIdx.x;
    const int xcd  = i & 7;
    const int slot = i >> 3;
    const int qt   = slot & 15;
    const int bh   = ((slot >> 4) << 3) | xcd;
    const int b    = bh >> 4, h = bh & 15;

    const int tid  = threadIdx.x;
    const int lane = tid & 63;
    const int wv   = tid >> 6;
    const int l4   = lane >> 4, l16 = lane & 15;

    // ---- Q fragments (x 1/sqrt(D)), 2 q-frags per wave (B-operand)
    short8 qh[2][2], ql[2][2];
    const int qr0 = qt * 128 + wv * 32;
#pragma unroll
    for (int qf = 0; qf < 2; ++qf)
#pragma unroll
    for (int sl = 0; sl < 2; ++sl) {
        const float* qp = Qb + (size_t)(b * LL + qr0 + qf * 16 + l16) * CC
                             + h * DD + sl * 32 + l4 * 8;
        f32x4 a = *(const f32x4*)qp;
        f32x4 c = *(const f32x4*)(qp + 4);
#pragma unroll
        for (int j = 0; j < 4; ++j) { a[j] *= 0.125f; c[j] *= 0.125f; }
        split8(a, c, qh[qf][sl], ql[qf][sl]);
    }

    f32x4 O[2][4];
    float mrow[2], lrow[2]; // state for q-row (qf*16 + l16), replicated over l4
#pragma unroll
    for (int qf = 0; qf < 2; ++qf) {
        mrow[qf] = -INFINITY; lrow[qf] = 0.f;
#pragma unroll
        for (int t = 0; t < 4; ++t) O[qf][t] = 0.f;
    }

    const int r_ = tid >> 2;          // staging row 0..63
    const int c2 = (tid & 3) * 2;     // chunk pair

    short8 stg[6];
    {
        const size_t kgb = ((size_t)bh * LL + r_) * DD + c2 * 8;
        const size_t vgb = ((size_t)bh * DD + r_) * LL + c2 * 8;
        stg[0] = *(const short8*)&Kh[kgb];  stg[1] = *(const short8*)&Kh[kgb + 8];
        stg[2] = *(const short8*)&Kl[kgb];  stg[3] = *(const short8*)&Kl[kgb + 8];
        stg[4] = *(const short8*)&Vth[vgb]; stg[5] = *(const short8*)&Vth[vgb + 8];
    }

    for (int kt = 0; kt < LL / 64; ++kt) {
        __syncthreads(); // previous tile fully consumed
        {
            const int wr = r_ * 64, s = r_ & 7;
            const int cA = ((c2) ^ s) * 8, cB = ((c2 + 1) ^ s) * 8;
            *(short8*)&sKh[wr + cA] = stg[0];
            *(short8*)&sKh[wr + cB] = stg[1];
            *(short8*)&sKl[wr + cA] = stg[2];
            *(short8*)&sKl[wr + cB] = stg[3];
            *(short8*)&sVh[wr + cA] = stg[4];
            *(short8*)&sVh[wr + cB] = stg[5];
        }
        __syncthreads();
        if (kt + 1 < LL / 64) { // prefetch next tile into regs
            const size_t kgb = ((size_t)bh * LL + (kt + 1) * 64 + r_) * DD + c2 * 8;
            const size_t vgb = ((size_t)bh * DD + r_) * LL + (kt + 1) * 64 + c2 * 8;
            stg[0] = *(const short8*)&Kh[kgb];  stg[1] = *(const short8*)&Kh[kgb + 8];
            stg[2] = *(const short8*)&Kl[kgb];  stg[3] = *(const short8*)&Kl[kgb + 8];
            stg[4] = *(const short8*)&Vth[vgb]; stg[5] = *(const short8*)&Vth[vgb + 8];
        }

        // ---- S^T = K Q : rows k (4*l4+r per tile t), cols q (l16)
        f32x4 S[2][4];
#pragma unroll
        for (int qf = 0; qf < 2; ++qf)
#pragma unroll
        for (int t = 0; t < 4; ++t) S[qf][t] = 0.f;

        __builtin_amdgcn_s_setprio(1);
#pragma unroll
        for (int t = 0; t < 4; ++t) {
            const int row = 16 * t + l16;
            const int swr = row & 7;
#pragma unroll
            for (int sl = 0; sl < 2; ++sl) {
                const int idx = row * 64 + (((sl << 2) | l4) ^ swr) * 8;
                short8 kh8 = *(const short8*)&sKh[idx];
                short8 kl8 = *(const short8*)&sKl[idx];
#pragma unroll
                for (int qf = 0; qf < 2; ++qf) {
                    S[qf][t] = MFMA_BF16(kh8, qh[qf][sl], S[qf][t]);
                    S[qf][t] = MFMA_BF16(kh8, ql[qf][sl], S[qf][t]);
                    S[qf][t] = MFMA_BF16(kl8, qh[qf][sl], S[qf][t]);
                }
            }
        }
        __builtin_amdgcn_s_setprio(0);

        // ---- lane-local softmax (each lane owns row q = qf*16+l16, 16 ks)
#pragma unroll
        for (int qf = 0; qf < 2; ++qf) {
            float pm = S[qf][0][0];
#pragma unroll
            for (int t = 0; t < 4; ++t)
#pragma unroll
                for (int r = 0; r < 4; ++r) pm = fmaxf(pm, S[qf][t][r]);
            pm = fmaxf(pm, __shfl_xor(pm, 16));
            pm = fmaxf(pm, __shfl_xor(pm, 32));

            if (__any(pm > mrow[qf] + 8.f)) { // rescale (rare after tile 0)
                const float mnew = fmaxf(mrow[qf], pm);
                const float corr = __expf(mrow[qf] - mnew);
                mrow[qf] = mnew;
                lrow[qf] *= corr;
                float c0 = __shfl(corr, 4 * l4 + 0);
                float c1 = __shfl(corr, 4 * l4 + 1);
                float c2v = __shfl(corr, 4 * l4 + 2);
                float c3 = __shfl(corr, 4 * l4 + 3);
#pragma unroll
                for (int dt = 0; dt < 4; ++dt) {
                    O[qf][dt][0] *= c0; O[qf][dt][1] *= c1;
                    O[qf][dt][2] *= c2v; O[qf][dt][3] *= c3;
                }
            }
            float rs = 0.f;
#pragma unroll
            for (int t = 0; t < 4; ++t)
#pragma unroll
                for (int r = 0; r < 4; ++r) {
                    float p = __expf(S[qf][t][r] - mrow[qf]);
                    S[qf][t][r] = p;
                    rs += p;
                }
            rs += __shfl_xor(rs, 16);
            rs += __shfl_xor(rs, 32);
            lrow[qf] += rs;
        }

        // ---- P -> per-wave LDS (bf16 hi-only), vector b64 writes
#pragma unroll
        for (int qf = 0; qf < 2; ++qf)
#pragma unroll
        for (int t = 0; t < 4; ++t) {
            unsigned lo = (unsigned)f2bf(S[qf][t][0]) | ((unsigned)f2bf(S[qf][t][1]) << 16);
            unsigned hi = (unsigned)f2bf(S[qf][t][2]) | ((unsigned)f2bf(S[qf][t][3]) << 16);
            const int widx = (qf * 16 + l16) * 68 + 16 * t + 4 * l4;
            *(u64_t*)&sP[wv][widx] = (u64_t)lo | ((u64_t)hi << 32);
        }
        asm volatile("s_waitcnt lgkmcnt(0)" ::: "memory");
        __builtin_amdgcn_sched_barrier(0);

        // ---- P A-fragments: row q = l16, k = sl*32 + 8*l4 + j
        short8 pa[2][2];
#pragma unroll
        for (int qf = 0; qf < 2; ++qf)
#pragma unroll
        for (int sl = 0; sl < 2; ++sl) {
            const int ridx = (qf * 16 + l16) * 68 + sl * 32 + 8 * l4;
            union { u64_t q[2]; short8 s8; } u;
            u.q[0] = *(const u64_t*)&sP[wv][ridx];
            u.q[1] = *(const u64_t*)&sP[wv][ridx + 4];
            pa[qf][sl] = u.s8;
        }

        // ---- O += P V (P hi-only; V hi-only)
        __builtin_amdgcn_s_setprio(1);
#pragma unroll
        for (int dt = 0; dt < 4; ++dt) {
            const int row = 16 * dt + l16;
            const int swr = row & 7;
#pragma unroll
            for (int sl = 0; sl < 2; ++sl) {
                const int idx = row * 64 + (((sl << 2) | l4) ^ swr) * 8;
                short8 vh8 = *(const short8*)&sVh[idx];
#pragma unroll
                for (int qf = 0; qf < 2; ++qf)
                    O[qf][dt] = MFMA_BF16(pa[qf][sl], vh8, O[qf][dt]);
            }
        }
        __builtin_amdgcn_s_setprio(0);
    }

    // ---- epilogue: h = O / l over Qbuf rows (unique owner)
#pragma unroll
    for (int qf = 0; qf < 2; ++qf) {
        const float inv = 1.0f / lrow[qf];
        float i0 = __shfl(inv, 4 * l4 + 0);
        float i1 = __shfl(inv, 4 * l4 + 1);
        float i2 = __shfl(inv, 4 * l4 + 2);
        float i3 = __shfl(inv, 4 * l4 + 3);
        f32x4 iv; iv[0] = i0; iv[1] = i1; iv[2] = i2; iv[3] = i3;
#pragma unroll
        for (int r = 0; r < 4; ++r) {
            const int q = qr0 + qf * 16 + 4 * l4 + r;
            float* op = Qb + (size_t)(b * LL + q) * CC + h * DD + l16;
#pragma unroll
            for (int dt = 0; dt < 4; ++dt)
                op[16 * dt] = O[qf][dt][r] * iv[r];
        }
    }
}

// ---------------------------------------------------------------------------
// Legacy fp32 fallback kernels (only if ws_size is too small; never expected)
// ---------------------------------------------------------------------------
#define Bb 128
#define Bn 128
#define BKG 8

__global__ __launch_bounds__(256)
void gemm_bias(const float* __restrict__ A, const float* __restrict__ B,
               const float* __restrict__ bias, float* __restrict__ C,
               int M, int N, int K, int lda, int ldb, int ldc)
{
    __shared__ float As[BKG][Bb];
    __shared__ float Bs[BKG][Bn];

    const int tid = threadIdx.x;
    const int m0 = blockIdx.y * Bb;
    const int n0 = blockIdx.x * Bn;
    const int ty = tid >> 4, tx = tid & 15;
    const int arow = tid >> 1, acol = (tid & 1) * 4;
    const int brow = tid >> 5, bcol = (tid & 31) * 4;

    const float* Ap = A + (size_t)(m0 + arow) * lda + acol;
    const float* Bp = B + (size_t)brow * ldb + n0 + bcol;

    float acc[8][8];
#pragma unroll
    for (int i = 0; i < 8; ++i)
#pragma unroll
        for (int j = 0; j < 8; ++j) acc[i][j] = 0.f;

    for (int k0 = 0; k0 < K; k0 += BKG) {
        float4 av = *(const float4*)(Ap + k0);
        float4 bv = *(const float4*)(Bp + (size_t)k0 * ldb);
        __syncthreads();
        As[acol + 0][arow] = av.x;
        As[acol + 1][arow] = av.y;
        As[acol + 2][arow] = av.z;
        As[acol + 3][arow] = av.w;
        *(float4*)&Bs[brow][bcol] = bv;
        __syncthreads();
#pragma unroll
        for (int kk = 0; kk < BKG; ++kk) {
            float a[8], bvv[8];
            *(float4*)&a[0] = *(const float4*)&As[kk][ty * 4];
            *(float4*)&a[4] = *(const float4*)&As[kk][64 + ty * 4];
            *(float4*)&bvv[0] = *(const float4*)&Bs[kk][tx * 4];
            *(float4*)&bvv[4] = *(const float4*)&Bs[kk][64 + tx * 4];
#pragma unroll
            for (int i = 0; i < 8; ++i)
#pragma unroll
                for (int j = 0; j < 8; ++j)
                    acc[i][j] = fmaf(a[i], bvv[j], acc[i][j]);
        }
    }
#pragma unroll
    for (int ih = 0; ih < 2; ++ih)
#pragma unroll
    for (int i = 0; i < 4; ++i) {
        const int m = m0 + ih * 64 + ty * 4 + i;
#pragma unroll
        for (int jh = 0; jh < 2; ++jh) {
            const int n = n0 + jh * 64 + tx * 4;
            float4 o;
            o.x = acc[ih*4+i][jh*4+0] + bias[n+0];
            o.y = acc[ih*4+i][jh*4+1] + bias[n+1];
            o.z = acc[ih*4+i][jh*4+2] + bias[n+2];
            o.w = acc[ih*4+i][jh*4+3] + bias[n+3];
            *(float4*)(C + (size_t)m * ldc + n) = o;
        }
    }
}

__global__ __launch_bounds__(256)
void rmsnorm_qk(float* __restrict__ qkv,
                const float* __restrict__ gq, const float* __restrict__ gk)
{
    const int gt    = blockIdx.x * 256 + threadIdx.x;
    const int lane  = gt & 63;
    const int wave  = gt >> 6;
    const int which = wave & 1;
    const int h     = (wave >> 1) & (HH - 1);
    const int bl    = wave >> 5;

    float* p = qkv + (size_t)bl * (3 * CC) + which * CC + h * DD + lane;
    float v = *p;
    float ss = v * v;
#pragma unroll
    for (int off = 32; off; off >>= 1) ss += __shfl_xor(ss, off);
    float nrm = fmaxf(sqrtf(ss), 1e-12f);
    const float* g = which ? gk : gq;
    *p = v * (8.0f / nrm) * g[h * DD + lane];
}

__global__ __launch_bounds__(256)
void flash_fp32(float* __restrict__ qkv)
{
    const int qt = blockIdx.x, hh = blockIdx.y, bb = blockIdx.z;

    __shared__ float Qt[DD][64];
    __shared__ float Kt[DD][64];
    __shared__ float Vs[64][DD];
    __shared__ float Ps[64][64 + 4];

    const int tid = threadIdx.x;
    const int ty = tid >> 4, tx = tid & 15;
    const size_t rs_ = 3 * CC;
    const float* qbase = qkv + ((size_t)bb * LL + (size_t)qt * 64) * rs_ + hh * DD;
    const float* kbase = qkv + (size_t)bb * LL * rs_ + CC + hh * DD;
    const float* vbase = kbase + CC;

    {
        const int r = tid >> 2, c0 = (tid & 3) * 16;
#pragma unroll
        for (int u = 0; u < 4; ++u) {
            float4 v = *(const float4*)(qbase + (size_t)r * rs_ + c0 + u * 4);
            Qt[c0 + u*4 + 0][r] = v.x; Qt[c0 + u*4 + 1][r] = v.y;
            Qt[c0 + u*4 + 2][r] = v.z; Qt[c0 + u*4 + 3][r] = v.w;
        }
    }

    float mrow[4], lrow[4], O[4][4];
#pragma unroll
    for (int i = 0; i < 4; ++i) {
        mrow[i] = -INFINITY; lrow[i] = 0.f;
#pragma unroll
        for (int j = 0; j < 4; ++j) O[i][j] = 0.f;
    }

    for (int kt = 0; kt < LL / 64; ++kt) {
        __syncthreads();
        {
            const int r = tid >> 2, c0 = (tid & 3) * 16;
            const float* kr = kbase + ((size_t)kt * 64 + r) * rs_;
            const float* vr = vbase + ((size_t)kt * 64 + r) * rs_;
#pragma unroll
            for (int u = 0; u < 4; ++u) {
                float4 kv = *(const float4*)(kr + c0 + u * 4);
                Kt[c0 + u*4 + 0][r] = kv.x; Kt[c0 + u*4 + 1][r] = kv.y;
                Kt[c0 + u*4 + 2][r] = kv.z; Kt[c0 + u*4 + 3][r] = kv.w;
                *(float4*)&Vs[r][c0 + u*4] = *(const float4*)(vr + c0 + u * 4);
            }
        }
        __syncthreads();

        float S[4][4];
#pragma unroll
        for (int i = 0; i < 4; ++i)
#pragma unroll
            for (int j = 0; j < 4; ++j) S[i][j] = 0.f;
#pragma unroll 8
        for (int d = 0; d < DD; ++d) {
            float a[4], b[4];
            *(float4*)a = *(const float4*)&Qt[d][ty * 4];
            *(float4*)b = *(const float4*)&Kt[d][tx * 4];
#pragma unroll
            for (int i = 0; i < 4; ++i)
#pragma unroll
                for (int j = 0; j < 4; ++j) S[i][j] = fmaf(a[i], b[j], S[i][j]);
        }
#pragma unroll
        for (int i = 0; i < 4; ++i) {
#pragma unroll
            for (int j = 0; j < 4; ++j) S[i][j] *= 0.125f;
            float pm = fmaxf(fmaxf(S[i][0], S[i][1]), fmaxf(S[i][2], S[i][3]));
#pragma unroll
            for (int off = 1; off < 16; off <<= 1) pm = fmaxf(pm, __shfl_xor(pm, off));
            const float mnew = fmaxf(mrow[i], pm);
            const float corr = __expf(mrow[i] - mnew);
            float rsum = 0.f;
#pragma unroll
            for (int j = 0; j < 4; ++j) { S[i][j] = __expf(S[i][j] - mnew); rsum += S[i][j]; }
#pragma unroll
            for (int off = 1; off < 16; off <<= 1) rsum += __shfl_xor(rsum, off);
            mrow[i] = mnew;
            lrow[i] = lrow[i] * corr + rsum;
#pragma unroll
            for (int j = 0; j < 4; ++j) O[i][j] *= corr;
        }
#pragma unroll
        for (int i = 0; i < 4; ++i)
            *(float4*)&Ps[ty * 4 + i][tx * 4] = *(float4*)&S[i][0];
        __syncthreads();
#pragma unroll 4
        for (int k = 0; k < 64; k += 4) {
            float a[4][4];
#pragma unroll
            for (int i = 0; i < 4; ++i)
                *(float4*)&a[i][0] = *(const float4*)&Ps[ty * 4 + i][k];
#pragma unroll
            for (int kk = 0; kk < 4; ++kk) {
                float bv[4];
                *(float4*)bv = *(const float4*)&Vs[k + kk][tx * 4];
#pragma unroll
                for (int i = 0; i < 4; ++i)
#pragma unroll
                    for (int j = 0; j < 4; ++j)
                        O[i][j] = fmaf(a[i][kk], bv[j], O[i][j]);
            }
        }
    }

    float* obase = qkv + ((size_t)bb * LL + (size_t)qt * 64) * rs_ + hh * DD;
#pragma unroll
    for (int i = 0; i < 4; ++i) {
        const float inv = 1.f / lrow[i];
        float4 o;
        o.x = O[i][0] * inv; o.y = O[i][1] * inv;
        o.z = O[i][2] * inv; o.w = O[i][3] * inv;
        *(float4*)(obase + (size_t)(ty * 4 + i) * rs_ + tx * 4) = o;
    }
}

// ---------------------------------------------------------------------------
extern "C" void kernel_launch(void* const* d_in, const int* in_sizes, int n_in,
                              void* d_out, int out_size, void* d_ws, size_t ws_size,
                              hipStream_t stream)
{
    const float* x    = (const float*)d_in[0];
    const float* Wqkv = (const float*)d_in[1];
    const float* bqkv = (const float*)d_in[2];
    const float* gq   = (const float*)d_in[3];
    const float* gk   = (const float*)d_in[4];
    const float* Wout = (const float*)d_in[5];
    const float* bout = (const float*)d_in[6];
    float* out = (float*)d_out;

    const size_t T_A = 150994944ull; // + x hi/lo split
    const size_t T_B = 117440512ull; // known-good workspace size (proven available)

    if (ws_size >= T_B) {
        char* wsb = (char*)d_ws;
        float*    Qb  = (float*)wsb;                      // 32 MiB
        ushort_t* Kh  = (ushort_t*)(wsb + 33554432);      // 16 MiB
        ushort_t* Kl  = (ushort_t*)(wsb + 50331648);      // 16 MiB
        ushort_t* Vth = (ushort_t*)(wsb + 67108864);      // 16 MiB
        ushort_t* wqh = (ushort_t*)(wsb + 100663296);     // 6 MiB
        ushort_t* woh = (ushort_t*)(wsb + 106954752);     // 2 MiB

        transp_hi<<<dim3(3 * CC / 64, CC / 64), 256, 0, stream>>>(Wqkv, wqh, CC, 3 * CC);
        transp_hi<<<dim3(CC / 64, CC / 64), 256, 0, stream>>>(Wout, woh, CC, CC);

        if (ws_size >= T_A) {
            ushort_t* xh = (ushort_t*)(wsb + 117440512);
            ushort_t* xl = (ushort_t*)(wsb + 134217728);
            split_bf16<<<dim3(MM * CC / 8 / 256), 256, 0, stream>>>(x, xh, xl, MM * CC);
            gemm_qkv<0><<<dim3(24 * 64), 256, 0, stream>>>(
                nullptr, xh, xl, wqh, bqkv, gq, gk, Qb, Kh, Kl, Vth);
        } else {
            gemm_qkv<1><<<dim3(24 * 64), 256, 0, stream>>>(
                x, nullptr, nullptr, wqh, bqkv, gq, gk, Qb, Kh, Kl, Vth);
        }

        flash4<<<dim3(1024), 256, 0, stream>>>(Qb, Kh, Kl, Vth);

        gemm_mfma<1><<<dim3(8 * 64), 256, 0, stream>>>(
            Qb, nullptr, nullptr, woh, bout, out, CC, CC, CC, CC / 128);
    } else {
        // legacy fp32 path
        float* qkv = (float*)d_ws;
        gemm_bias<<<dim3((3 * CC) / Bn, MM / Bb), 256, 0, stream>>>(
            x, Wqkv, bqkv, qkv, MM, 3 * CC, CC, CC, 3 * CC, 3 * CC);
        rmsnorm_qk<<<dim3((MM * HH * 2 * 64) / 256), 256, 0, stream>>>(qkv, gq, gk);
        flash_fp32<<<dim3(LL / 64, HH, BB), 256, 0, stream>>>(qkv);
        gemm_bias<<<dim3(CC / Bn, MM / Bb), 256, 0, stream>>>(
            qkv, Wout, bout, out, MM, CC, CC, 3 * CC, CC, CC);
    }
}

// Round 8
// 340.449 us; speedup vs baseline: 5.5885x; 1.0021x over previous
//
#include <hip/hip_runtime.h>
#include <math.h>

// Problem constants (B=4, L=2048, C=1024, H=16, D=64)
#define BB 4
#define LL 2048
#define CC 1024
#define HH 16
#define DD 64
#define MM (BB * LL) // 8192 rows

typedef float f32x4 __attribute__((ext_vector_type(4)));
typedef short short8 __attribute__((ext_vector_type(8))); // 8 bf16 (4 VGPRs)
typedef unsigned short ushort_t;
typedef unsigned long long u64_t;

#define MFMA_BF16(A, B, C) __builtin_amdgcn_mfma_f32_16x16x32_bf16(A, B, C, 0, 0, 0)

__device__ __forceinline__ unsigned short f2bf(float x) {
    unsigned int u = __float_as_uint(x);
    u += 0x7fffu + ((u >> 16) & 1u); // RTN-even
    return (unsigned short)(u >> 16);
}
__device__ __forceinline__ float bf2f(unsigned short h) {
    return __uint_as_float(((unsigned int)h) << 16);
}
__device__ __forceinline__ void split8(const f32x4& a, const f32x4& b,
                                       short8& h, short8& l) {
#pragma unroll
    for (int j = 0; j < 4; ++j) {
        unsigned short ha = f2bf(a[j]);
        h[j] = (short)ha; l[j] = (short)f2bf(a[j] - bf2f(ha));
        unsigned short hb = f2bf(b[j]);
        h[4 + j] = (short)hb; l[4 + j] = (short)f2bf(b[j] - bf2f(hb));
    }
}

// ---------------------------------------------------------------------------
// Elementwise f32 -> bf16 hi/lo split (for x).
// ---------------------------------------------------------------------------
__global__ __launch_bounds__(256)
void split_bf16(const float* __restrict__ src, ushort_t* __restrict__ hi,
                ushort_t* __restrict__ lo, int n)
{
    const int i = (blockIdx.x * 256 + threadIdx.x) * 8;
    if (i >= n) return;
    f32x4 a = *(const f32x4*)(src + i);
    f32x4 b = *(const f32x4*)(src + i + 4);
    short8 h, l;
    split8(a, b, h, l);
    *(short8*)(hi + i) = h;
    *(short8*)(lo + i) = l;
}

// ---------------------------------------------------------------------------
// Transpose + bf16 round (hi only): W[K][N] f32 row-major -> WT[N][K] bf16.
// ---------------------------------------------------------------------------
__global__ __launch_bounds__(256)
void transp_hi(const float* __restrict__ W, ushort_t* __restrict__ Th,
               int K, int N)
{
    __shared__ float sT[64][65];
    const int k0 = blockIdx.y * 64, n0 = blockIdx.x * 64;
    const int tid = threadIdx.x;
    const int r = tid >> 2, c0 = (tid & 3) * 16;

    const float* wp = W + (size_t)(k0 + r) * N + n0 + c0;
#pragma unroll
    for (int u = 0; u < 4; ++u) {
        f32x4 v = *(const f32x4*)(wp + 4 * u);
        sT[r][c0 + 4 * u + 0] = v[0];
        sT[r][c0 + 4 * u + 1] = v[1];
        sT[r][c0 + 4 * u + 2] = v[2];
        sT[r][c0 + 4 * u + 3] = v[3];
    }
    __syncthreads();

    const int nn = tid >> 2, kk0 = (tid & 3) * 16;
    short8 h0, h1;
#pragma unroll
    for (int u = 0; u < 8; ++u) {
        h0[u] = (short)f2bf(sT[kk0 + u][nn]);
        h1[u] = (short)f2bf(sT[kk0 + 8 + u][nn]);
    }
    ushort_t* oh = Th + (size_t)(n0 + nn) * K + k0 + kk0;
    *(short8*)oh = h0; *(short8*)(oh + 8) = h1;
}

// ---------------------------------------------------------------------------
// Fused QKV GEMM (2-term split: Ah*Bh + Al*Bh; B = bf16 weights).
// Epilogue: rmsnorm q->Qb f32, rmsnorm k->bf16 hi [b][h][l][d],
// v->bf16 hi, transposed [b][h][d][l].
// ---------------------------------------------------------------------------
template<int AF32>
__global__ __launch_bounds__(256, 3)
void gemm_qkv(const float* __restrict__ Af,
              const ushort_t* __restrict__ Agh, const ushort_t* __restrict__ Agl,
              const ushort_t* __restrict__ Bh,
              const float* __restrict__ bias,
              const float* __restrict__ gq, const float* __restrict__ gk,
              float* __restrict__ Qb,
              ushort_t* __restrict__ Kh,
              ushort_t* __restrict__ Vth)
{
    __shared__ ushort_t smem[24576]; // 48 KB
    ushort_t* sAh = smem;
    ushort_t* sAl = smem + 8192;
    ushort_t* sBh = smem + 16384;

    const int K = CC, lda = CC, nbx = (3 * CC) / 128; // 24

    const int nwg = gridDim.x;
    const int cpx = nwg >> 3;
    const int id  = blockIdx.x;
    const int swz = (id & 7) * cpx + (id >> 3);
    const int bx = swz % nbx, by = swz / nbx;
    const int m0 = by * 128, n0 = bx * 128;

    const int tid  = threadIdx.x;
    const int lane = tid & 63;
    const int wv   = tid >> 6;
    const int l4   = lane >> 4, l16 = lane & 15;
    const int wm   = wv >> 1,  wn  = wv & 1;

    const int r0  = tid >> 2;
    const int c0  = (tid & 3) * 16;
    const int ch0 = c0 >> 3;

    f32x4 acc[4][4];
#pragma unroll
    for (int i = 0; i < 4; ++i)
#pragma unroll
        for (int j = 0; j < 4; ++j) acc[i][j] = 0.f;

    for (int kt = 0; kt < K; kt += 64) {
        __syncthreads();
#pragma unroll
        for (int it = 0; it < 2; ++it) {
            const int row  = r0 + 64 * it;
            const int sA   = row & 7;
            const int base = row * 64;
            const int cA = ((ch0) ^ sA) * 8, cB = ((ch0 + 1) ^ sA) * 8;

            if constexpr (AF32) {
                const float* ap = Af + (size_t)(m0 + row) * lda + kt + c0;
                f32x4 v0 = *(const f32x4*)(ap);
                f32x4 v1 = *(const f32x4*)(ap + 4);
                f32x4 v2 = *(const f32x4*)(ap + 8);
                f32x4 v3 = *(const f32x4*)(ap + 12);
                short8 h0, l0, h1, l1;
                split8(v0, v1, h0, l0);
                split8(v2, v3, h1, l1);
                *(short8*)&sAh[base + cA] = h0;
                *(short8*)&sAh[base + cB] = h1;
                *(short8*)&sAl[base + cA] = l0;
                *(short8*)&sAl[base + cB] = l1;
            } else {
                const ushort_t* ahp = Agh + (size_t)(m0 + row) * lda + kt + c0;
                const ushort_t* alp = Agl + (size_t)(m0 + row) * lda + kt + c0;
                *(short8*)&sAh[base + cA] = *(const short8*)(ahp);
                *(short8*)&sAh[base + cB] = *(const short8*)(ahp + 8);
                *(short8*)&sAl[base + cA] = *(const short8*)(alp);
                *(short8*)&sAl[base + cB] = *(const short8*)(alp + 8);
            }
            const ushort_t* bhp = Bh + (size_t)(n0 + row) * K + kt + c0;
            *(short8*)&sBh[base + cA] = *(const short8*)(bhp);
            *(short8*)&sBh[base + cB] = *(const short8*)(bhp + 8);
        }
        __syncthreads();

#pragma unroll
        for (int ks = 0; ks < 2; ++ks) {
            const int chf = (((ks << 2) | l4) ^ (l16 & 7)) * 8;
            short8 fbh[4];
#pragma unroll
            for (int j = 0; j < 4; ++j) {
                const int idx = (64 * wn + 16 * j + l16) * 64 + chf;
                fbh[j] = *(const short8*)&sBh[idx];
            }
#pragma unroll
            for (int i = 0; i < 4; ++i) {
                const int idx = (64 * wm + 16 * i + l16) * 64 + chf;
                short8 fah = *(const short8*)&sAh[idx];
                short8 fal = *(const short8*)&sAl[idx];
#pragma unroll
                for (int j = 0; j < 4; ++j) {
                    acc[i][j] = MFMA_BF16(fah, fbh[j], acc[i][j]);
                    acc[i][j] = MFMA_BF16(fal, fbh[j], acc[i][j]);
                }
            }
        }
    }

    // ---- epilogue -------------------------------------------------------
    const int region = n0 >> 10; // 0=q, 1=k, 2=v
    float bv[4];
#pragma unroll
    for (int j = 0; j < 4; ++j) bv[j] = bias[n0 + 64 * wn + 16 * j + l16];
#pragma unroll
    for (int i = 0; i < 4; ++i)
#pragma unroll
        for (int j = 0; j < 4; ++j)
#pragma unroll
            for (int r = 0; r < 4; ++r) acc[i][j][r] += bv[j];

    const int b = m0 >> 11;

    if (region < 2) {
        const int hloc = ((n0 & 1023) >> 6) + wn;
        const float* g = (region == 0 ? gq : gk) + hloc * DD;
        float gv[4];
#pragma unroll
        for (int j = 0; j < 4; ++j) gv[j] = g[16 * j + l16];
#pragma unroll
        for (int i = 0; i < 4; ++i)
#pragma unroll
        for (int r = 0; r < 4; ++r) {
            float ss = 0.f;
#pragma unroll
            for (int j = 0; j < 4; ++j) ss += acc[i][j][r] * acc[i][j][r];
#pragma unroll
            for (int off = 1; off < 16; off <<= 1) ss += __shfl_xor(ss, off);
            const float s = 8.0f / fmaxf(sqrtf(ss), 1e-12f);
#pragma unroll
            for (int j = 0; j < 4; ++j) acc[i][j][r] *= s * gv[j];
        }

        if (region == 0) {
#pragma unroll
            for (int i = 0; i < 4; ++i)
#pragma unroll
            for (int r = 0; r < 4; ++r) {
                const int row = m0 + 64 * wm + 16 * i + 4 * l4 + r;
                float* op = Qb + (size_t)row * CC + n0 + 64 * wn + l16;
#pragma unroll
                for (int j = 0; j < 4; ++j) op[16 * j] = acc[i][j][r];
            }
        } else {
            const int hk = ((n0 - 1024) >> 6) + wn;
#pragma unroll
            for (int i = 0; i < 4; ++i)
#pragma unroll
            for (int r = 0; r < 4; ++r) {
                const int l = (m0 & 2047) + 64 * wm + 16 * i + 4 * l4 + r;
                const size_t base = ((size_t)(b * HH + hk) * LL + l) * DD + l16;
#pragma unroll
                for (int j = 0; j < 4; ++j)
                    Kh[base + 16 * j] = f2bf(acc[i][j][r]);
            }
        }
    } else {
        // V: bf16 hi-only + 128x128 LDS transpose + vector store to [b][h][d][l]
        __syncthreads();
        ushort_t* vh = smem; // [128][128] = 32 KB (fits in 48 KB smem)
#pragma unroll
        for (int i = 0; i < 4; ++i)
#pragma unroll
        for (int r = 0; r < 4; ++r) {
            const int lr = 64 * wm + 16 * i + 4 * l4 + r;
#pragma unroll
            for (int j = 0; j < 4; ++j) {
                const int c = 64 * wn + 16 * j + l16;
                vh[lr * 128 + c] = f2bf(acc[i][j][r]);
            }
        }
        __syncthreads();
        const int c    = tid & 127;
        const int half = tid >> 7;
        const int hv   = ((n0 - 2048) >> 6) + (c >> 6);
        const int d    = c & 63;
        ushort_t* oh = Vth + ((size_t)(b * HH + hv) * DD + d) * LL + (m0 & 2047) + half * 64;
#pragma unroll
        for (int u = 0; u < 8; ++u) {
            const int l0 = half * 64 + u * 8;
            short8 hv8;
#pragma unroll
            for (int e = 0; e < 8; ++e)
                hv8[e] = (short)vh[(l0 + e) * 128 + c];
            *(short8*)&oh[u * 8] = hv8;
        }
    }
}

// ---------------------------------------------------------------------------
// MFMA GEMM (2-term split, plain bias epilogue) — output projection.
// ---------------------------------------------------------------------------
template<int AF32>
__global__ __launch_bounds__(256, 3)
void gemm_mfma(const float* __restrict__ Af,
               const ushort_t* __restrict__ Agh, const ushort_t* __restrict__ Agl,
               const ushort_t* __restrict__ Bh,
               const float* __restrict__ bias, float* __restrict__ Cg,
               int K, int lda, int ldc, int nbx)
{
    __shared__ ushort_t sAh[128 * 64];
    __shared__ ushort_t sAl[128 * 64];
    __shared__ ushort_t sBh[128 * 64];

    const int nwg = gridDim.x;
    const int cpx = nwg >> 3;
    const int id  = blockIdx.x;
    const int sw  = (id & 7) * cpx + (id >> 3);
    const int bx = sw % nbx, by = sw / nbx;
    const int m0 = by * 128, n0 = bx * 128;

    const int tid  = threadIdx.x;
    const int lane = tid & 63;
    const int wv   = tid >> 6;
    const int l4   = lane >> 4, l16 = lane & 15;
    const int wm   = wv >> 1,  wn  = wv & 1;

    const int r0  = tid >> 2;
    const int c0  = (tid & 3) * 16;
    const int ch0 = c0 >> 3;

    f32x4 acc[4][4];
#pragma unroll
    for (int i = 0; i < 4; ++i)
#pragma unroll
        for (int j = 0; j < 4; ++j) acc[i][j] = 0.f;

    for (int kt = 0; kt < K; kt += 64) {
        __syncthreads();
#pragma unroll
        for (int it = 0; it < 2; ++it) {
            const int row  = r0 + 64 * it;
            const int sA   = row & 7;
            const int base = row * 64;
            const int cA = ((ch0) ^ sA) * 8, cB = ((ch0 + 1) ^ sA) * 8;

            if constexpr (AF32) {
                const float* ap = Af + (size_t)(m0 + row) * lda + kt + c0;
                f32x4 v0 = *(const f32x4*)(ap);
                f32x4 v1 = *(const f32x4*)(ap + 4);
                f32x4 v2 = *(const f32x4*)(ap + 8);
                f32x4 v3 = *(const f32x4*)(ap + 12);
                short8 h0, l0, h1, l1;
                split8(v0, v1, h0, l0);
                split8(v2, v3, h1, l1);
                *(short8*)&sAh[base + cA] = h0;
                *(short8*)&sAh[base + cB] = h1;
                *(short8*)&sAl[base + cA] = l0;
                *(short8*)&sAl[base + cB] = l1;
            } else {
                const ushort_t* ahp = Agh + (size_t)(m0 + row) * lda + kt + c0;
                const ushort_t* alp = Agl + (size_t)(m0 + row) * lda + kt + c0;
                *(short8*)&sAh[base + cA] = *(const short8*)(ahp);
                *(short8*)&sAh[base + cB] = *(const short8*)(ahp + 8);
                *(short8*)&sAl[base + cA] = *(const short8*)(alp);
                *(short8*)&sAl[base + cB] = *(const short8*)(alp + 8);
            }
            const ushort_t* bhp = Bh + (size_t)(n0 + row) * K + kt + c0;
            *(short8*)&sBh[base + cA] = *(const short8*)(bhp);
            *(short8*)&sBh[base + cB] = *(const short8*)(bhp + 8);
        }
        __syncthreads();

#pragma unroll
        for (int ks = 0; ks < 2; ++ks) {
            const int chf = (((ks << 2) | l4) ^ (l16 & 7)) * 8;
            short8 fbh[4];
#pragma unroll
            for (int j = 0; j < 4; ++j) {
                const int idx = (64 * wn + 16 * j + l16) * 64 + chf;
                fbh[j] = *(const short8*)&sBh[idx];
            }
#pragma unroll
            for (int i = 0; i < 4; ++i) {
                const int idx = (64 * wm + 16 * i + l16) * 64 + chf;
                short8 fah = *(const short8*)&sAh[idx];
                short8 fal = *(const short8*)&sAl[idx];
#pragma unroll
                for (int j = 0; j < 4; ++j) {
                    acc[i][j] = MFMA_BF16(fah, fbh[j], acc[i][j]);
                    acc[i][j] = MFMA_BF16(fal, fbh[j], acc[i][j]);
                }
            }
        }
    }

    float bv[4];
#pragma unroll
    for (int j = 0; j < 4; ++j) bv[j] = bias[n0 + 64 * wn + 16 * j + l16];
#pragma unroll
    for (int i = 0; i < 4; ++i)
#pragma unroll
    for (int r = 0; r < 4; ++r) {
        const int row = m0 + 64 * wm + 16 * i + 4 * l4 + r;
        float* cp = Cg + (size_t)row * ldc + n0 + 64 * wn + l16;
#pragma unroll
        for (int j = 0; j < 4; ++j) cp[16 * j] = acc[i][j][r] + bv[j];
    }
}

// ---------------------------------------------------------------------------
// Flash attention v5: swapped QK^T with bf16 K (S = kh*qh + kh*ql),
// lane-local softmax, P hi-only bf16, V hi-only. LDS 33.4 KB -> 4 blocks/CU.
// Defer-max (THR=8).
// ---------------------------------------------------------------------------
__global__ __launch_bounds__(256, 4)
void flash5(float* __restrict__ Qb,
            const ushort_t* __restrict__ Kh,
            const ushort_t* __restrict__ Vth)
{
    __shared__ ushort_t sKh[4096], sVh[4096]; // 16 KB
    __shared__ ushort_t sP[4][32 * 68];       // 17 KB

    const int i    = blockIdx.x;
    const int xcd  = i & 7;
    const int slot = i >> 3;
    const int qt   = slot & 15;
    const int bh   = ((slot >> 4) << 3) | xcd;
    const int b    = bh >> 4, h = bh & 15;

    const int tid  = threadIdx.x;
    const int lane = tid & 63;
    const int wv   = tid >> 6;
    const int l4   = lane >> 4, l16 = lane & 15;

    // ---- Q fragments (x 1/sqrt(D)), 2 q-frags per wave (B-operand)
    short8 qh[2][2], ql[2][2];
    const int qr0 = qt * 128 + wv * 32;
#pragma unroll
    for (int qf = 0; qf < 2; ++qf)
#pragma unroll
    for (int sl = 0; sl < 2; ++sl) {
        const float* qp = Qb + (size_t)(b * LL + qr0 + qf * 16 + l16) * CC
                             + h * DD + sl * 32 + l4 * 8;
        f32x4 a = *(const f32x4*)qp;
        f32x4 c = *(const f32x4*)(qp + 4);
#pragma unroll
        for (int j = 0; j < 4; ++j) { a[j] *= 0.125f; c[j] *= 0.125f; }
        split8(a, c, qh[qf][sl], ql[qf][sl]);
    }

    f32x4 O[2][4];
    float mrow[2], lrow[2]; // state for q-row (qf*16 + l16), replicated over l4
#pragma unroll
    for (int qf = 0; qf < 2; ++qf) {
        mrow[qf] = -INFINITY; lrow[qf] = 0.f;
#pragma unroll
        for (int t = 0; t < 4; ++t) O[qf][t] = 0.f;
    }

    const int r_ = tid >> 2;          // staging row 0..63
    const int c2 = (tid & 3) * 2;     // chunk pair

    short8 stg[4];
    {
        const size_t kgb = ((size_t)bh * LL + r_) * DD + c2 * 8;
        const size_t vgb = ((size_t)bh * DD + r_) * LL + c2 * 8;
        stg[0] = *(const short8*)&Kh[kgb];  stg[1] = *(const short8*)&Kh[kgb + 8];
        stg[2] = *(const short8*)&Vth[vgb]; stg[3] = *(const short8*)&Vth[vgb + 8];
    }

    for (int kt = 0; kt < LL / 64; ++kt) {
        __syncthreads(); // previous tile fully consumed
        {
            const int wr = r_ * 64, s = r_ & 7;
            const int cA = ((c2) ^ s) * 8, cB = ((c2 + 1) ^ s) * 8;
            *(short8*)&sKh[wr + cA] = stg[0];
            *(short8*)&sKh[wr + cB] = stg[1];
            *(short8*)&sVh[wr + cA] = stg[2];
            *(short8*)&sVh[wr + cB] = stg[3];
        }
        __syncthreads();
        if (kt + 1 < LL / 64) { // prefetch next tile into regs
            const size_t kgb = ((size_t)bh * LL + (kt + 1) * 64 + r_) * DD + c2 * 8;
            const size_t vgb = ((size_t)bh * DD + r_) * LL + (kt + 1) * 64 + c2 * 8;
            stg[0] = *(const short8*)&Kh[kgb];  stg[1] = *(const short8*)&Kh[kgb + 8];
            stg[2] = *(const short8*)&Vth[vgb]; stg[3] = *(const short8*)&Vth[vgb + 8];
        }

        // ---- S^T = K Q : rows k (4*l4+r per tile t), cols q (l16)
        f32x4 S[2][4];
#pragma unroll
        for (int qf = 0; qf < 2; ++qf)
#pragma unroll
        for (int t = 0; t < 4; ++t) S[qf][t] = 0.f;

        __builtin_amdgcn_s_setprio(1);
#pragma unroll
        for (int t = 0; t < 4; ++t) {
            const int row = 16 * t + l16;
            const int swr = row & 7;
#pragma unroll
            for (int sl = 0; sl < 2; ++sl) {
                const int idx = row * 64 + (((sl << 2) | l4) ^ swr) * 8;
                short8 kh8 = *(const short8*)&sKh[idx];
#pragma unroll
                for (int qf = 0; qf < 2; ++qf) {
                    S[qf][t] = MFMA_BF16(kh8, qh[qf][sl], S[qf][t]);
                    S[qf][t] = MFMA_BF16(kh8, ql[qf][sl], S[qf][t]);
                }
            }
        }
        __builtin_amdgcn_s_setprio(0);

        // ---- lane-local softmax (each lane owns row q = qf*16+l16, 16 ks)
#pragma unroll
        for (int qf = 0; qf < 2; ++qf) {
            float pm = S[qf][0][0];
#pragma unroll
            for (int t = 0; t < 4; ++t)
#pragma unroll
                for (int r = 0; r < 4; ++r) pm = fmaxf(pm, S[qf][t][r]);
            pm = fmaxf(pm, __shfl_xor(pm, 16));
            pm = fmaxf(pm, __shfl_xor(pm, 32));

            if (__any(pm > mrow[qf] + 8.f)) { // rescale (rare after tile 0)
                const float mnew = fmaxf(mrow[qf], pm);
                const float corr = __expf(mrow[qf] - mnew);
                mrow[qf] = mnew;
                lrow[qf] *= corr;
                float c0 = __shfl(corr, 4 * l4 + 0);
                float c1 = __shfl(corr, 4 * l4 + 1);
                float c2v = __shfl(corr, 4 * l4 + 2);
                float c3 = __shfl(corr, 4 * l4 + 3);
#pragma unroll
                for (int dt = 0; dt < 4; ++dt) {
                    O[qf][dt][0] *= c0; O[qf][dt][1] *= c1;
                    O[qf][dt][2] *= c2v; O[qf][dt][3] *= c3;
                }
            }
            float rs = 0.f;
#pragma unroll
            for (int t = 0; t < 4; ++t)
#pragma unroll
                for (int r = 0; r < 4; ++r) {
                    float p = __expf(S[qf][t][r] - mrow[qf]);
                    S[qf][t][r] = p;
                    rs += p;
                }
            rs += __shfl_xor(rs, 16);
            rs += __shfl_xor(rs, 32);
            lrow[qf] += rs;
        }

        // ---- P -> per-wave LDS (bf16 hi-only), vector b64 writes
#pragma unroll
        for (int qf = 0; qf < 2; ++qf)
#pragma unroll
        for (int t = 0; t < 4; ++t) {
            unsigned lo = (unsigned)f2bf(S[qf][t][0]) | ((unsigned)f2bf(S[qf][t][1]) << 16);
            unsigned hi = (unsigned)f2bf(S[qf][t][2]) | ((unsigned)f2bf(S[qf][t][3]) << 16);
            const int widx = (qf * 16 + l16) * 68 + 16 * t + 4 * l4;
            *(u64_t*)&sP[wv][widx] = (u64_t)lo | ((u64_t)hi << 32);
        }
        asm volatile("s_waitcnt lgkmcnt(0)" ::: "memory");
        __builtin_amdgcn_sched_barrier(0);

        // ---- P A-fragments: row q = l16, k = sl*32 + 8*l4 + j
        short8 pa[2][2];
#pragma unroll
        for (int qf = 0; qf < 2; ++qf)
#pragma unroll
        for (int sl = 0; sl < 2; ++sl) {
            const int ridx = (qf * 16 + l16) * 68 + sl * 32 + 8 * l4;
            union { u64_t q[2]; short8 s8; } u;
            u.q[0] = *(const u64_t*)&sP[wv][ridx];
            u.q[1] = *(const u64_t*)&sP[wv][ridx + 4];
            pa[qf][sl] = u.s8;
        }

        // ---- O += P V (P hi-only; V hi-only)
        __builtin_amdgcn_s_setprio(1);
#pragma unroll
        for (int dt = 0; dt < 4; ++dt) {
            const int row = 16 * dt + l16;
            const int swr = row & 7;
#pragma unroll
            for (int sl = 0; sl < 2; ++sl) {
                const int idx = row * 64 + (((sl << 2) | l4) ^ swr) * 8;
                short8 vh8 = *(const short8*)&sVh[idx];
#pragma unroll
                for (int qf = 0; qf < 2; ++qf)
                    O[qf][dt] = MFMA_BF16(pa[qf][sl], vh8, O[qf][dt]);
            }
        }
        __builtin_amdgcn_s_setprio(0);
    }

    // ---- epilogue: h = O / l over Qbuf rows (unique owner)
#pragma unroll
    for (int qf = 0; qf < 2; ++qf) {
        const float inv = 1.0f / lrow[qf];
        float i0 = __shfl(inv, 4 * l4 + 0);
        float i1 = __shfl(inv, 4 * l4 + 1);
        float i2 = __shfl(inv, 4 * l4 + 2);
        float i3 = __shfl(inv, 4 * l4 + 3);
        f32x4 iv; iv[0] = i0; iv[1] = i1; iv[2] = i2; iv[3] = i3;
#pragma unroll
        for (int r = 0; r < 4; ++r) {
            const int q = qr0 + qf * 16 + 4 * l4 + r;
            float* op = Qb + (size_t)(b * LL + q) * CC + h * DD + l16;
#pragma unroll
            for (int dt = 0; dt < 4; ++dt)
                op[16 * dt] = O[qf][dt][r] * iv[r];
        }
    }
}

// ---------------------------------------------------------------------------
// Legacy fp32 fallback kernels (only if ws_size is too small; never expected)
// ---------------------------------------------------------------------------
#define Bb 128
#define Bn 128
#define BKG 8

__global__ __launch_bounds__(256)
void gemm_bias(const float* __restrict__ A, const float* __restrict__ B,
               const float* __restrict__ bias, float* __restrict__ C,
               int M, int N, int K, int lda, int ldb, int ldc)
{
    __shared__ float As[BKG][Bb];
    __shared__ float Bs[BKG][Bn];

    const int tid = threadIdx.x;
    const int m0 = blockIdx.y * Bb;
    const int n0 = blockIdx.x * Bn;
    const int ty = tid >> 4, tx = tid & 15;
    const int arow = tid >> 1, acol = (tid & 1) * 4;
    const int brow = tid >> 5, bcol = (tid & 31) * 4;

    const float* Ap = A + (size_t)(m0 + arow) * lda + acol;
    const float* Bp = B + (size_t)brow * ldb + n0 + bcol;

    float acc[8][8];
#pragma unroll
    for (int i = 0; i < 8; ++i)
#pragma unroll
        for (int j = 0; j < 8; ++j) acc[i][j] = 0.f;

    for (int k0 = 0; k0 < K; k0 += BKG) {
        float4 av = *(const float4*)(Ap + k0);
        float4 bv = *(const float4*)(Bp + (size_t)k0 * ldb);
        __syncthreads();
        As[acol + 0][arow] = av.x;
        As[acol + 1][arow] = av.y;
        As[acol + 2][arow] = av.z;
        As[acol + 3][arow] = av.w;
        *(float4*)&Bs[brow][bcol] = bv;
        __syncthreads();
#pragma unroll
        for (int kk = 0; kk < BKG; ++kk) {
            float a[8], bvv[8];
            *(float4*)&a[0] = *(const float4*)&As[kk][ty * 4];
            *(float4*)&a[4] = *(const float4*)&As[kk][64 + ty * 4];
            *(float4*)&bvv[0] = *(const float4*)&Bs[kk][tx * 4];
            *(float4*)&bvv[4] = *(const float4*)&Bs[kk][64 + tx * 4];
#pragma unroll
            for (int i = 0; i < 8; ++i)
#pragma unroll
                for (int j = 0; j < 8; ++j)
                    acc[i][j] = fmaf(a[i], bvv[j], acc[i][j]);
        }
    }
#pragma unroll
    for (int ih = 0; ih < 2; ++ih)
#pragma unroll
    for (int i = 0; i < 4; ++i) {
        const int m = m0 + ih * 64 + ty * 4 + i;
#pragma unroll
        for (int jh = 0; jh < 2; ++jh) {
            const int n = n0 + jh * 64 + tx * 4;
            float4 o;
            o.x = acc[ih*4+i][jh*4+0] + bias[n+0];
            o.y = acc[ih*4+i][jh*4+1] + bias[n+1];
            o.z = acc[ih*4+i][jh*4+2] + bias[n+2];
            o.w = acc[ih*4+i][jh*4+3] + bias[n+3];
            *(float4*)(C + (size_t)m * ldc + n) = o;
        }
    }
}

__global__ __launch_bounds__(256)
void rmsnorm_qk(float* __restrict__ qkv,
                const float* __restrict__ gq, const float* __restrict__ gk)
{
    const int gt    = blockIdx.x * 256 + threadIdx.x;
    const int lane  = gt & 63;
    const int wave  = gt >> 6;
    const int which = wave & 1;
    const int h     = (wave >> 1) & (HH - 1);
    const int bl    = wave >> 5;

    float* p = qkv + (size_t)bl * (3 * CC) + which * CC + h * DD + lane;
    float v = *p;
    float ss = v * v;
#pragma unroll
    for (int off = 32; off; off >>= 1) ss += __shfl_xor(ss, off);
    float nrm = fmaxf(sqrtf(ss), 1e-12f);
    const float* g = which ? gk : gq;
    *p = v * (8.0f / nrm) * g[h * DD + lane];
}

__global__ __launch_bounds__(256)
void flash_fp32(float* __restrict__ qkv)
{
    const int qt = blockIdx.x, hh = blockIdx.y, bb = blockIdx.z;

    __shared__ float Qt[DD][64];
    __shared__ float Kt[DD][64];
    __shared__ float Vs[64][DD];
    __shared__ float Ps[64][64 + 4];

    const int tid = threadIdx.x;
    const int ty = tid >> 4, tx = tid & 15;
    const size_t rs_ = 3 * CC;
    const float* qbase = qkv + ((size_t)bb * LL + (size_t)qt * 64) * rs_ + hh * DD;
    const float* kbase = qkv + (size_t)bb * LL * rs_ + CC + hh * DD;
    const float* vbase = kbase + CC;

    {
        const int r = tid >> 2, c0 = (tid & 3) * 16;
#pragma unroll
        for (int u = 0; u < 4; ++u) {
            float4 v = *(const float4*)(qbase + (size_t)r * rs_ + c0 + u * 4);
            Qt[c0 + u*4 + 0][r] = v.x; Qt[c0 + u*4 + 1][r] = v.y;
            Qt[c0 + u*4 + 2][r] = v.z; Qt[c0 + u*4 + 3][r] = v.w;
        }
    }

    float mrow[4], lrow[4], O[4][4];
#pragma unroll
    for (int i = 0; i < 4; ++i) {
        mrow[i] = -INFINITY; lrow[i] = 0.f;
#pragma unroll
        for (int j = 0; j < 4; ++j) O[i][j] = 0.f;
    }

    for (int kt = 0; kt < LL / 64; ++kt) {
        __syncthreads();
        {
            const int r = tid >> 2, c0 = (tid & 3) * 16;
            const float* kr = kbase + ((size_t)kt * 64 + r) * rs_;
            const float* vr = vbase + ((size_t)kt * 64 + r) * rs_;
#pragma unroll
            for (int u = 0; u < 4; ++u) {
                float4 kv = *(const float4*)(kr + c0 + u * 4);
                Kt[c0 + u*4 + 0][r] = kv.x; Kt[c0 + u*4 + 1][r] = kv.y;
                Kt[c0 + u*4 + 2][r] = kv.z; Kt[c0 + u*4 + 3][r] = kv.w;
                *(float4*)&Vs[r][c0 + u*4] = *(const float4*)(vr + c0 + u * 4);
            }
        }
        __syncthreads();

        float S[4][4];
#pragma unroll
        for (int i = 0; i < 4; ++i)
#pragma unroll
            for (int j = 0; j < 4; ++j) S[i][j] = 0.f;
#pragma unroll 8
        for (int d = 0; d < DD; ++d) {
            float a[4], b[4];
            *(float4*)a = *(const float4*)&Qt[d][ty * 4];
            *(float4*)b = *(const float4*)&Kt[d][tx * 4];
#pragma unroll
            for (int i = 0; i < 4; ++i)
#pragma unroll
                for (int j = 0; j < 4; ++j) S[i][j] = fmaf(a[i], b[j], S[i][j]);
        }
#pragma unroll
        for (int i = 0; i < 4; ++i) {
#pragma unroll
            for (int j = 0; j < 4; ++j) S[i][j] *= 0.125f;
            float pm = fmaxf(fmaxf(S[i][0], S[i][1]), fmaxf(S[i][2], S[i][3]));
#pragma unroll
            for (int off = 1; off < 16; off <<= 1) pm = fmaxf(pm, __shfl_xor(pm, off));
            const float mnew = fmaxf(mrow[i], pm);
            const float corr = __expf(mrow[i] - mnew);
            float rsum = 0.f;
#pragma unroll
            for (int j = 0; j < 4; ++j) { S[i][j] = __expf(S[i][j] - mnew); rsum += S[i][j]; }
#pragma unroll
            for (int off = 1; off < 16; off <<= 1) rsum += __shfl_xor(rsum, off);
            mrow[i] = mnew;
            lrow[i] = lrow[i] * corr + rsum;
#pragma unroll
            for (int j = 0; j < 4; ++j) O[i][j] *= corr;
        }
#pragma unroll
        for (int i = 0; i < 4; ++i)
            *(float4*)&Ps[ty * 4 + i][tx * 4] = *(float4*)&S[i][0];
        __syncthreads();
#pragma unroll 4
        for (int k = 0; k < 64; k += 4) {
            float a[4][4];
#pragma unroll
            for (int i = 0; i < 4; ++i)
                *(float4*)&a[i][0] = *(const float4*)&Ps[ty * 4 + i][k];
#pragma unroll
            for (int kk = 0; kk < 4; ++kk) {
                float bv[4];
                *(float4*)bv = *(const float4*)&Vs[k + kk][tx * 4];
#pragma unroll
                for (int i = 0; i < 4; ++i)
#pragma unroll
                    for (int j = 0; j < 4; ++j)
                        O[i][j] = fmaf(a[i][kk], bv[j], O[i][j]);
            }
        }
    }

    float* obase = qkv + ((size_t)bb * LL + (size_t)qt * 64) * rs_ + hh * DD;
#pragma unroll
    for (int i = 0; i < 4; ++i) {
        const float inv = 1.f / lrow[i];
        float4 o;
        o.x = O[i][0] * inv; o.y = O[i][1] * inv;
        o.z = O[i][2] * inv; o.w = O[i][3] * inv;
        *(float4*)(obase + (size_t)(ty * 4 + i) * rs_ + tx * 4) = o;
    }
}

// ---------------------------------------------------------------------------
extern "C" void kernel_launch(void* const* d_in, const int* in_sizes, int n_in,
                              void* d_out, int out_size, void* d_ws, size_t ws_size,
                              hipStream_t stream)
{
    const float* x    = (const float*)d_in[0];
    const float* Wqkv = (const float*)d_in[1];
    const float* bqkv = (const float*)d_in[2];
    const float* gq   = (const float*)d_in[3];
    const float* gk   = (const float*)d_in[4];
    const float* Wout = (const float*)d_in[5];
    const float* bout = (const float*)d_in[6];
    float* out = (float*)d_out;

    const size_t T_A = 150994944ull; // + x hi/lo split
    const size_t T_B = 117440512ull; // known-good workspace size (proven available)

    if (ws_size >= T_B) {
        char* wsb = (char*)d_ws;
        float*    Qb  = (float*)wsb;                      // 32 MiB
        ushort_t* Kh  = (ushort_t*)(wsb + 33554432);      // 16 MiB
        ushort_t* Vth = (ushort_t*)(wsb + 67108864);      // 16 MiB
        ushort_t* wqh = (ushort_t*)(wsb + 100663296);     // 6 MiB
        ushort_t* woh = (ushort_t*)(wsb + 106954752);     // 2 MiB

        transp_hi<<<dim3(3 * CC / 64, CC / 64), 256, 0, stream>>>(Wqkv, wqh, CC, 3 * CC);
        transp_hi<<<dim3(CC / 64, CC / 64), 256, 0, stream>>>(Wout, woh, CC, CC);

        if (ws_size >= T_A) {
            ushort_t* xh = (ushort_t*)(wsb + 117440512);
            ushort_t* xl = (ushort_t*)(wsb + 134217728);
            split_bf16<<<dim3(MM * CC / 8 / 256), 256, 0, stream>>>(x, xh, xl, MM * CC);
            gemm_qkv<0><<<dim3(24 * 64), 256, 0, stream>>>(
                nullptr, xh, xl, wqh, bqkv, gq, gk, Qb, Kh, Vth);
        } else {
            gemm_qkv<1><<<dim3(24 * 64), 256, 0, stream>>>(
                x, nullptr, nullptr, wqh, bqkv, gq, gk, Qb, Kh, Vth);
        }

        flash5<<<dim3(1024), 256, 0, stream>>>(Qb, Kh, Vth);

        gemm_mfma<1><<<dim3(8 * 64), 256, 0, stream>>>(
            Qb, nullptr, nullptr, woh, bout, out, CC, CC, CC, CC / 128);
    } else {
        // legacy fp32 path
        float* qkv = (float*)d_ws;
        gemm_bias<<<dim3((3 * CC) / Bn, MM / Bb), 256, 0, stream>>>(
            x, Wqkv, bqkv, qkv, MM, 3 * CC, CC, CC, 3 * CC, 3 * CC);
        rmsnorm_qk<<<dim3((MM * HH * 2 * 64) / 256), 256, 0, stream>>>(qkv, gq, gk);
        flash_fp32<<<dim3(LL / 64, HH, BB), 256, 0, stream>>>(qkv);
        gemm_bias<<<dim3(CC / Bn, MM / Bb), 256, 0, stream>>>(
            qkv, Wout, bout, out, MM, CC, CC, 3 * CC, CC, CC);
    }
}

// Round 9
// 299.704 us; speedup vs baseline: 6.3482x; 1.1360x over previous
//
#include <hip/hip_runtime.h>
#include <math.h>

// Problem constants (B=4, L=2048, C=1024, H=16, D=64)
#define BB 4
#define LL 2048
#define CC 1024
#define HH 16
#define DD 64
#define MM (BB * LL) // 8192 rows

typedef float f32x4 __attribute__((ext_vector_type(4)));
typedef short short8 __attribute__((ext_vector_type(8))); // 8 bf16 (4 VGPRs)
typedef unsigned short ushort_t;
typedef unsigned long long u64_t;

#define MFMA_BF16(A, B, C) __builtin_amdgcn_mfma_f32_16x16x32_bf16(A, B, C, 0, 0, 0)

__device__ __forceinline__ unsigned short f2bf(float x) {
    unsigned int u = __float_as_uint(x);
    u += 0x7fffu + ((u >> 16) & 1u); // RTN-even
    return (unsigned short)(u >> 16);
}
__device__ __forceinline__ float bf2f(unsigned short h) {
    return __uint_as_float(((unsigned int)h) << 16);
}
__device__ __forceinline__ void split8(const f32x4& a, const f32x4& b,
                                       short8& h, short8& l) {
#pragma unroll
    for (int j = 0; j < 4; ++j) {
        unsigned short ha = f2bf(a[j]);
        h[j] = (short)ha; l[j] = (short)f2bf(a[j] - bf2f(ha));
        unsigned short hb = f2bf(b[j]);
        h[4 + j] = (short)hb; l[4 + j] = (short)f2bf(b[j] - bf2f(hb));
    }
}

// ---------------------------------------------------------------------------
// Elementwise f32 -> bf16 hi/lo split (for x).
// ---------------------------------------------------------------------------
__global__ __launch_bounds__(256)
void split_bf16(const float* __restrict__ src, ushort_t* __restrict__ hi,
                ushort_t* __restrict__ lo, int n)
{
    const int i = (blockIdx.x * 256 + threadIdx.x) * 8;
    if (i >= n) return;
    f32x4 a = *(const f32x4*)(src + i);
    f32x4 b = *(const f32x4*)(src + i + 4);
    short8 h, l;
    split8(a, b, h, l);
    *(short8*)(hi + i) = h;
    *(short8*)(lo + i) = l;
}

// ---------------------------------------------------------------------------
// Transpose + bf16 round (hi only): W[K][N] f32 row-major -> WT[N][K] bf16.
// ---------------------------------------------------------------------------
__global__ __launch_bounds__(256)
void transp_hi(const float* __restrict__ W, ushort_t* __restrict__ Th,
               int K, int N)
{
    __shared__ float sT[64][65];
    const int k0 = blockIdx.y * 64, n0 = blockIdx.x * 64;
    const int tid = threadIdx.x;
    const int r = tid >> 2, c0 = (tid & 3) * 16;

    const float* wp = W + (size_t)(k0 + r) * N + n0 + c0;
#pragma unroll
    for (int u = 0; u < 4; ++u) {
        f32x4 v = *(const f32x4*)(wp + 4 * u);
        sT[r][c0 + 4 * u + 0] = v[0];
        sT[r][c0 + 4 * u + 1] = v[1];
        sT[r][c0 + 4 * u + 2] = v[2];
        sT[r][c0 + 4 * u + 3] = v[3];
    }
    __syncthreads();

    const int nn = tid >> 2, kk0 = (tid & 3) * 16;
    short8 h0, h1;
#pragma unroll
    for (int u = 0; u < 8; ++u) {
        h0[u] = (short)f2bf(sT[kk0 + u][nn]);
        h1[u] = (short)f2bf(sT[kk0 + 8 + u][nn]);
    }
    ushort_t* oh = Th + (size_t)(n0 + nn) * K + k0 + kk0;
    *(short8*)oh = h0; *(short8*)(oh + 8) = h1;
}

// ---------------------------------------------------------------------------
// Fused QKV GEMM (2-term split: Ah*Bh + Al*Bh; B = bf16 weights).
// Epilogue: rmsnorm q->Qb f32, rmsnorm k->bf16 hi [b][h][l][d],
// v->bf16 hi, transposed [b][h][d][l].
// ---------------------------------------------------------------------------
template<int AF32>
__global__ __launch_bounds__(256, 3)
void gemm_qkv(const float* __restrict__ Af,
              const ushort_t* __restrict__ Agh, const ushort_t* __restrict__ Agl,
              const ushort_t* __restrict__ Bh,
              const float* __restrict__ bias,
              const float* __restrict__ gq, const float* __restrict__ gk,
              float* __restrict__ Qb,
              ushort_t* __restrict__ Kh,
              ushort_t* __restrict__ Vth)
{
    __shared__ ushort_t smem[24576]; // 48 KB
    ushort_t* sAh = smem;
    ushort_t* sAl = smem + 8192;
    ushort_t* sBh = smem + 16384;

    const int K = CC, lda = CC, nbx = (3 * CC) / 128; // 24

    const int nwg = gridDim.x;
    const int cpx = nwg >> 3;
    const int id  = blockIdx.x;
    const int swz = (id & 7) * cpx + (id >> 3);
    const int bx = swz % nbx, by = swz / nbx;
    const int m0 = by * 128, n0 = bx * 128;

    const int tid  = threadIdx.x;
    const int lane = tid & 63;
    const int wv   = tid >> 6;
    const int l4   = lane >> 4, l16 = lane & 15;
    const int wm   = wv >> 1,  wn  = wv & 1;

    const int r0  = tid >> 2;
    const int c0  = (tid & 3) * 16;
    const int ch0 = c0 >> 3;

    f32x4 acc[4][4];
#pragma unroll
    for (int i = 0; i < 4; ++i)
#pragma unroll
        for (int j = 0; j < 4; ++j) acc[i][j] = 0.f;

    for (int kt = 0; kt < K; kt += 64) {
        __syncthreads();
#pragma unroll
        for (int it = 0; it < 2; ++it) {
            const int row  = r0 + 64 * it;
            const int sA   = row & 7;
            const int base = row * 64;
            const int cA = ((ch0) ^ sA) * 8, cB = ((ch0 + 1) ^ sA) * 8;

            if constexpr (AF32) {
                const float* ap = Af + (size_t)(m0 + row) * lda + kt + c0;
                f32x4 v0 = *(const f32x4*)(ap);
                f32x4 v1 = *(const f32x4*)(ap + 4);
                f32x4 v2 = *(const f32x4*)(ap + 8);
                f32x4 v3 = *(const f32x4*)(ap + 12);
                short8 h0, l0, h1, l1;
                split8(v0, v1, h0, l0);
                split8(v2, v3, h1, l1);
                *(short8*)&sAh[base + cA] = h0;
                *(short8*)&sAh[base + cB] = h1;
                *(short8*)&sAl[base + cA] = l0;
                *(short8*)&sAl[base + cB] = l1;
            } else {
                const ushort_t* ahp = Agh + (size_t)(m0 + row) * lda + kt + c0;
                const ushort_t* alp = Agl + (size_t)(m0 + row) * lda + kt + c0;
                *(short8*)&sAh[base + cA] = *(const short8*)(ahp);
                *(short8*)&sAh[base + cB] = *(const short8*)(ahp + 8);
                *(short8*)&sAl[base + cA] = *(const short8*)(alp);
                *(short8*)&sAl[base + cB] = *(const short8*)(alp + 8);
            }
            const ushort_t* bhp = Bh + (size_t)(n0 + row) * K + kt + c0;
            *(short8*)&sBh[base + cA] = *(const short8*)(bhp);
            *(short8*)&sBh[base + cB] = *(const short8*)(bhp + 8);
        }
        __syncthreads();

#pragma unroll
        for (int ks = 0; ks < 2; ++ks) {
            const int chf = (((ks << 2) | l4) ^ (l16 & 7)) * 8;
            short8 fbh[4];
#pragma unroll
            for (int j = 0; j < 4; ++j) {
                const int idx = (64 * wn + 16 * j + l16) * 64 + chf;
                fbh[j] = *(const short8*)&sBh[idx];
            }
#pragma unroll
            for (int i = 0; i < 4; ++i) {
                const int idx = (64 * wm + 16 * i + l16) * 64 + chf;
                short8 fah = *(const short8*)&sAh[idx];
                short8 fal = *(const short8*)&sAl[idx];
#pragma unroll
                for (int j = 0; j < 4; ++j) {
                    acc[i][j] = MFMA_BF16(fah, fbh[j], acc[i][j]);
                    acc[i][j] = MFMA_BF16(fal, fbh[j], acc[i][j]);
                }
            }
        }
    }

    // ---- epilogue -------------------------------------------------------
    const int region = n0 >> 10; // 0=q, 1=k, 2=v
    float bv[4];
#pragma unroll
    for (int j = 0; j < 4; ++j) bv[j] = bias[n0 + 64 * wn + 16 * j + l16];
#pragma unroll
    for (int i = 0; i < 4; ++i)
#pragma unroll
        for (int j = 0; j < 4; ++j)
#pragma unroll
            for (int r = 0; r < 4; ++r) acc[i][j][r] += bv[j];

    const int b = m0 >> 11;

    if (region < 2) {
        const int hloc = ((n0 & 1023) >> 6) + wn;
        const float* g = (region == 0 ? gq : gk) + hloc * DD;
        float gv[4];
#pragma unroll
        for (int j = 0; j < 4; ++j) gv[j] = g[16 * j + l16];
#pragma unroll
        for (int i = 0; i < 4; ++i)
#pragma unroll
        for (int r = 0; r < 4; ++r) {
            float ss = 0.f;
#pragma unroll
            for (int j = 0; j < 4; ++j) ss += acc[i][j][r] * acc[i][j][r];
#pragma unroll
            for (int off = 1; off < 16; off <<= 1) ss += __shfl_xor(ss, off);
            const float s = 8.0f / fmaxf(sqrtf(ss), 1e-12f);
#pragma unroll
            for (int j = 0; j < 4; ++j) acc[i][j][r] *= s * gv[j];
        }

        if (region == 0) {
#pragma unroll
            for (int i = 0; i < 4; ++i)
#pragma unroll
            for (int r = 0; r < 4; ++r) {
                const int row = m0 + 64 * wm + 16 * i + 4 * l4 + r;
                float* op = Qb + (size_t)row * CC + n0 + 64 * wn + l16;
#pragma unroll
                for (int j = 0; j < 4; ++j) op[16 * j] = acc[i][j][r];
            }
        } else {
            const int hk = ((n0 - 1024) >> 6) + wn;
#pragma unroll
            for (int i = 0; i < 4; ++i)
#pragma unroll
            for (int r = 0; r < 4; ++r) {
                const int l = (m0 & 2047) + 64 * wm + 16 * i + 4 * l4 + r;
                const size_t base = ((size_t)(b * HH + hk) * LL + l) * DD + l16;
#pragma unroll
                for (int j = 0; j < 4; ++j)
                    Kh[base + 16 * j] = f2bf(acc[i][j][r]);
            }
        }
    } else {
        // V: bf16 hi-only + 128x128 LDS transpose + vector store to [b][h][d][l]
        __syncthreads();
        ushort_t* vh = smem; // [128][128] = 32 KB (fits in 48 KB smem)
#pragma unroll
        for (int i = 0; i < 4; ++i)
#pragma unroll
        for (int r = 0; r < 4; ++r) {
            const int lr = 64 * wm + 16 * i + 4 * l4 + r;
#pragma unroll
            for (int j = 0; j < 4; ++j) {
                const int c = 64 * wn + 16 * j + l16;
                vh[lr * 128 + c] = f2bf(acc[i][j][r]);
            }
        }
        __syncthreads();
        const int c    = tid & 127;
        const int half = tid >> 7;
        const int hv   = ((n0 - 2048) >> 6) + (c >> 6);
        const int d    = c & 63;
        ushort_t* oh = Vth + ((size_t)(b * HH + hv) * DD + d) * LL + (m0 & 2047) + half * 64;
#pragma unroll
        for (int u = 0; u < 8; ++u) {
            const int l0 = half * 64 + u * 8;
            short8 hv8;
#pragma unroll
            for (int e = 0; e < 8; ++e)
                hv8[e] = (short)vh[(l0 + e) * 128 + c];
            *(short8*)&oh[u * 8] = hv8;
        }
    }
}

// ---------------------------------------------------------------------------
// MFMA GEMM (2-term split, plain bias epilogue) — output projection.
// ---------------------------------------------------------------------------
template<int AF32>
__global__ __launch_bounds__(256, 3)
void gemm_mfma(const float* __restrict__ Af,
               const ushort_t* __restrict__ Agh, const ushort_t* __restrict__ Agl,
               const ushort_t* __restrict__ Bh,
               const float* __restrict__ bias, float* __restrict__ Cg,
               int K, int lda, int ldc, int nbx)
{
    __shared__ ushort_t sAh[128 * 64];
    __shared__ ushort_t sAl[128 * 64];
    __shared__ ushort_t sBh[128 * 64];

    const int nwg = gridDim.x;
    const int cpx = nwg >> 3;
    const int id  = blockIdx.x;
    const int sw  = (id & 7) * cpx + (id >> 3);
    const int bx = sw % nbx, by = sw / nbx;
    const int m0 = by * 128, n0 = bx * 128;

    const int tid  = threadIdx.x;
    const int lane = tid & 63;
    const int wv   = tid >> 6;
    const int l4   = lane >> 4, l16 = lane & 15;
    const int wm   = wv >> 1,  wn  = wv & 1;

    const int r0  = tid >> 2;
    const int c0  = (tid & 3) * 16;
    const int ch0 = c0 >> 3;

    f32x4 acc[4][4];
#pragma unroll
    for (int i = 0; i < 4; ++i)
#pragma unroll
        for (int j = 0; j < 4; ++j) acc[i][j] = 0.f;

    for (int kt = 0; kt < K; kt += 64) {
        __syncthreads();
#pragma unroll
        for (int it = 0; it < 2; ++it) {
            const int row  = r0 + 64 * it;
            const int sA   = row & 7;
            const int base = row * 64;
            const int cA = ((ch0) ^ sA) * 8, cB = ((ch0 + 1) ^ sA) * 8;

            if constexpr (AF32) {
                const float* ap = Af + (size_t)(m0 + row) * lda + kt + c0;
                f32x4 v0 = *(const f32x4*)(ap);
                f32x4 v1 = *(const f32x4*)(ap + 4);
                f32x4 v2 = *(const f32x4*)(ap + 8);
                f32x4 v3 = *(const f32x4*)(ap + 12);
                short8 h0, l0, h1, l1;
                split8(v0, v1, h0, l0);
                split8(v2, v3, h1, l1);
                *(short8*)&sAh[base + cA] = h0;
                *(short8*)&sAh[base + cB] = h1;
                *(short8*)&sAl[base + cA] = l0;
                *(short8*)&sAl[base + cB] = l1;
            } else {
                const ushort_t* ahp = Agh + (size_t)(m0 + row) * lda + kt + c0;
                const ushort_t* alp = Agl + (size_t)(m0 + row) * lda + kt + c0;
                *(short8*)&sAh[base + cA] = *(const short8*)(ahp);
                *(short8*)&sAh[base + cB] = *(const short8*)(ahp + 8);
                *(short8*)&sAl[base + cA] = *(const short8*)(alp);
                *(short8*)&sAl[base + cB] = *(const short8*)(alp + 8);
            }
            const ushort_t* bhp = Bh + (size_t)(n0 + row) * K + kt + c0;
            *(short8*)&sBh[base + cA] = *(const short8*)(bhp);
            *(short8*)&sBh[base + cB] = *(const short8*)(bhp + 8);
        }
        __syncthreads();

#pragma unroll
        for (int ks = 0; ks < 2; ++ks) {
            const int chf = (((ks << 2) | l4) ^ (l16 & 7)) * 8;
            short8 fbh[4];
#pragma unroll
            for (int j = 0; j < 4; ++j) {
                const int idx = (64 * wn + 16 * j + l16) * 64 + chf;
                fbh[j] = *(const short8*)&sBh[idx];
            }
#pragma unroll
            for (int i = 0; i < 4; ++i) {
                const int idx = (64 * wm + 16 * i + l16) * 64 + chf;
                short8 fah = *(const short8*)&sAh[idx];
                short8 fal = *(const short8*)&sAl[idx];
#pragma unroll
                for (int j = 0; j < 4; ++j) {
                    acc[i][j] = MFMA_BF16(fah, fbh[j], acc[i][j]);
                    acc[i][j] = MFMA_BF16(fal, fbh[j], acc[i][j]);
                }
            }
        }
    }

    float bv[4];
#pragma unroll
    for (int j = 0; j < 4; ++j) bv[j] = bias[n0 + 64 * wn + 16 * j + l16];
#pragma unroll
    for (int i = 0; i < 4; ++i)
#pragma unroll
    for (int r = 0; r < 4; ++r) {
        const int row = m0 + 64 * wm + 16 * i + 4 * l4 + r;
        float* cp = Cg + (size_t)row * ldc + n0 + 64 * wn + l16;
#pragma unroll
        for (int j = 0; j < 4; ++j) cp[16 * j] = acc[i][j][r] + bv[j];
    }
}

// ---------------------------------------------------------------------------
// Flash attention v6: fully-bf16 attention operands (Q,K,V,P bf16; fp32
// accum). Swapped QK^T, lane-local softmax, defer-max (THR=8).
// S-phase 16 MFMA + PV 16 MFMA per wave-tile. launch_bounds(256,3): no
// forced spill (round-8 lesson: (256,4) caused 87 MB scratch traffic).
// ---------------------------------------------------------------------------
__global__ __launch_bounds__(256, 3)
void flash6(float* __restrict__ Qb,
            const ushort_t* __restrict__ Kh,
            const ushort_t* __restrict__ Vth)
{
    __shared__ ushort_t sKh[4096], sVh[4096]; // 16 KB
    __shared__ ushort_t sP[4][32 * 68];       // 17 KB

    const int i    = blockIdx.x;
    const int xcd  = i & 7;
    const int slot = i >> 3;
    const int qt   = slot & 15;
    const int bh   = ((slot >> 4) << 3) | xcd;
    const int b    = bh >> 4, h = bh & 15;

    const int tid  = threadIdx.x;
    const int lane = tid & 63;
    const int wv   = tid >> 6;
    const int l4   = lane >> 4, l16 = lane & 15;

    // ---- Q fragments (x 1/sqrt(D)), bf16 hi only, 2 q-frags per wave
    short8 qh[2][2];
    const int qr0 = qt * 128 + wv * 32;
#pragma unroll
    for (int qf = 0; qf < 2; ++qf)
#pragma unroll
    for (int sl = 0; sl < 2; ++sl) {
        const float* qp = Qb + (size_t)(b * LL + qr0 + qf * 16 + l16) * CC
                             + h * DD + sl * 32 + l4 * 8;
        f32x4 a = *(const f32x4*)qp;
        f32x4 c = *(const f32x4*)(qp + 4);
#pragma unroll
        for (int j = 0; j < 4; ++j) {
            qh[qf][sl][j]     = (short)f2bf(a[j] * 0.125f);
            qh[qf][sl][4 + j] = (short)f2bf(c[j] * 0.125f);
        }
    }

    f32x4 O[2][4];
    float mrow[2], lrow[2]; // state for q-row (qf*16 + l16), replicated over l4
#pragma unroll
    for (int qf = 0; qf < 2; ++qf) {
        mrow[qf] = -INFINITY; lrow[qf] = 0.f;
#pragma unroll
        for (int t = 0; t < 4; ++t) O[qf][t] = 0.f;
    }

    const int r_ = tid >> 2;          // staging row 0..63
    const int c2 = (tid & 3) * 2;     // chunk pair

    short8 stg[4];
    {
        const size_t kgb = ((size_t)bh * LL + r_) * DD + c2 * 8;
        const size_t vgb = ((size_t)bh * DD + r_) * LL + c2 * 8;
        stg[0] = *(const short8*)&Kh[kgb];  stg[1] = *(const short8*)&Kh[kgb + 8];
        stg[2] = *(const short8*)&Vth[vgb]; stg[3] = *(const short8*)&Vth[vgb + 8];
    }

    for (int kt = 0; kt < LL / 64; ++kt) {
        __syncthreads(); // previous tile fully consumed
        {
            const int wr = r_ * 64, s = r_ & 7;
            const int cA = ((c2) ^ s) * 8, cB = ((c2 + 1) ^ s) * 8;
            *(short8*)&sKh[wr + cA] = stg[0];
            *(short8*)&sKh[wr + cB] = stg[1];
            *(short8*)&sVh[wr + cA] = stg[2];
            *(short8*)&sVh[wr + cB] = stg[3];
        }
        __syncthreads();
        if (kt + 1 < LL / 64) { // prefetch next tile into regs
            const size_t kgb = ((size_t)bh * LL + (kt + 1) * 64 + r_) * DD + c2 * 8;
            const size_t vgb = ((size_t)bh * DD + r_) * LL + (kt + 1) * 64 + c2 * 8;
            stg[0] = *(const short8*)&Kh[kgb];  stg[1] = *(const short8*)&Kh[kgb + 8];
            stg[2] = *(const short8*)&Vth[vgb]; stg[3] = *(const short8*)&Vth[vgb + 8];
        }

        // ---- S^T = K Q : rows k (4*l4+r per tile t), cols q (l16)
        f32x4 S[2][4];
#pragma unroll
        for (int qf = 0; qf < 2; ++qf)
#pragma unroll
        for (int t = 0; t < 4; ++t) S[qf][t] = 0.f;

        __builtin_amdgcn_s_setprio(1);
#pragma unroll
        for (int t = 0; t < 4; ++t) {
            const int row = 16 * t + l16;
            const int swr = row & 7;
#pragma unroll
            for (int sl = 0; sl < 2; ++sl) {
                const int idx = row * 64 + (((sl << 2) | l4) ^ swr) * 8;
                short8 kh8 = *(const short8*)&sKh[idx];
#pragma unroll
                for (int qf = 0; qf < 2; ++qf)
                    S[qf][t] = MFMA_BF16(kh8, qh[qf][sl], S[qf][t]);
            }
        }
        __builtin_amdgcn_s_setprio(0);

        // ---- lane-local softmax (each lane owns row q = qf*16+l16, 16 ks)
#pragma unroll
        for (int qf = 0; qf < 2; ++qf) {
            float pm = S[qf][0][0];
#pragma unroll
            for (int t = 0; t < 4; ++t)
#pragma unroll
                for (int r = 0; r < 4; ++r) pm = fmaxf(pm, S[qf][t][r]);
            pm = fmaxf(pm, __shfl_xor(pm, 16));
            pm = fmaxf(pm, __shfl_xor(pm, 32));

            if (__any(pm > mrow[qf] + 8.f)) { // rescale (rare after tile 0)
                const float mnew = fmaxf(mrow[qf], pm);
                const float corr = __expf(mrow[qf] - mnew);
                mrow[qf] = mnew;
                lrow[qf] *= corr;
                float c0 = __shfl(corr, 4 * l4 + 0);
                float c1 = __shfl(corr, 4 * l4 + 1);
                float c2v = __shfl(corr, 4 * l4 + 2);
                float c3 = __shfl(corr, 4 * l4 + 3);
#pragma unroll
                for (int dt = 0; dt < 4; ++dt) {
                    O[qf][dt][0] *= c0; O[qf][dt][1] *= c1;
                    O[qf][dt][2] *= c2v; O[qf][dt][3] *= c3;
                }
            }
            float rs = 0.f;
#pragma unroll
            for (int t = 0; t < 4; ++t)
#pragma unroll
                for (int r = 0; r < 4; ++r) {
                    float p = __expf(S[qf][t][r] - mrow[qf]);
                    S[qf][t][r] = p;
                    rs += p;
                }
            rs += __shfl_xor(rs, 16);
            rs += __shfl_xor(rs, 32);
            lrow[qf] += rs;
        }

        // ---- P -> per-wave LDS (bf16 hi-only), vector b64 writes
#pragma unroll
        for (int qf = 0; qf < 2; ++qf)
#pragma unroll
        for (int t = 0; t < 4; ++t) {
            unsigned lo = (unsigned)f2bf(S[qf][t][0]) | ((unsigned)f2bf(S[qf][t][1]) << 16);
            unsigned hi = (unsigned)f2bf(S[qf][t][2]) | ((unsigned)f2bf(S[qf][t][3]) << 16);
            const int widx = (qf * 16 + l16) * 68 + 16 * t + 4 * l4;
            *(u64_t*)&sP[wv][widx] = (u64_t)lo | ((u64_t)hi << 32);
        }
        asm volatile("s_waitcnt lgkmcnt(0)" ::: "memory");
        __builtin_amdgcn_sched_barrier(0);

        // ---- P A-fragments: row q = l16, k = sl*32 + 8*l4 + j
        short8 pa[2][2];
#pragma unroll
        for (int qf = 0; qf < 2; ++qf)
#pragma unroll
        for (int sl = 0; sl < 2; ++sl) {
            const int ridx = (qf * 16 + l16) * 68 + sl * 32 + 8 * l4;
            union { u64_t q[2]; short8 s8; } u;
            u.q[0] = *(const u64_t*)&sP[wv][ridx];
            u.q[1] = *(const u64_t*)&sP[wv][ridx + 4];
            pa[qf][sl] = u.s8;
        }

        // ---- O += P V (P hi-only; V hi-only)
        __builtin_amdgcn_s_setprio(1);
#pragma unroll
        for (int dt = 0; dt < 4; ++dt) {
            const int row = 16 * dt + l16;
            const int swr = row & 7;
#pragma unroll
            for (int sl = 0; sl < 2; ++sl) {
                const int idx = row * 64 + (((sl << 2) | l4) ^ swr) * 8;
                short8 vh8 = *(const short8*)&sVh[idx];
#pragma unroll
                for (int qf = 0; qf < 2; ++qf)
                    O[qf][dt] = MFMA_BF16(pa[qf][sl], vh8, O[qf][dt]);
            }
        }
        __builtin_amdgcn_s_setprio(0);
    }

    // ---- epilogue: h = O / l over Qbuf rows (unique owner)
#pragma unroll
    for (int qf = 0; qf < 2; ++qf) {
        const float inv = 1.0f / lrow[qf];
        float i0 = __shfl(inv, 4 * l4 + 0);
        float i1 = __shfl(inv, 4 * l4 + 1);
        float i2 = __shfl(inv, 4 * l4 + 2);
        float i3 = __shfl(inv, 4 * l4 + 3);
        f32x4 iv; iv[0] = i0; iv[1] = i1; iv[2] = i2; iv[3] = i3;
#pragma unroll
        for (int r = 0; r < 4; ++r) {
            const int q = qr0 + qf * 16 + 4 * l4 + r;
            float* op = Qb + (size_t)(b * LL + q) * CC + h * DD + l16;
#pragma unroll
            for (int dt = 0; dt < 4; ++dt)
                op[16 * dt] = O[qf][dt][r] * iv[r];
        }
    }
}

// ---------------------------------------------------------------------------
// Legacy fp32 fallback kernels (only if ws_size is too small; never expected)
// ---------------------------------------------------------------------------
#define Bb 128
#define Bn 128
#define BKG 8

__global__ __launch_bounds__(256)
void gemm_bias(const float* __restrict__ A, const float* __restrict__ B,
               const float* __restrict__ bias, float* __restrict__ C,
               int M, int N, int K, int lda, int ldb, int ldc)
{
    __shared__ float As[BKG][Bb];
    __shared__ float Bs[BKG][Bn];

    const int tid = threadIdx.x;
    const int m0 = blockIdx.y * Bb;
    const int n0 = blockIdx.x * Bn;
    const int ty = tid >> 4, tx = tid & 15;
    const int arow = tid >> 1, acol = (tid & 1) * 4;
    const int brow = tid >> 5, bcol = (tid & 31) * 4;

    const float* Ap = A + (size_t)(m0 + arow) * lda + acol;
    const float* Bp = B + (size_t)brow * ldb + n0 + bcol;

    float acc[8][8];
#pragma unroll
    for (int i = 0; i < 8; ++i)
#pragma unroll
        for (int j = 0; j < 8; ++j) acc[i][j] = 0.f;

    for (int k0 = 0; k0 < K; k0 += BKG) {
        float4 av = *(const float4*)(Ap + k0);
        float4 bv = *(const float4*)(Bp + (size_t)k0 * ldb);
        __syncthreads();
        As[acol + 0][arow] = av.x;
        As[acol + 1][arow] = av.y;
        As[acol + 2][arow] = av.z;
        As[acol + 3][arow] = av.w;
        *(float4*)&Bs[brow][bcol] = bv;
        __syncthreads();
#pragma unroll
        for (int kk = 0; kk < BKG; ++kk) {
            float a[8], bvv[8];
            *(float4*)&a[0] = *(const float4*)&As[kk][ty * 4];
            *(float4*)&a[4] = *(const float4*)&As[kk][64 + ty * 4];
            *(float4*)&bvv[0] = *(const float4*)&Bs[kk][tx * 4];
            *(float4*)&bvv[4] = *(const float4*)&Bs[kk][64 + tx * 4];
#pragma unroll
            for (int i = 0; i < 8; ++i)
#pragma unroll
                for (int j = 0; j < 8; ++j)
                    acc[i][j] = fmaf(a[i], bvv[j], acc[i][j]);
        }
    }
#pragma unroll
    for (int ih = 0; ih < 2; ++ih)
#pragma unroll
    for (int i = 0; i < 4; ++i) {
        const int m = m0 + ih * 64 + ty * 4 + i;
#pragma unroll
        for (int jh = 0; jh < 2; ++jh) {
            const int n = n0 + jh * 64 + tx * 4;
            float4 o;
            o.x = acc[ih*4+i][jh*4+0] + bias[n+0];
            o.y = acc[ih*4+i][jh*4+1] + bias[n+1];
            o.z = acc[ih*4+i][jh*4+2] + bias[n+2];
            o.w = acc[ih*4+i][jh*4+3] + bias[n+3];
            *(float4*)(C + (size_t)m * ldc + n) = o;
        }
    }
}

__global__ __launch_bounds__(256)
void rmsnorm_qk(float* __restrict__ qkv,
                const float* __restrict__ gq, const float* __restrict__ gk)
{
    const int gt    = blockIdx.x * 256 + threadIdx.x;
    const int lane  = gt & 63;
    const int wave  = gt >> 6;
    const int which = wave & 1;
    const int h     = (wave >> 1) & (HH - 1);
    const int bl    = wave >> 5;

    float* p = qkv + (size_t)bl * (3 * CC) + which * CC + h * DD + lane;
    float v = *p;
    float ss = v * v;
#pragma unroll
    for (int off = 32; off; off >>= 1) ss += __shfl_xor(ss, off);
    float nrm = fmaxf(sqrtf(ss), 1e-12f);
    const float* g = which ? gk : gq;
    *p = v * (8.0f / nrm) * g[h * DD + lane];
}

__global__ __launch_bounds__(256)
void flash_fp32(float* __restrict__ qkv)
{
    const int qt = blockIdx.x, hh = blockIdx.y, bb = blockIdx.z;

    __shared__ float Qt[DD][64];
    __shared__ float Kt[DD][64];
    __shared__ float Vs[64][DD];
    __shared__ float Ps[64][64 + 4];

    const int tid = threadIdx.x;
    const int ty = tid >> 4, tx = tid & 15;
    const size_t rs_ = 3 * CC;
    const float* qbase = qkv + ((size_t)bb * LL + (size_t)qt * 64) * rs_ + hh * DD;
    const float* kbase = qkv + (size_t)bb * LL * rs_ + CC + hh * DD;
    const float* vbase = kbase + CC;

    {
        const int r = tid >> 2, c0 = (tid & 3) * 16;
#pragma unroll
        for (int u = 0; u < 4; ++u) {
            float4 v = *(const float4*)(qbase + (size_t)r * rs_ + c0 + u * 4);
            Qt[c0 + u*4 + 0][r] = v.x; Qt[c0 + u*4 + 1][r] = v.y;
            Qt[c0 + u*4 + 2][r] = v.z; Qt[c0 + u*4 + 3][r] = v.w;
        }
    }

    float mrow[4], lrow[4], O[4][4];
#pragma unroll
    for (int i = 0; i < 4; ++i) {
        mrow[i] = -INFINITY; lrow[i] = 0.f;
#pragma unroll
        for (int j = 0; j < 4; ++j) O[i][j] = 0.f;
    }

    for (int kt = 0; kt < LL / 64; ++kt) {
        __syncthreads();
        {
            const int r = tid >> 2, c0 = (tid & 3) * 16;
            const float* kr = kbase + ((size_t)kt * 64 + r) * rs_;
            const float* vr = vbase + ((size_t)kt * 64 + r) * rs_;
#pragma unroll
            for (int u = 0; u < 4; ++u) {
                float4 kv = *(const float4*)(kr + c0 + u * 4);
                Kt[c0 + u*4 + 0][r] = kv.x; Kt[c0 + u*4 + 1][r] = kv.y;
                Kt[c0 + u*4 + 2][r] = kv.z; Kt[c0 + u*4 + 3][r] = kv.w;
                *(float4*)&Vs[r][c0 + u*4] = *(const float4*)(vr + c0 + u * 4);
            }
        }
        __syncthreads();

        float S[4][4];
#pragma unroll
        for (int i = 0; i < 4; ++i)
#pragma unroll
            for (int j = 0; j < 4; ++j) S[i][j] = 0.f;
#pragma unroll 8
        for (int d = 0; d < DD; ++d) {
            float a[4], b[4];
            *(float4*)a = *(const float4*)&Qt[d][ty * 4];
            *(float4*)b = *(const float4*)&Kt[d][tx * 4];
#pragma unroll
            for (int i = 0; i < 4; ++i)
#pragma unroll
                for (int j = 0; j < 4; ++j) S[i][j] = fmaf(a[i], b[j], S[i][j]);
        }
#pragma unroll
        for (int i = 0; i < 4; ++i) {
#pragma unroll
            for (int j = 0; j < 4; ++j) S[i][j] *= 0.125f;
            float pm = fmaxf(fmaxf(S[i][0], S[i][1]), fmaxf(S[i][2], S[i][3]));
#pragma unroll
            for (int off = 1; off < 16; off <<= 1) pm = fmaxf(pm, __shfl_xor(pm, off));
            const float mnew = fmaxf(mrow[i], pm);
            const float corr = __expf(mrow[i] - mnew);
            float rsum = 0.f;
#pragma unroll
            for (int j = 0; j < 4; ++j) { S[i][j] = __expf(S[i][j] - mnew); rsum += S[i][j]; }
#pragma unroll
            for (int off = 1; off < 16; off <<= 1) rsum += __shfl_xor(rsum, off);
            mrow[i] = mnew;
            lrow[i] = lrow[i] * corr + rsum;
#pragma unroll
            for (int j = 0; j < 4; ++j) O[i][j] *= corr;
        }
#pragma unroll
        for (int i = 0; i < 4; ++i)
            *(float4*)&Ps[ty * 4 + i][tx * 4] = *(float4*)&S[i][0];
        __syncthreads();
#pragma unroll 4
        for (int k = 0; k < 64; k += 4) {
            float a[4][4];
#pragma unroll
            for (int i = 0; i < 4; ++i)
                *(float4*)&a[i][0] = *(const float4*)&Ps[ty * 4 + i][k];
#pragma unroll
            for (int kk = 0; kk < 4; ++kk) {
                float bv[4];
                *(float4*)bv = *(const float4*)&Vs[k + kk][tx * 4];
#pragma unroll
                for (int i = 0; i < 4; ++i)
#pragma unroll
                    for (int j = 0; j < 4; ++j)
                        O[i][j] = fmaf(a[i][kk], bv[j], O[i][j]);
            }
        }
    }

    float* obase = qkv + ((size_t)bb * LL + (size_t)qt * 64) * rs_ + hh * DD;
#pragma unroll
    for (int i = 0; i < 4; ++i) {
        const float inv = 1.f / lrow[i];
        float4 o;
        o.x = O[i][0] * inv; o.y = O[i][1] * inv;
        o.z = O[i][2] * inv; o.w = O[i][3] * inv;
        *(float4*)(obase + (size_t)(ty * 4 + i) * rs_ + tx * 4) = o;
    }
}

// ---------------------------------------------------------------------------
extern "C" void kernel_launch(void* const* d_in, const int* in_sizes, int n_in,
                              void* d_out, int out_size, void* d_ws, size_t ws_size,
                              hipStream_t stream)
{
    const float* x    = (const float*)d_in[0];
    const float* Wqkv = (const float*)d_in[1];
    const float* bqkv = (const float*)d_in[2];
    const float* gq   = (const float*)d_in[3];
    const float* gk   = (const float*)d_in[4];
    const float* Wout = (const float*)d_in[5];
    const float* bout = (const float*)d_in[6];
    float* out = (float*)d_out;

    const size_t T_A = 150994944ull; // + x hi/lo split
    const size_t T_B = 117440512ull; // known-good workspace size (proven available)

    if (ws_size >= T_B) {
        char* wsb = (char*)d_ws;
        float*    Qb  = (float*)wsb;                      // 32 MiB
        ushort_t* Kh  = (ushort_t*)(wsb + 33554432);      // 16 MiB
        ushort_t* Vth = (ushort_t*)(wsb + 67108864);      // 16 MiB
        ushort_t* wqh = (ushort_t*)(wsb + 100663296);     // 6 MiB
        ushort_t* woh = (ushort_t*)(wsb + 106954752);     // 2 MiB

        transp_hi<<<dim3(3 * CC / 64, CC / 64), 256, 0, stream>>>(Wqkv, wqh, CC, 3 * CC);
        transp_hi<<<dim3(CC / 64, CC / 64), 256, 0, stream>>>(Wout, woh, CC, CC);

        if (ws_size >= T_A) {
            ushort_t* xh = (ushort_t*)(wsb + 117440512);
            ushort_t* xl = (ushort_t*)(wsb + 134217728);
            split_bf16<<<dim3(MM * CC / 8 / 256), 256, 0, stream>>>(x, xh, xl, MM * CC);
            gemm_qkv<0><<<dim3(24 * 64), 256, 0, stream>>>(
                nullptr, xh, xl, wqh, bqkv, gq, gk, Qb, Kh, Vth);
        } else {
            gemm_qkv<1><<<dim3(24 * 64), 256, 0, stream>>>(
                x, nullptr, nullptr, wqh, bqkv, gq, gk, Qb, Kh, Vth);
        }

        flash6<<<dim3(1024), 256, 0, stream>>>(Qb, Kh, Vth);

        gemm_mfma<1><<<dim3(8 * 64), 256, 0, stream>>>(
            Qb, nullptr, nullptr, woh, bout, out, CC, CC, CC, CC / 128);
    } else {
        // legacy fp32 path
        float* qkv = (float*)d_ws;
        gemm_bias<<<dim3((3 * CC) / Bn, MM / Bb), 256, 0, stream>>>(
            x, Wqkv, bqkv, qkv, MM, 3 * CC, CC, CC, 3 * CC, 3 * CC);
        rmsnorm_qk<<<dim3((MM * HH * 2 * 64) / 256), 256, 0, stream>>>(qkv, gq, gk);
        flash_fp32<<<dim3(LL / 64, HH, BB), 256, 0, stream>>>(qkv);
        gemm_bias<<<dim3(CC / Bn, MM / Bb), 256, 0, stream>>>(
            qkv, Wout, bout, out, MM, CC, CC, 3 * CC, CC, CC);
    }
}

// Round 10
// 273.974 us; speedup vs baseline: 6.9444x; 1.0939x over previous
//
#include <hip/hip_runtime.h>
#include <math.h>

// Problem constants (B=4, L=2048, C=1024, H=16, D=64)
#define BB 4
#define LL 2048
#define CC 1024
#define HH 16
#define DD 64
#define MM (BB * LL) // 8192 rows

typedef float f32x4 __attribute__((ext_vector_type(4)));
typedef short short8 __attribute__((ext_vector_type(8))); // 8 bf16 (4 VGPRs)
typedef unsigned short ushort_t;
typedef unsigned long long u64_t;

#define MFMA_BF16(A, B, C) __builtin_amdgcn_mfma_f32_16x16x32_bf16(A, B, C, 0, 0, 0)

// q pre-scale: 1/sqrt(D) * log2(e), so softmax runs in exp2 domain
#define QSCALE 0.180336880f

__device__ __forceinline__ unsigned short f2bf(float x) {
    unsigned int u = __float_as_uint(x);
    u += 0x7fffu + ((u >> 16) & 1u); // RTN-even
    return (unsigned short)(u >> 16);
}
__device__ __forceinline__ float bf2f(unsigned short h) {
    return __uint_as_float(((unsigned int)h) << 16);
}
__device__ __forceinline__ void split8(const f32x4& a, const f32x4& b,
                                       short8& h, short8& l) {
#pragma unroll
    for (int j = 0; j < 4; ++j) {
        unsigned short ha = f2bf(a[j]);
        h[j] = (short)ha; l[j] = (short)f2bf(a[j] - bf2f(ha));
        unsigned short hb = f2bf(b[j]);
        h[4 + j] = (short)hb; l[4 + j] = (short)f2bf(b[j] - bf2f(hb));
    }
}

// ---------------------------------------------------------------------------
// Elementwise f32 -> bf16 hi/lo split (for x).
// ---------------------------------------------------------------------------
__global__ __launch_bounds__(256)
void split_bf16(const float* __restrict__ src, ushort_t* __restrict__ hi,
                ushort_t* __restrict__ lo, int n)
{
    const int i = (blockIdx.x * 256 + threadIdx.x) * 8;
    if (i >= n) return;
    f32x4 a = *(const f32x4*)(src + i);
    f32x4 b = *(const f32x4*)(src + i + 4);
    short8 h, l;
    split8(a, b, h, l);
    *(short8*)(hi + i) = h;
    *(short8*)(lo + i) = l;
}

// ---------------------------------------------------------------------------
// Transpose + bf16 round (hi only): W[K][N] f32 row-major -> WT[N][K] bf16.
// ---------------------------------------------------------------------------
__global__ __launch_bounds__(256)
void transp_hi(const float* __restrict__ W, ushort_t* __restrict__ Th,
               int K, int N)
{
    __shared__ float sT[64][65];
    const int k0 = blockIdx.y * 64, n0 = blockIdx.x * 64;
    const int tid = threadIdx.x;
    const int r = tid >> 2, c0 = (tid & 3) * 16;

    const float* wp = W + (size_t)(k0 + r) * N + n0 + c0;
#pragma unroll
    for (int u = 0; u < 4; ++u) {
        f32x4 v = *(const f32x4*)(wp + 4 * u);
        sT[r][c0 + 4 * u + 0] = v[0];
        sT[r][c0 + 4 * u + 1] = v[1];
        sT[r][c0 + 4 * u + 2] = v[2];
        sT[r][c0 + 4 * u + 3] = v[3];
    }
    __syncthreads();

    const int nn = tid >> 2, kk0 = (tid & 3) * 16;
    short8 h0, h1;
#pragma unroll
    for (int u = 0; u < 8; ++u) {
        h0[u] = (short)f2bf(sT[kk0 + u][nn]);
        h1[u] = (short)f2bf(sT[kk0 + 8 + u][nn]);
    }
    ushort_t* oh = Th + (size_t)(n0 + nn) * K + k0 + kk0;
    *(short8*)oh = h0; *(short8*)(oh + 8) = h1;
}

// ---------------------------------------------------------------------------
// Fused QKV GEMM (2-term split: Ah*Bh + Al*Bh; A = pre-split x, B = bf16 W).
// Epilogue: rmsnorm q -> bf16 Qbh (scaled by QSCALE), rmsnorm k -> bf16 Kh
// [b][h][l][d], v -> bf16 Vth transposed [b][h][d][l].
// ---------------------------------------------------------------------------
__global__ __launch_bounds__(256, 3)
void gemm_qkv(const ushort_t* __restrict__ Agh, const ushort_t* __restrict__ Agl,
              const ushort_t* __restrict__ Bh,
              const float* __restrict__ bias,
              const float* __restrict__ gq, const float* __restrict__ gk,
              ushort_t* __restrict__ Qbh,
              ushort_t* __restrict__ Kh,
              ushort_t* __restrict__ Vth)
{
    __shared__ ushort_t smem[24576]; // 48 KB
    ushort_t* sAh = smem;
    ushort_t* sAl = smem + 8192;
    ushort_t* sBh = smem + 16384;

    const int K = CC, lda = CC, nbx = (3 * CC) / 128; // 24

    const int nwg = gridDim.x;
    const int cpx = nwg >> 3;
    const int id  = blockIdx.x;
    const int swz = (id & 7) * cpx + (id >> 3);
    const int bx = swz % nbx, by = swz / nbx;
    const int m0 = by * 128, n0 = bx * 128;

    const int tid  = threadIdx.x;
    const int lane = tid & 63;
    const int wv   = tid >> 6;
    const int l4   = lane >> 4, l16 = lane & 15;
    const int wm   = wv >> 1,  wn  = wv & 1;

    const int r0  = tid >> 2;
    const int c0  = (tid & 3) * 16;
    const int ch0 = c0 >> 3;

    f32x4 acc[4][4];
#pragma unroll
    for (int i = 0; i < 4; ++i)
#pragma unroll
        for (int j = 0; j < 4; ++j) acc[i][j] = 0.f;

    for (int kt = 0; kt < K; kt += 64) {
        __syncthreads();
#pragma unroll
        for (int it = 0; it < 2; ++it) {
            const int row  = r0 + 64 * it;
            const int sA   = row & 7;
            const int base = row * 64;
            const int cA = ((ch0) ^ sA) * 8, cB = ((ch0 + 1) ^ sA) * 8;

            const ushort_t* ahp = Agh + (size_t)(m0 + row) * lda + kt + c0;
            const ushort_t* alp = Agl + (size_t)(m0 + row) * lda + kt + c0;
            *(short8*)&sAh[base + cA] = *(const short8*)(ahp);
            *(short8*)&sAh[base + cB] = *(const short8*)(ahp + 8);
            *(short8*)&sAl[base + cA] = *(const short8*)(alp);
            *(short8*)&sAl[base + cB] = *(const short8*)(alp + 8);
            const ushort_t* bhp = Bh + (size_t)(n0 + row) * K + kt + c0;
            *(short8*)&sBh[base + cA] = *(const short8*)(bhp);
            *(short8*)&sBh[base + cB] = *(const short8*)(bhp + 8);
        }
        __syncthreads();

#pragma unroll
        for (int ks = 0; ks < 2; ++ks) {
            const int chf = (((ks << 2) | l4) ^ (l16 & 7)) * 8;
            short8 fbh[4];
#pragma unroll
            for (int j = 0; j < 4; ++j) {
                const int idx = (64 * wn + 16 * j + l16) * 64 + chf;
                fbh[j] = *(const short8*)&sBh[idx];
            }
#pragma unroll
            for (int i = 0; i < 4; ++i) {
                const int idx = (64 * wm + 16 * i + l16) * 64 + chf;
                short8 fah = *(const short8*)&sAh[idx];
                short8 fal = *(const short8*)&sAl[idx];
#pragma unroll
                for (int j = 0; j < 4; ++j) {
                    acc[i][j] = MFMA_BF16(fah, fbh[j], acc[i][j]);
                    acc[i][j] = MFMA_BF16(fal, fbh[j], acc[i][j]);
                }
            }
        }
    }

    // ---- epilogue -------------------------------------------------------
    const int region = n0 >> 10; // 0=q, 1=k, 2=v
    float bv[4];
#pragma unroll
    for (int j = 0; j < 4; ++j) bv[j] = bias[n0 + 64 * wn + 16 * j + l16];
#pragma unroll
    for (int i = 0; i < 4; ++i)
#pragma unroll
        for (int j = 0; j < 4; ++j)
#pragma unroll
            for (int r = 0; r < 4; ++r) acc[i][j][r] += bv[j];

    const int b = m0 >> 11;

    if (region < 2) {
        const int hloc = ((n0 & 1023) >> 6) + wn;
        const float* g = (region == 0 ? gq : gk) + hloc * DD;
        float gv[4];
#pragma unroll
        for (int j = 0; j < 4; ++j) gv[j] = g[16 * j + l16];
#pragma unroll
        for (int i = 0; i < 4; ++i)
#pragma unroll
        for (int r = 0; r < 4; ++r) {
            float ss = 0.f;
#pragma unroll
            for (int j = 0; j < 4; ++j) ss += acc[i][j][r] * acc[i][j][r];
#pragma unroll
            for (int off = 1; off < 16; off <<= 1) ss += __shfl_xor(ss, off);
            const float s = 8.0f / fmaxf(sqrtf(ss), 1e-12f);
#pragma unroll
            for (int j = 0; j < 4; ++j) acc[i][j][r] *= s * gv[j];
        }

        if (region == 0) {
            // q: bf16, pre-scaled for exp2-domain softmax
#pragma unroll
            for (int i = 0; i < 4; ++i)
#pragma unroll
            for (int r = 0; r < 4; ++r) {
                const int row = m0 + 64 * wm + 16 * i + 4 * l4 + r;
                ushort_t* op = Qbh + (size_t)row * CC + n0 + 64 * wn + l16;
#pragma unroll
                for (int j = 0; j < 4; ++j)
                    op[16 * j] = f2bf(acc[i][j][r] * QSCALE);
            }
        } else {
            const int hk = ((n0 - 1024) >> 6) + wn;
#pragma unroll
            for (int i = 0; i < 4; ++i)
#pragma unroll
            for (int r = 0; r < 4; ++r) {
                const int l = (m0 & 2047) + 64 * wm + 16 * i + 4 * l4 + r;
                const size_t base = ((size_t)(b * HH + hk) * LL + l) * DD + l16;
#pragma unroll
                for (int j = 0; j < 4; ++j)
                    Kh[base + 16 * j] = f2bf(acc[i][j][r]);
            }
        }
    } else {
        // V: bf16 + 128x128 LDS transpose + vector store to [b][h][d][l]
        __syncthreads();
        ushort_t* vh = smem; // [128][128] = 32 KB (fits in 48 KB smem)
#pragma unroll
        for (int i = 0; i < 4; ++i)
#pragma unroll
        for (int r = 0; r < 4; ++r) {
            const int lr = 64 * wm + 16 * i + 4 * l4 + r;
#pragma unroll
            for (int j = 0; j < 4; ++j) {
                const int c = 64 * wn + 16 * j + l16;
                vh[lr * 128 + c] = f2bf(acc[i][j][r]);
            }
        }
        __syncthreads();
        const int c    = tid & 127;
        const int half = tid >> 7;
        const int hv   = ((n0 - 2048) >> 6) + (c >> 6);
        const int d    = c & 63;
        ushort_t* oh = Vth + ((size_t)(b * HH + hv) * DD + d) * LL + (m0 & 2047) + half * 64;
#pragma unroll
        for (int u = 0; u < 8; ++u) {
            const int l0 = half * 64 + u * 8;
            short8 hv8;
#pragma unroll
            for (int e = 0; e < 8; ++e)
                hv8[e] = (short)vh[(l0 + e) * 128 + c];
            *(short8*)&oh[u * 8] = hv8;
        }
    }
}

// ---------------------------------------------------------------------------
// Output projection, single-term bf16: out = Hb @ WoutT^T + bias.
// A = Hb [M][K] bf16, B = woh [N][K] bf16. 128x128 tile, BK=64.
// ---------------------------------------------------------------------------
__global__ __launch_bounds__(256, 3)
void gemm_out1(const ushort_t* __restrict__ Ah,
               const ushort_t* __restrict__ Bh,
               const float* __restrict__ bias, float* __restrict__ Cg)
{
    __shared__ ushort_t sAh[8192];
    __shared__ ushort_t sBh[8192];

    const int K = CC, nbx = CC / 128; // 8

    const int nwg = gridDim.x;
    const int cpx = nwg >> 3;
    const int id  = blockIdx.x;
    const int sw  = (id & 7) * cpx + (id >> 3);
    const int bx = sw % nbx, by = sw / nbx;
    const int m0 = by * 128, n0 = bx * 128;

    const int tid  = threadIdx.x;
    const int lane = tid & 63;
    const int wv   = tid >> 6;
    const int l4   = lane >> 4, l16 = lane & 15;
    const int wm   = wv >> 1,  wn  = wv & 1;

    const int r0  = tid >> 2;
    const int c0  = (tid & 3) * 16;
    const int ch0 = c0 >> 3;

    f32x4 acc[4][4];
#pragma unroll
    for (int i = 0; i < 4; ++i)
#pragma unroll
        for (int j = 0; j < 4; ++j) acc[i][j] = 0.f;

    for (int kt = 0; kt < K; kt += 64) {
        __syncthreads();
#pragma unroll
        for (int it = 0; it < 2; ++it) {
            const int row  = r0 + 64 * it;
            const int sA   = row & 7;
            const int base = row * 64;
            const int cA = ((ch0) ^ sA) * 8, cB = ((ch0 + 1) ^ sA) * 8;

            const ushort_t* ahp = Ah + (size_t)(m0 + row) * CC + kt + c0;
            *(short8*)&sAh[base + cA] = *(const short8*)(ahp);
            *(short8*)&sAh[base + cB] = *(const short8*)(ahp + 8);
            const ushort_t* bhp = Bh + (size_t)(n0 + row) * K + kt + c0;
            *(short8*)&sBh[base + cA] = *(const short8*)(bhp);
            *(short8*)&sBh[base + cB] = *(const short8*)(bhp + 8);
        }
        __syncthreads();

#pragma unroll
        for (int ks = 0; ks < 2; ++ks) {
            const int chf = (((ks << 2) | l4) ^ (l16 & 7)) * 8;
            short8 fbh[4];
#pragma unroll
            for (int j = 0; j < 4; ++j) {
                const int idx = (64 * wn + 16 * j + l16) * 64 + chf;
                fbh[j] = *(const short8*)&sBh[idx];
            }
#pragma unroll
            for (int i = 0; i < 4; ++i) {
                const int idx = (64 * wm + 16 * i + l16) * 64 + chf;
                short8 fah = *(const short8*)&sAh[idx];
#pragma unroll
                for (int j = 0; j < 4; ++j)
                    acc[i][j] = MFMA_BF16(fah, fbh[j], acc[i][j]);
            }
        }
    }

    float bv[4];
#pragma unroll
    for (int j = 0; j < 4; ++j) bv[j] = bias[n0 + 64 * wn + 16 * j + l16];
#pragma unroll
    for (int i = 0; i < 4; ++i)
#pragma unroll
    for (int r = 0; r < 4; ++r) {
        const int row = m0 + 64 * wm + 16 * i + 4 * l4 + r;
        float* cp = Cg + (size_t)row * CC + n0 + 64 * wn + l16;
#pragma unroll
        for (int j = 0; j < 4; ++j) cp[16 * j] = acc[i][j][r] + bv[j];
    }
}

// ---------------------------------------------------------------------------
// Flash attention v7: fully-bf16 operands, exp2-domain softmax (QSCALE baked
// into q), v_cvt_pk_bf16_f32 P-pack, bf16 h output. Swapped QK^T, lane-local
// softmax, defer-max (THR = 8*log2e = 11.5).
// ---------------------------------------------------------------------------
__global__ __launch_bounds__(256, 3)
void flash7(const ushort_t* __restrict__ Qbh,
            const ushort_t* __restrict__ Kh,
            const ushort_t* __restrict__ Vth,
            ushort_t* __restrict__ Hb)
{
    __shared__ ushort_t sKh[4096], sVh[4096]; // 16 KB
    __shared__ ushort_t sP[4][32 * 68];       // 17 KB

    const int i    = blockIdx.x;
    const int xcd  = i & 7;
    const int slot = i >> 3;
    const int qt   = slot & 15;
    const int bh   = ((slot >> 4) << 3) | xcd;
    const int b    = bh >> 4, h = bh & 15;

    const int tid  = threadIdx.x;
    const int lane = tid & 63;
    const int wv   = tid >> 6;
    const int l4   = lane >> 4, l16 = lane & 15;

    // ---- Q fragments: direct bf16 loads (pre-scaled in gemm_qkv epilogue)
    short8 qh[2][2];
    const int qr0 = qt * 128 + wv * 32;
#pragma unroll
    for (int qf = 0; qf < 2; ++qf)
#pragma unroll
    for (int sl = 0; sl < 2; ++sl)
        qh[qf][sl] = *(const short8*)(Qbh + (size_t)(b * LL + qr0 + qf * 16 + l16) * CC
                                      + h * DD + sl * 32 + l4 * 8);

    f32x4 O[2][4];
    float mrow[2], lrow[2]; // state for q-row (qf*16 + l16), replicated over l4
#pragma unroll
    for (int qf = 0; qf < 2; ++qf) {
        mrow[qf] = -INFINITY; lrow[qf] = 0.f;
#pragma unroll
        for (int t = 0; t < 4; ++t) O[qf][t] = 0.f;
    }

    const int r_ = tid >> 2;          // staging row 0..63
    const int c2 = (tid & 3) * 2;     // chunk pair

    short8 stg[4];
    {
        const size_t kgb = ((size_t)bh * LL + r_) * DD + c2 * 8;
        const size_t vgb = ((size_t)bh * DD + r_) * LL + c2 * 8;
        stg[0] = *(const short8*)&Kh[kgb];  stg[1] = *(const short8*)&Kh[kgb + 8];
        stg[2] = *(const short8*)&Vth[vgb]; stg[3] = *(const short8*)&Vth[vgb + 8];
    }

    for (int kt = 0; kt < LL / 64; ++kt) {
        __syncthreads(); // previous tile fully consumed
        {
            const int wr = r_ * 64, s = r_ & 7;
            const int cA = ((c2) ^ s) * 8, cB = ((c2 + 1) ^ s) * 8;
            *(short8*)&sKh[wr + cA] = stg[0];
            *(short8*)&sKh[wr + cB] = stg[1];
            *(short8*)&sVh[wr + cA] = stg[2];
            *(short8*)&sVh[wr + cB] = stg[3];
        }
        __syncthreads();
        if (kt + 1 < LL / 64) { // prefetch next tile into regs
            const size_t kgb = ((size_t)bh * LL + (kt + 1) * 64 + r_) * DD + c2 * 8;
            const size_t vgb = ((size_t)bh * DD + r_) * LL + (kt + 1) * 64 + c2 * 8;
            stg[0] = *(const short8*)&Kh[kgb];  stg[1] = *(const short8*)&Kh[kgb + 8];
            stg[2] = *(const short8*)&Vth[vgb]; stg[3] = *(const short8*)&Vth[vgb + 8];
        }

        // ---- S^T = K Q : rows k (4*l4+r per tile t), cols q (l16); log2 units
        f32x4 S[2][4];
#pragma unroll
        for (int qf = 0; qf < 2; ++qf)
#pragma unroll
        for (int t = 0; t < 4; ++t) S[qf][t] = 0.f;

        __builtin_amdgcn_s_setprio(1);
#pragma unroll
        for (int t = 0; t < 4; ++t) {
            const int row = 16 * t + l16;
            const int swr = row & 7;
#pragma unroll
            for (int sl = 0; sl < 2; ++sl) {
                const int idx = row * 64 + (((sl << 2) | l4) ^ swr) * 8;
                short8 kh8 = *(const short8*)&sKh[idx];
#pragma unroll
                for (int qf = 0; qf < 2; ++qf)
                    S[qf][t] = MFMA_BF16(kh8, qh[qf][sl], S[qf][t]);
            }
        }
        __builtin_amdgcn_s_setprio(0);

        // ---- lane-local softmax (exp2 domain)
#pragma unroll
        for (int qf = 0; qf < 2; ++qf) {
            float pm = S[qf][0][0];
#pragma unroll
            for (int t = 0; t < 4; ++t)
#pragma unroll
                for (int r = 0; r < 4; ++r) pm = fmaxf(pm, S[qf][t][r]);
            pm = fmaxf(pm, __shfl_xor(pm, 16));
            pm = fmaxf(pm, __shfl_xor(pm, 32));

            if (__any(pm > mrow[qf] + 11.5f)) { // rescale (rare after tile 0)
                const float mnew = fmaxf(mrow[qf], pm);
                const float corr = exp2f(mrow[qf] - mnew);
                mrow[qf] = mnew;
                lrow[qf] *= corr;
                float c0 = __shfl(corr, 4 * l4 + 0);
                float c1 = __shfl(corr, 4 * l4 + 1);
                float c2v = __shfl(corr, 4 * l4 + 2);
                float c3 = __shfl(corr, 4 * l4 + 3);
#pragma unroll
                for (int dt = 0; dt < 4; ++dt) {
                    O[qf][dt][0] *= c0; O[qf][dt][1] *= c1;
                    O[qf][dt][2] *= c2v; O[qf][dt][3] *= c3;
                }
            }
            float rs = 0.f;
#pragma unroll
            for (int t = 0; t < 4; ++t)
#pragma unroll
                for (int r = 0; r < 4; ++r) {
                    float p = exp2f(S[qf][t][r] - mrow[qf]);
                    S[qf][t][r] = p;
                    rs += p;
                }
            rs += __shfl_xor(rs, 16);
            rs += __shfl_xor(rs, 32);
            lrow[qf] += rs;
        }

        // ---- P -> per-wave LDS (bf16), v_cvt_pk_bf16_f32 + b64 writes
#pragma unroll
        for (int qf = 0; qf < 2; ++qf)
#pragma unroll
        for (int t = 0; t < 4; ++t) {
            unsigned lo, hi;
            asm("v_cvt_pk_bf16_f32 %0, %1, %2" : "=v"(lo)
                : "v"(S[qf][t][0]), "v"(S[qf][t][1]));
            asm("v_cvt_pk_bf16_f32 %0, %1, %2" : "=v"(hi)
                : "v"(S[qf][t][2]), "v"(S[qf][t][3]));
            const int widx = (qf * 16 + l16) * 68 + 16 * t + 4 * l4;
            *(u64_t*)&sP[wv][widx] = (u64_t)lo | ((u64_t)hi << 32);
        }
        asm volatile("s_waitcnt lgkmcnt(0)" ::: "memory");
        __builtin_amdgcn_sched_barrier(0);

        // ---- P A-fragments: row q = l16, k = sl*32 + 8*l4 + j
        short8 pa[2][2];
#pragma unroll
        for (int qf = 0; qf < 2; ++qf)
#pragma unroll
        for (int sl = 0; sl < 2; ++sl) {
            const int ridx = (qf * 16 + l16) * 68 + sl * 32 + 8 * l4;
            union { u64_t q[2]; short8 s8; } u;
            u.q[0] = *(const u64_t*)&sP[wv][ridx];
            u.q[1] = *(const u64_t*)&sP[wv][ridx + 4];
            pa[qf][sl] = u.s8;
        }

        // ---- O += P V
        __builtin_amdgcn_s_setprio(1);
#pragma unroll
        for (int dt = 0; dt < 4; ++dt) {
            const int row = 16 * dt + l16;
            const int swr = row & 7;
#pragma unroll
            for (int sl = 0; sl < 2; ++sl) {
                const int idx = row * 64 + (((sl << 2) | l4) ^ swr) * 8;
                short8 vh8 = *(const short8*)&sVh[idx];
#pragma unroll
                for (int qf = 0; qf < 2; ++qf)
                    O[qf][dt] = MFMA_BF16(pa[qf][sl], vh8, O[qf][dt]);
            }
        }
        __builtin_amdgcn_s_setprio(0);
    }

    // ---- epilogue: h = O / l -> bf16 Hb rows
#pragma unroll
    for (int qf = 0; qf < 2; ++qf) {
        const float inv = 1.0f / lrow[qf];
        float i0 = __shfl(inv, 4 * l4 + 0);
        float i1 = __shfl(inv, 4 * l4 + 1);
        float i2 = __shfl(inv, 4 * l4 + 2);
        float i3 = __shfl(inv, 4 * l4 + 3);
        f32x4 iv; iv[0] = i0; iv[1] = i1; iv[2] = i2; iv[3] = i3;
#pragma unroll
        for (int r = 0; r < 4; ++r) {
            const int q = qr0 + qf * 16 + 4 * l4 + r;
            ushort_t* op = Hb + (size_t)(b * LL + q) * CC + h * DD + l16;
#pragma unroll
            for (int dt = 0; dt < 4; ++dt)
                op[16 * dt] = f2bf(O[qf][dt][r] * iv[r]);
        }
    }
}

// ---------------------------------------------------------------------------
// Legacy fp32 fallback kernels (only if ws_size is too small; never expected)
// ---------------------------------------------------------------------------
#define Bb 128
#define Bn 128
#define BKG 8

__global__ __launch_bounds__(256)
void gemm_bias(const float* __restrict__ A, const float* __restrict__ B,
               const float* __restrict__ bias, float* __restrict__ C,
               int M, int N, int K, int lda, int ldb, int ldc)
{
    __shared__ float As[BKG][Bb];
    __shared__ float Bs[BKG][Bn];

    const int tid = threadIdx.x;
    const int m0 = blockIdx.y * Bb;
    const int n0 = blockIdx.x * Bn;
    const int ty = tid >> 4, tx = tid & 15;
    const int arow = tid >> 1, acol = (tid & 1) * 4;
    const int brow = tid >> 5, bcol = (tid & 31) * 4;

    const float* Ap = A + (size_t)(m0 + arow) * lda + acol;
    const float* Bp = B + (size_t)brow * ldb + n0 + bcol;

    float acc[8][8];
#pragma unroll
    for (int i = 0; i < 8; ++i)
#pragma unroll
        for (int j = 0; j < 8; ++j) acc[i][j] = 0.f;

    for (int k0 = 0; k0 < K; k0 += BKG) {
        float4 av = *(const float4*)(Ap + k0);
        float4 bv = *(const float4*)(Bp + (size_t)k0 * ldb);
        __syncthreads();
        As[acol + 0][arow] = av.x;
        As[acol + 1][arow] = av.y;
        As[acol + 2][arow] = av.z;
        As[acol + 3][arow] = av.w;
        *(float4*)&Bs[brow][bcol] = bv;
        __syncthreads();
#pragma unroll
        for (int kk = 0; kk < BKG; ++kk) {
            float a[8], bvv[8];
            *(float4*)&a[0] = *(const float4*)&As[kk][ty * 4];
            *(float4*)&a[4] = *(const float4*)&As[kk][64 + ty * 4];
            *(float4*)&bvv[0] = *(const float4*)&Bs[kk][tx * 4];
            *(float4*)&bvv[4] = *(const float4*)&Bs[kk][64 + tx * 4];
#pragma unroll
            for (int i = 0; i < 8; ++i)
#pragma unroll
                for (int j = 0; j < 8; ++j)
                    acc[i][j] = fmaf(a[i], bvv[j], acc[i][j]);
        }
    }
#pragma unroll
    for (int ih = 0; ih < 2; ++ih)
#pragma unroll
    for (int i = 0; i < 4; ++i) {
        const int m = m0 + ih * 64 + ty * 4 + i;
#pragma unroll
        for (int jh = 0; jh < 2; ++jh) {
            const int n = n0 + jh * 64 + tx * 4;
            float4 o;
            o.x = acc[ih*4+i][jh*4+0] + bias[n+0];
            o.y = acc[ih*4+i][jh*4+1] + bias[n+1];
            o.z = acc[ih*4+i][jh*4+2] + bias[n+2];
            o.w = acc[ih*4+i][jh*4+3] + bias[n+3];
            *(float4*)(C + (size_t)m * ldc + n) = o;
        }
    }
}

__global__ __launch_bounds__(256)
void rmsnorm_qk(float* __restrict__ qkv,
                const float* __restrict__ gq, const float* __restrict__ gk)
{
    const int gt    = blockIdx.x * 256 + threadIdx.x;
    const int lane  = gt & 63;
    const int wave  = gt >> 6;
    const int which = wave & 1;
    const int h     = (wave >> 1) & (HH - 1);
    const int bl    = wave >> 5;

    float* p = qkv + (size_t)bl * (3 * CC) + which * CC + h * DD + lane;
    float v = *p;
    float ss = v * v;
#pragma unroll
    for (int off = 32; off; off >>= 1) ss += __shfl_xor(ss, off);
    float nrm = fmaxf(sqrtf(ss), 1e-12f);
    const float* g = which ? gk : gq;
    *p = v * (8.0f / nrm) * g[h * DD + lane];
}

__global__ __launch_bounds__(256)
void flash_fp32(float* __restrict__ qkv)
{
    const int qt = blockIdx.x, hh = blockIdx.y, bb = blockIdx.z;

    __shared__ float Qt[DD][64];
    __shared__ float Kt[DD][64];
    __shared__ float Vs[64][DD];
    __shared__ float Ps[64][64 + 4];

    const int tid = threadIdx.x;
    const int ty = tid >> 4, tx = tid & 15;
    const size_t rs_ = 3 * CC;
    const float* qbase = qkv + ((size_t)bb * LL + (size_t)qt * 64) * rs_ + hh * DD;
    const float* kbase = qkv + (size_t)bb * LL * rs_ + CC + hh * DD;
    const float* vbase = kbase + CC;

    {
        const int r = tid >> 2, c0 = (tid & 3) * 16;
#pragma unroll
        for (int u = 0; u < 4; ++u) {
            float4 v = *(const float4*)(qbase + (size_t)r * rs_ + c0 + u * 4);
            Qt[c0 + u*4 + 0][r] = v.x; Qt[c0 + u*4 + 1][r] = v.y;
            Qt[c0 + u*4 + 2][r] = v.z; Qt[c0 + u*4 + 3][r] = v.w;
        }
    }

    float mrow[4], lrow[4], O[4][4];
#pragma unroll
    for (int i = 0; i < 4; ++i) {
        mrow[i] = -INFINITY; lrow[i] = 0.f;
#pragma unroll
        for (int j = 0; j < 4; ++j) O[i][j] = 0.f;
    }

    for (int kt = 0; kt < LL / 64; ++kt) {
        __syncthreads();
        {
            const int r = tid >> 2, c0 = (tid & 3) * 16;
            const float* kr = kbase + ((size_t)kt * 64 + r) * rs_;
            const float* vr = vbase + ((size_t)kt * 64 + r) * rs_;
#pragma unroll
            for (int u = 0; u < 4; ++u) {
                float4 kv = *(const float4*)(kr + c0 + u * 4);
                Kt[c0 + u*4 + 0][r] = kv.x; Kt[c0 + u*4 + 1][r] = kv.y;
                Kt[c0 + u*4 + 2][r] = kv.z; Kt[c0 + u*4 + 3][r] = kv.w;
                *(float4*)&Vs[r][c0 + u*4] = *(const float4*)(vr + c0 + u * 4);
            }
        }
        __syncthreads();

        float S[4][4];
#pragma unroll
        for (int i = 0; i < 4; ++i)
#pragma unroll
            for (int j = 0; j < 4; ++j) S[i][j] = 0.f;
#pragma unroll 8
        for (int d = 0; d < DD; ++d) {
            float a[4], b[4];
            *(float4*)a = *(const float4*)&Qt[d][ty * 4];
            *(float4*)b = *(const float4*)&Kt[d][tx * 4];
#pragma unroll
            for (int i = 0; i < 4; ++i)
#pragma unroll
                for (int j = 0; j < 4; ++j) S[i][j] = fmaf(a[i], b[j], S[i][j]);
        }
#pragma unroll
        for (int i = 0; i < 4; ++i) {
#pragma unroll
            for (int j = 0; j < 4; ++j) S[i][j] *= 0.125f;
            float pm = fmaxf(fmaxf(S[i][0], S[i][1]), fmaxf(S[i][2], S[i][3]));
#pragma unroll
            for (int off = 1; off < 16; off <<= 1) pm = fmaxf(pm, __shfl_xor(pm, off));
            const float mnew = fmaxf(mrow[i], pm);
            const float corr = __expf(mrow[i] - mnew);
            float rsum = 0.f;
#pragma unroll
            for (int j = 0; j < 4; ++j) { S[i][j] = __expf(S[i][j] - mnew); rsum += S[i][j]; }
#pragma unroll
            for (int off = 1; off < 16; off <<= 1) rsum += __shfl_xor(rsum, off);
            mrow[i] = mnew;
            lrow[i] = lrow[i] * corr + rsum;
#pragma unroll
            for (int j = 0; j < 4; ++j) O[i][j] *= corr;
        }
#pragma unroll
        for (int i = 0; i < 4; ++i)
            *(float4*)&Ps[ty * 4 + i][tx * 4] = *(float4*)&S[i][0];
        __syncthreads();
#pragma unroll 4
        for (int k = 0; k < 64; k += 4) {
            float a[4][4];
#pragma unroll
            for (int i = 0; i < 4; ++i)
                *(float4*)&a[i][0] = *(const float4*)&Ps[ty * 4 + i][k];
#pragma unroll
            for (int kk = 0; kk < 4; ++kk) {
                float bv[4];
                *(float4*)bv = *(const float4*)&Vs[k + kk][tx * 4];
#pragma unroll
                for (int i = 0; i < 4; ++i)
#pragma unroll
                    for (int j = 0; j < 4; ++j)
                        O[i][j] = fmaf(a[i][kk], bv[j], O[i][j]);
            }
        }
    }

    float* obase = qkv + ((size_t)bb * LL + (size_t)qt * 64) * rs_ + hh * DD;
#pragma unroll
    for (int i = 0; i < 4; ++i) {
        const float inv = 1.f / lrow[i];
        float4 o;
        o.x = O[i][0] * inv; o.y = O[i][1] * inv;
        o.z = O[i][2] * inv; o.w = O[i][3] * inv;
        *(float4*)(obase + (size_t)(ty * 4 + i) * rs_ + tx * 4) = o;
    }
}

// ---------------------------------------------------------------------------
extern "C" void kernel_launch(void* const* d_in, const int* in_sizes, int n_in,
                              void* d_out, int out_size, void* d_ws, size_t ws_size,
                              hipStream_t stream)
{
    const float* x    = (const float*)d_in[0];
    const float* Wqkv = (const float*)d_in[1];
    const float* bqkv = (const float*)d_in[2];
    const float* gq   = (const float*)d_in[3];
    const float* gk   = (const float*)d_in[4];
    const float* Wout = (const float*)d_in[5];
    const float* bout = (const float*)d_in[6];
    float* out = (float*)d_out;

    const size_t NEED = 109051904ull; // 104 MiB

    if (ws_size >= NEED) {
        char* wsb = (char*)d_ws;
        ushort_t* Qbh = (ushort_t*)(wsb);                 // 16 MiB
        ushort_t* Kh  = (ushort_t*)(wsb + 16777216);      // 16 MiB
        ushort_t* Vth = (ushort_t*)(wsb + 33554432);      // 16 MiB
        ushort_t* Hb  = (ushort_t*)(wsb + 50331648);      // 16 MiB
        ushort_t* wqh = (ushort_t*)(wsb + 67108864);      // 6 MiB
        ushort_t* woh = (ushort_t*)(wsb + 73400320);      // 2 MiB
        ushort_t* xh  = (ushort_t*)(wsb + 75497472);      // 16 MiB
        ushort_t* xl  = (ushort_t*)(wsb + 92274688);      // 16 MiB

        transp_hi<<<dim3(3 * CC / 64, CC / 64), 256, 0, stream>>>(Wqkv, wqh, CC, 3 * CC);
        transp_hi<<<dim3(CC / 64, CC / 64), 256, 0, stream>>>(Wout, woh, CC, CC);
        split_bf16<<<dim3(MM * CC / 8 / 256), 256, 0, stream>>>(x, xh, xl, MM * CC);

        gemm_qkv<<<dim3(24 * 64), 256, 0, stream>>>(
            xh, xl, wqh, bqkv, gq, gk, Qbh, Kh, Vth);

        flash7<<<dim3(1024), 256, 0, stream>>>(Qbh, Kh, Vth, Hb);

        gemm_out1<<<dim3(8 * 64), 256, 0, stream>>>(Hb, woh, bout, out);
    } else {
        // legacy fp32 path
        float* qkv = (float*)d_ws;
        gemm_bias<<<dim3((3 * CC) / Bn, MM / Bb), 256, 0, stream>>>(
            x, Wqkv, bqkv, qkv, MM, 3 * CC, CC, CC, 3 * CC, 3 * CC);
        rmsnorm_qk<<<dim3((MM * HH * 2 * 64) / 256), 256, 0, stream>>>(qkv, gq, gk);
        flash_fp32<<<dim3(LL / 64, HH, BB), 256, 0, stream>>>(qkv);
        gemm_bias<<<dim3(CC / Bn, MM / Bb), 256, 0, stream>>>(
            qkv, Wout, bout, out, MM, CC, CC, 3 * CC, CC, CC);
    }
}

// Round 11
// 241.659 us; speedup vs baseline: 7.8730x; 1.1337x over previous
//
#include <hip/hip_runtime.h>
#include <math.h>

// Problem constants (B=4, L=2048, C=1024, H=16, D=64)
#define BB 4
#define LL 2048
#define CC 1024
#define HH 16
#define DD 64
#define MM (BB * LL) // 8192 rows

typedef float f32x4 __attribute__((ext_vector_type(4)));
typedef short short8 __attribute__((ext_vector_type(8))); // 8 bf16 (4 VGPRs)
typedef unsigned short ushort_t;
typedef unsigned long long u64_t;

#define MFMA_BF16(A, B, C) __builtin_amdgcn_mfma_f32_16x16x32_bf16(A, B, C, 0, 0, 0)

// q pre-scale: 1/sqrt(D) * log2(e), so softmax runs in exp2 domain
#define QSCALE 0.180336880f

__device__ __forceinline__ unsigned short f2bf(float x) {
    unsigned int u = __float_as_uint(x);
    u += 0x7fffu + ((u >> 16) & 1u); // RTN-even
    return (unsigned short)(u >> 16);
}
__device__ __forceinline__ float bf2f(unsigned short h) {
    return __uint_as_float(((unsigned int)h) << 16);
}

// ---------------------------------------------------------------------------
// Elementwise f32 -> bf16 round (for x).
// ---------------------------------------------------------------------------
__global__ __launch_bounds__(256)
void round_bf16(const float* __restrict__ src, ushort_t* __restrict__ dst, int n)
{
    const int i = (blockIdx.x * 256 + threadIdx.x) * 8;
    if (i >= n) return;
    f32x4 a = *(const f32x4*)(src + i);
    f32x4 b = *(const f32x4*)(src + i + 4);
    short8 h;
#pragma unroll
    for (int j = 0; j < 4; ++j) {
        h[j]     = (short)f2bf(a[j]);
        h[4 + j] = (short)f2bf(b[j]);
    }
    *(short8*)(dst + i) = h;
}

// ---------------------------------------------------------------------------
// Transpose + bf16 round: W[K][N] f32 row-major -> WT[N][K] bf16.
// ---------------------------------------------------------------------------
__global__ __launch_bounds__(256)
void transp_hi(const float* __restrict__ W, ushort_t* __restrict__ Th,
               int K, int N)
{
    __shared__ float sT[64][65];
    const int k0 = blockIdx.y * 64, n0 = blockIdx.x * 64;
    const int tid = threadIdx.x;
    const int r = tid >> 2, c0 = (tid & 3) * 16;

    const float* wp = W + (size_t)(k0 + r) * N + n0 + c0;
#pragma unroll
    for (int u = 0; u < 4; ++u) {
        f32x4 v = *(const f32x4*)(wp + 4 * u);
        sT[r][c0 + 4 * u + 0] = v[0];
        sT[r][c0 + 4 * u + 1] = v[1];
        sT[r][c0 + 4 * u + 2] = v[2];
        sT[r][c0 + 4 * u + 3] = v[3];
    }
    __syncthreads();

    const int nn = tid >> 2, kk0 = (tid & 3) * 16;
    short8 h0, h1;
#pragma unroll
    for (int u = 0; u < 8; ++u) {
        h0[u] = (short)f2bf(sT[kk0 + u][nn]);
        h1[u] = (short)f2bf(sT[kk0 + 8 + u][nn]);
    }
    ushort_t* oh = Th + (size_t)(n0 + nn) * K + k0 + kk0;
    *(short8*)oh = h0; *(short8*)(oh + 8) = h1;
}

// ---------------------------------------------------------------------------
// Fused QKV GEMM, single-term bf16 (A = bf16 x, B = bf16 W^T).
// Epilogue: rmsnorm q -> bf16 Qbh (scaled by QSCALE), rmsnorm k -> bf16 Kh
// [b][h][l][d], v -> bf16 Vth transposed [b][h][d][l].
// ---------------------------------------------------------------------------
__global__ __launch_bounds__(256, 3)
void gemm_qkv(const ushort_t* __restrict__ Agh,
              const ushort_t* __restrict__ Bh,
              const float* __restrict__ bias,
              const float* __restrict__ gq, const float* __restrict__ gk,
              ushort_t* __restrict__ Qbh,
              ushort_t* __restrict__ Kh,
              ushort_t* __restrict__ Vth)
{
    __shared__ ushort_t smem[16384]; // 32 KB
    ushort_t* sAh = smem;
    ushort_t* sBh = smem + 8192;

    const int K = CC, lda = CC, nbx = (3 * CC) / 128; // 24

    const int nwg = gridDim.x;
    const int cpx = nwg >> 3;
    const int id  = blockIdx.x;
    const int swz = (id & 7) * cpx + (id >> 3);
    const int bx = swz % nbx, by = swz / nbx;
    const int m0 = by * 128, n0 = bx * 128;

    const int tid  = threadIdx.x;
    const int lane = tid & 63;
    const int wv   = tid >> 6;
    const int l4   = lane >> 4, l16 = lane & 15;
    const int wm   = wv >> 1,  wn  = wv & 1;

    const int r0  = tid >> 2;
    const int c0  = (tid & 3) * 16;
    const int ch0 = c0 >> 3;

    f32x4 acc[4][4];
#pragma unroll
    for (int i = 0; i < 4; ++i)
#pragma unroll
        for (int j = 0; j < 4; ++j) acc[i][j] = 0.f;

    for (int kt = 0; kt < K; kt += 64) {
        __syncthreads();
#pragma unroll
        for (int it = 0; it < 2; ++it) {
            const int row  = r0 + 64 * it;
            const int sA   = row & 7;
            const int base = row * 64;
            const int cA = ((ch0) ^ sA) * 8, cB = ((ch0 + 1) ^ sA) * 8;

            const ushort_t* ahp = Agh + (size_t)(m0 + row) * lda + kt + c0;
            *(short8*)&sAh[base + cA] = *(const short8*)(ahp);
            *(short8*)&sAh[base + cB] = *(const short8*)(ahp + 8);
            const ushort_t* bhp = Bh + (size_t)(n0 + row) * K + kt + c0;
            *(short8*)&sBh[base + cA] = *(const short8*)(bhp);
            *(short8*)&sBh[base + cB] = *(const short8*)(bhp + 8);
        }
        __syncthreads();

#pragma unroll
        for (int ks = 0; ks < 2; ++ks) {
            const int chf = (((ks << 2) | l4) ^ (l16 & 7)) * 8;
            short8 fbh[4];
#pragma unroll
            for (int j = 0; j < 4; ++j) {
                const int idx = (64 * wn + 16 * j + l16) * 64 + chf;
                fbh[j] = *(const short8*)&sBh[idx];
            }
#pragma unroll
            for (int i = 0; i < 4; ++i) {
                const int idx = (64 * wm + 16 * i + l16) * 64 + chf;
                short8 fah = *(const short8*)&sAh[idx];
#pragma unroll
                for (int j = 0; j < 4; ++j)
                    acc[i][j] = MFMA_BF16(fah, fbh[j], acc[i][j]);
            }
        }
    }

    // ---- epilogue -------------------------------------------------------
    const int region = n0 >> 10; // 0=q, 1=k, 2=v
    float bv[4];
#pragma unroll
    for (int j = 0; j < 4; ++j) bv[j] = bias[n0 + 64 * wn + 16 * j + l16];
#pragma unroll
    for (int i = 0; i < 4; ++i)
#pragma unroll
        for (int j = 0; j < 4; ++j)
#pragma unroll
            for (int r = 0; r < 4; ++r) acc[i][j][r] += bv[j];

    const int b = m0 >> 11;

    if (region < 2) {
        const int hloc = ((n0 & 1023) >> 6) + wn;
        const float* g = (region == 0 ? gq : gk) + hloc * DD;
        float gv[4];
#pragma unroll
        for (int j = 0; j < 4; ++j) gv[j] = g[16 * j + l16];
#pragma unroll
        for (int i = 0; i < 4; ++i)
#pragma unroll
        for (int r = 0; r < 4; ++r) {
            float ss = 0.f;
#pragma unroll
            for (int j = 0; j < 4; ++j) ss += acc[i][j][r] * acc[i][j][r];
#pragma unroll
            for (int off = 1; off < 16; off <<= 1) ss += __shfl_xor(ss, off);
            const float s = 8.0f / fmaxf(sqrtf(ss), 1e-12f);
#pragma unroll
            for (int j = 0; j < 4; ++j) acc[i][j][r] *= s * gv[j];
        }

        if (region == 0) {
            // q: bf16, pre-scaled for exp2-domain softmax
#pragma unroll
            for (int i = 0; i < 4; ++i)
#pragma unroll
            for (int r = 0; r < 4; ++r) {
                const int row = m0 + 64 * wm + 16 * i + 4 * l4 + r;
                ushort_t* op = Qbh + (size_t)row * CC + n0 + 64 * wn + l16;
#pragma unroll
                for (int j = 0; j < 4; ++j)
                    op[16 * j] = f2bf(acc[i][j][r] * QSCALE);
            }
        } else {
            const int hk = ((n0 - 1024) >> 6) + wn;
#pragma unroll
            for (int i = 0; i < 4; ++i)
#pragma unroll
            for (int r = 0; r < 4; ++r) {
                const int l = (m0 & 2047) + 64 * wm + 16 * i + 4 * l4 + r;
                const size_t base = ((size_t)(b * HH + hk) * LL + l) * DD + l16;
#pragma unroll
                for (int j = 0; j < 4; ++j)
                    Kh[base + 16 * j] = f2bf(acc[i][j][r]);
            }
        }
    } else {
        // V: bf16 + 128x128 LDS transpose + vector store to [b][h][d][l]
        __syncthreads();
        ushort_t* vh = smem; // [128][128] = 32 KB exactly
#pragma unroll
        for (int i = 0; i < 4; ++i)
#pragma unroll
        for (int r = 0; r < 4; ++r) {
            const int lr = 64 * wm + 16 * i + 4 * l4 + r;
#pragma unroll
            for (int j = 0; j < 4; ++j) {
                const int c = 64 * wn + 16 * j + l16;
                vh[lr * 128 + c] = f2bf(acc[i][j][r]);
            }
        }
        __syncthreads();
        const int c    = tid & 127;
        const int half = tid >> 7;
        const int hv   = ((n0 - 2048) >> 6) + (c >> 6);
        const int d    = c & 63;
        ushort_t* oh = Vth + ((size_t)(b * HH + hv) * DD + d) * LL + (m0 & 2047) + half * 64;
#pragma unroll
        for (int u = 0; u < 8; ++u) {
            const int l0 = half * 64 + u * 8;
            short8 hv8;
#pragma unroll
            for (int e = 0; e < 8; ++e)
                hv8[e] = (short)vh[(l0 + e) * 128 + c];
            *(short8*)&oh[u * 8] = hv8;
        }
    }
}

// ---------------------------------------------------------------------------
// Output projection, single-term bf16: out = Hb @ WoutT^T + bias.
// ---------------------------------------------------------------------------
__global__ __launch_bounds__(256, 3)
void gemm_out1(const ushort_t* __restrict__ Ah,
               const ushort_t* __restrict__ Bh,
               const float* __restrict__ bias, float* __restrict__ Cg)
{
    __shared__ ushort_t sAh[8192];
    __shared__ ushort_t sBh[8192];

    const int K = CC, nbx = CC / 128; // 8

    const int nwg = gridDim.x;
    const int cpx = nwg >> 3;
    const int id  = blockIdx.x;
    const int sw  = (id & 7) * cpx + (id >> 3);
    const int bx = sw % nbx, by = sw / nbx;
    const int m0 = by * 128, n0 = bx * 128;

    const int tid  = threadIdx.x;
    const int lane = tid & 63;
    const int wv   = tid >> 6;
    const int l4   = lane >> 4, l16 = lane & 15;
    const int wm   = wv >> 1,  wn  = wv & 1;

    const int r0  = tid >> 2;
    const int c0  = (tid & 3) * 16;
    const int ch0 = c0 >> 3;

    f32x4 acc[4][4];
#pragma unroll
    for (int i = 0; i < 4; ++i)
#pragma unroll
        for (int j = 0; j < 4; ++j) acc[i][j] = 0.f;

    for (int kt = 0; kt < K; kt += 64) {
        __syncthreads();
#pragma unroll
        for (int it = 0; it < 2; ++it) {
            const int row  = r0 + 64 * it;
            const int sA   = row & 7;
            const int base = row * 64;
            const int cA = ((ch0) ^ sA) * 8, cB = ((ch0 + 1) ^ sA) * 8;

            const ushort_t* ahp = Ah + (size_t)(m0 + row) * CC + kt + c0;
            *(short8*)&sAh[base + cA] = *(const short8*)(ahp);
            *(short8*)&sAh[base + cB] = *(const short8*)(ahp + 8);
            const ushort_t* bhp = Bh + (size_t)(n0 + row) * K + kt + c0;
            *(short8*)&sBh[base + cA] = *(const short8*)(bhp);
            *(short8*)&sBh[base + cB] = *(const short8*)(bhp + 8);
        }
        __syncthreads();

#pragma unroll
        for (int ks = 0; ks < 2; ++ks) {
            const int chf = (((ks << 2) | l4) ^ (l16 & 7)) * 8;
            short8 fbh[4];
#pragma unroll
            for (int j = 0; j < 4; ++j) {
                const int idx = (64 * wn + 16 * j + l16) * 64 + chf;
                fbh[j] = *(const short8*)&sBh[idx];
            }
#pragma unroll
            for (int i = 0; i < 4; ++i) {
                const int idx = (64 * wm + 16 * i + l16) * 64 + chf;
                short8 fah = *(const short8*)&sAh[idx];
#pragma unroll
                for (int j = 0; j < 4; ++j)
                    acc[i][j] = MFMA_BF16(fah, fbh[j], acc[i][j]);
            }
        }
    }

    float bv[4];
#pragma unroll
    for (int j = 0; j < 4; ++j) bv[j] = bias[n0 + 64 * wn + 16 * j + l16];
#pragma unroll
    for (int i = 0; i < 4; ++i)
#pragma unroll
    for (int r = 0; r < 4; ++r) {
        const int row = m0 + 64 * wm + 16 * i + 4 * l4 + r;
        float* cp = Cg + (size_t)row * CC + n0 + 64 * wn + l16;
#pragma unroll
        for (int j = 0; j < 4; ++j) cp[16 * j] = acc[i][j][r] + bv[j];
    }
}

// ---------------------------------------------------------------------------
// Flash attention v8: fully-bf16 operands, exp2-domain softmax, scalar f2bf
// P-pack (m240: don't hand-write cvt_pk), row-sum l via MFMA(P, ones) so
// the denominator lives in O's register layout (no shfl chains).
// ---------------------------------------------------------------------------
__global__ __launch_bounds__(256, 3)
void flash8(const ushort_t* __restrict__ Qbh,
            const ushort_t* __restrict__ Kh,
            const ushort_t* __restrict__ Vth,
            ushort_t* __restrict__ Hb)
{
    __shared__ ushort_t sKh[4096], sVh[4096]; // 16 KB
    __shared__ ushort_t sP[4][32 * 68];       // 17 KB

    const int i    = blockIdx.x;
    const int xcd  = i & 7;
    const int slot = i >> 3;
    const int qt   = slot & 15;
    const int bh   = ((slot >> 4) << 3) | xcd;
    const int b    = bh >> 4, h = bh & 15;

    const int tid  = threadIdx.x;
    const int lane = tid & 63;
    const int wv   = tid >> 6;
    const int l4   = lane >> 4, l16 = lane & 15;

    // ---- Q fragments: direct bf16 loads (pre-scaled in gemm_qkv epilogue)
    short8 qh[2][2];
    const int qr0 = qt * 128 + wv * 32;
#pragma unroll
    for (int qf = 0; qf < 2; ++qf)
#pragma unroll
    for (int sl = 0; sl < 2; ++sl)
        qh[qf][sl] = *(const short8*)(Qbh + (size_t)(b * LL + qr0 + qf * 16 + l16) * CC
                                      + h * DD + sl * 32 + l4 * 8);

    // bf16 1.0 vector for the MFMA row-sum
    short8 ones;
#pragma unroll
    for (int j = 0; j < 8; ++j) ones[j] = (short)0x3F80;

    f32x4 O[2][4];
    f32x4 acc_l[2];   // row-sum of P, layout q = 4*l4 + r (same as O rows)
    float mrow[2];    // running max for q-row (qf*16 + l16)
#pragma unroll
    for (int qf = 0; qf < 2; ++qf) {
        mrow[qf] = -INFINITY; acc_l[qf] = 0.f;
#pragma unroll
        for (int t = 0; t < 4; ++t) O[qf][t] = 0.f;
    }

    const int r_ = tid >> 2;          // staging row 0..63
    const int c2 = (tid & 3) * 2;     // chunk pair

    short8 stg[4];
    {
        const size_t kgb = ((size_t)bh * LL + r_) * DD + c2 * 8;
        const size_t vgb = ((size_t)bh * DD + r_) * LL + c2 * 8;
        stg[0] = *(const short8*)&Kh[kgb];  stg[1] = *(const short8*)&Kh[kgb + 8];
        stg[2] = *(const short8*)&Vth[vgb]; stg[3] = *(const short8*)&Vth[vgb + 8];
    }

    for (int kt = 0; kt < LL / 64; ++kt) {
        __syncthreads(); // previous tile fully consumed
        {
            const int wr = r_ * 64, s = r_ & 7;
            const int cA = ((c2) ^ s) * 8, cB = ((c2 + 1) ^ s) * 8;
            *(short8*)&sKh[wr + cA] = stg[0];
            *(short8*)&sKh[wr + cB] = stg[1];
            *(short8*)&sVh[wr + cA] = stg[2];
            *(short8*)&sVh[wr + cB] = stg[3];
        }
        __syncthreads();
        if (kt + 1 < LL / 64) { // prefetch next tile into regs
            const size_t kgb = ((size_t)bh * LL + (kt + 1) * 64 + r_) * DD + c2 * 8;
            const size_t vgb = ((size_t)bh * DD + r_) * LL + (kt + 1) * 64 + c2 * 8;
            stg[0] = *(const short8*)&Kh[kgb];  stg[1] = *(const short8*)&Kh[kgb + 8];
            stg[2] = *(const short8*)&Vth[vgb]; stg[3] = *(const short8*)&Vth[vgb + 8];
        }

        // ---- S^T = K Q : rows k (16t + 4*l4 + r), cols q (l16); log2 units
        f32x4 S[2][4];
#pragma unroll
        for (int qf = 0; qf < 2; ++qf)
#pragma unroll
        for (int t = 0; t < 4; ++t) S[qf][t] = 0.f;

        __builtin_amdgcn_s_setprio(1);
#pragma unroll
        for (int t = 0; t < 4; ++t) {
            const int row = 16 * t + l16;
            const int swr = row & 7;
#pragma unroll
            for (int sl = 0; sl < 2; ++sl) {
                const int idx = row * 64 + (((sl << 2) | l4) ^ swr) * 8;
                short8 kh8 = *(const short8*)&sKh[idx];
#pragma unroll
                for (int qf = 0; qf < 2; ++qf)
                    S[qf][t] = MFMA_BF16(kh8, qh[qf][sl], S[qf][t]);
            }
        }
        __builtin_amdgcn_s_setprio(0);

        // ---- lane-local softmax (exp2 domain), max via pairwise tree
#pragma unroll
        for (int qf = 0; qf < 2; ++qf) {
            float m0a = fmaxf(fmaxf(S[qf][0][0], S[qf][0][1]),
                              fmaxf(S[qf][0][2], S[qf][0][3]));
            float m1a = fmaxf(fmaxf(S[qf][1][0], S[qf][1][1]),
                              fmaxf(S[qf][1][2], S[qf][1][3]));
            float m2a = fmaxf(fmaxf(S[qf][2][0], S[qf][2][1]),
                              fmaxf(S[qf][2][2], S[qf][2][3]));
            float m3a = fmaxf(fmaxf(S[qf][3][0], S[qf][3][1]),
                              fmaxf(S[qf][3][2], S[qf][3][3]));
            float pm = fmaxf(fmaxf(m0a, m1a), fmaxf(m2a, m3a));
            pm = fmaxf(pm, __shfl_xor(pm, 16));
            pm = fmaxf(pm, __shfl_xor(pm, 32));

            if (__any(pm > mrow[qf] + 11.5f)) { // rescale (rare after tile 0)
                const float mnew = fmaxf(mrow[qf], pm);
                const float corr = exp2f(mrow[qf] - mnew);
                mrow[qf] = mnew;
                float c0 = __shfl(corr, 4 * l4 + 0);
                float c1 = __shfl(corr, 4 * l4 + 1);
                float c2v = __shfl(corr, 4 * l4 + 2);
                float c3 = __shfl(corr, 4 * l4 + 3);
                acc_l[qf][0] *= c0; acc_l[qf][1] *= c1;
                acc_l[qf][2] *= c2v; acc_l[qf][3] *= c3;
#pragma unroll
                for (int dt = 0; dt < 4; ++dt) {
                    O[qf][dt][0] *= c0; O[qf][dt][1] *= c1;
                    O[qf][dt][2] *= c2v; O[qf][dt][3] *= c3;
                }
            }
#pragma unroll
            for (int t = 0; t < 4; ++t)
#pragma unroll
                for (int r = 0; r < 4; ++r)
                    S[qf][t][r] = exp2f(S[qf][t][r] - mrow[qf]);
        }

        // ---- P -> per-wave LDS (bf16, scalar f2bf pack), b64 writes
#pragma unroll
        for (int qf = 0; qf < 2; ++qf)
#pragma unroll
        for (int t = 0; t < 4; ++t) {
            unsigned lo = (unsigned)f2bf(S[qf][t][0]) | ((unsigned)f2bf(S[qf][t][1]) << 16);
            unsigned hi = (unsigned)f2bf(S[qf][t][2]) | ((unsigned)f2bf(S[qf][t][3]) << 16);
            const int widx = (qf * 16 + l16) * 68 + 16 * t + 4 * l4;
            *(u64_t*)&sP[wv][widx] = (u64_t)lo | ((u64_t)hi << 32);
        }
        asm volatile("s_waitcnt lgkmcnt(0)" ::: "memory");
        __builtin_amdgcn_sched_barrier(0);

        // ---- P A-fragments: row q = l16, k = sl*32 + 8*l4 + j
        short8 pa[2][2];
#pragma unroll
        for (int qf = 0; qf < 2; ++qf)
#pragma unroll
        for (int sl = 0; sl < 2; ++sl) {
            const int ridx = (qf * 16 + l16) * 68 + sl * 32 + 8 * l4;
            union { u64_t q[2]; short8 s8; } u;
            u.q[0] = *(const u64_t*)&sP[wv][ridx];
            u.q[1] = *(const u64_t*)&sP[wv][ridx + 4];
            pa[qf][sl] = u.s8;
        }

        // ---- O += P V ; acc_l += P . ones (row-sum in O's layout)
        __builtin_amdgcn_s_setprio(1);
#pragma unroll
        for (int qf = 0; qf < 2; ++qf) {
            acc_l[qf] = MFMA_BF16(pa[qf][0], ones, acc_l[qf]);
            acc_l[qf] = MFMA_BF16(pa[qf][1], ones, acc_l[qf]);
        }
#pragma unroll
        for (int dt = 0; dt < 4; ++dt) {
            const int row = 16 * dt + l16;
            const int swr = row & 7;
#pragma unroll
            for (int sl = 0; sl < 2; ++sl) {
                const int idx = row * 64 + (((sl << 2) | l4) ^ swr) * 8;
                short8 vh8 = *(const short8*)&sVh[idx];
#pragma unroll
                for (int qf = 0; qf < 2; ++qf)
                    O[qf][dt] = MFMA_BF16(pa[qf][sl], vh8, O[qf][dt]);
            }
        }
        __builtin_amdgcn_s_setprio(0);
    }

    // ---- epilogue: h = O / l -> bf16 Hb rows (l is lane-local now)
#pragma unroll
    for (int qf = 0; qf < 2; ++qf) {
        f32x4 iv;
#pragma unroll
        for (int r = 0; r < 4; ++r) iv[r] = 1.0f / acc_l[qf][r];
#pragma unroll
        for (int r = 0; r < 4; ++r) {
            const int q = qr0 + qf * 16 + 4 * l4 + r;
            ushort_t* op = Hb + (size_t)(b * LL + q) * CC + h * DD + l16;
#pragma unroll
            for (int dt = 0; dt < 4; ++dt)
                op[16 * dt] = f2bf(O[qf][dt][r] * iv[r]);
        }
    }
}

// ---------------------------------------------------------------------------
// Legacy fp32 fallback kernels (only if ws_size is too small; never expected)
// ---------------------------------------------------------------------------
#define Bb 128
#define Bn 128
#define BKG 8

__global__ __launch_bounds__(256)
void gemm_bias(const float* __restrict__ A, const float* __restrict__ B,
               const float* __restrict__ bias, float* __restrict__ C,
               int M, int N, int K, int lda, int ldb, int ldc)
{
    __shared__ float As[BKG][Bb];
    __shared__ float Bs[BKG][Bn];

    const int tid = threadIdx.x;
    const int m0 = blockIdx.y * Bb;
    const int n0 = blockIdx.x * Bn;
    const int ty = tid >> 4, tx = tid & 15;
    const int arow = tid >> 1, acol = (tid & 1) * 4;
    const int brow = tid >> 5, bcol = (tid & 31) * 4;

    const float* Ap = A + (size_t)(m0 + arow) * lda + acol;
    const float* Bp = B + (size_t)brow * ldb + n0 + bcol;

    float acc[8][8];
#pragma unroll
    for (int i = 0; i < 8; ++i)
#pragma unroll
        for (int j = 0; j < 8; ++j) acc[i][j] = 0.f;

    for (int k0 = 0; k0 < K; k0 += BKG) {
        float4 av = *(const float4*)(Ap + k0);
        float4 bv = *(const float4*)(Bp + (size_t)k0 * ldb);
        __syncthreads();
        As[acol + 0][arow] = av.x;
        As[acol + 1][arow] = av.y;
        As[acol + 2][arow] = av.z;
        As[acol + 3][arow] = av.w;
        *(float4*)&Bs[brow][bcol] = bv;
        __syncthreads();
#pragma unroll
        for (int kk = 0; kk < BKG; ++kk) {
            float a[8], bvv[8];
            *(float4*)&a[0] = *(const float4*)&As[kk][ty * 4];
            *(float4*)&a[4] = *(const float4*)&As[kk][64 + ty * 4];
            *(float4*)&bvv[0] = *(const float4*)&Bs[kk][tx * 4];
            *(float4*)&bvv[4] = *(const float4*)&Bs[kk][64 + tx * 4];
#pragma unroll
            for (int i = 0; i < 8; ++i)
#pragma unroll
                for (int j = 0; j < 8; ++j)
                    acc[i][j] = fmaf(a[i], bvv[j], acc[i][j]);
        }
    }
#pragma unroll
    for (int ih = 0; ih < 2; ++ih)
#pragma unroll
    for (int i = 0; i < 4; ++i) {
        const int m = m0 + ih * 64 + ty * 4 + i;
#pragma unroll
        for (int jh = 0; jh < 2; ++jh) {
            const int n = n0 + jh * 64 + tx * 4;
            float4 o;
            o.x = acc[ih*4+i][jh*4+0] + bias[n+0];
            o.y = acc[ih*4+i][jh*4+1] + bias[n+1];
            o.z = acc[ih*4+i][jh*4+2] + bias[n+2];
            o.w = acc[ih*4+i][jh*4+3] + bias[n+3];
            *(float4*)(C + (size_t)m * ldc + n) = o;
        }
    }
}

__global__ __launch_bounds__(256)
void rmsnorm_qk(float* __restrict__ qkv,
                const float* __restrict__ gq, const float* __restrict__ gk)
{
    const int gt    = blockIdx.x * 256 + threadIdx.x;
    const int lane  = gt & 63;
    const int wave  = gt >> 6;
    const int which = wave & 1;
    const int h     = (wave >> 1) & (HH - 1);
    const int bl    = wave >> 5;

    float* p = qkv + (size_t)bl * (3 * CC) + which * CC + h * DD + lane;
    float v = *p;
    float ss = v * v;
#pragma unroll
    for (int off = 32; off; off >>= 1) ss += __shfl_xor(ss, off);
    float nrm = fmaxf(sqrtf(ss), 1e-12f);
    const float* g = which ? gk : gq;
    *p = v * (8.0f / nrm) * g[h * DD + lane];
}

__global__ __launch_bounds__(256)
void flash_fp32(float* __restrict__ qkv)
{
    const int qt = blockIdx.x, hh = blockIdx.y, bb = blockIdx.z;

    __shared__ float Qt[DD][64];
    __shared__ float Kt[DD][64];
    __shared__ float Vs[64][DD];
    __shared__ float Ps[64][64 + 4];

    const int tid = threadIdx.x;
    const int ty = tid >> 4, tx = tid & 15;
    const size_t rs_ = 3 * CC;
    const float* qbase = qkv + ((size_t)bb * LL + (size_t)qt * 64) * rs_ + hh * DD;
    const float* kbase = qkv + (size_t)bb * LL * rs_ + CC + hh * DD;
    const float* vbase = kbase + CC;

    {
        const int r = tid >> 2, c0 = (tid & 3) * 16;
#pragma unroll
        for (int u = 0; u < 4; ++u) {
            float4 v = *(const float4*)(qbase + (size_t)r * rs_ + c0 + u * 4);
            Qt[c0 + u*4 + 0][r] = v.x; Qt[c0 + u*4 + 1][r] = v.y;
            Qt[c0 + u*4 + 2][r] = v.z; Qt[c0 + u*4 + 3][r] = v.w;
        }
    }

    float mrow[4], lrow[4], O[4][4];
#pragma unroll
    for (int i = 0; i < 4; ++i) {
        mrow[i] = -INFINITY; lrow[i] = 0.f;
#pragma unroll
        for (int j = 0; j < 4; ++j) O[i][j] = 0.f;
    }

    for (int kt = 0; kt < LL / 64; ++kt) {
        __syncthreads();
        {
            const int r = tid >> 2, c0 = (tid & 3) * 16;
            const float* kr = kbase + ((size_t)kt * 64 + r) * rs_;
            const float* vr = vbase + ((size_t)kt * 64 + r) * rs_;
#pragma unroll
            for (int u = 0; u < 4; ++u) {
                float4 kv = *(const float4*)(kr + c0 + u * 4);
                Kt[c0 + u*4 + 0][r] = kv.x; Kt[c0 + u*4 + 1][r] = kv.y;
                Kt[c0 + u*4 + 2][r] = kv.z; Kt[c0 + u*4 + 3][r] = kv.w;
                *(float4*)&Vs[r][c0 + u*4] = *(const float4*)(vr + c0 + u * 4);
            }
        }
        __syncthreads();

        float S[4][4];
#pragma unroll
        for (int i = 0; i < 4; ++i)
#pragma unroll
            for (int j = 0; j < 4; ++j) S[i][j] = 0.f;
#pragma unroll 8
        for (int d = 0; d < DD; ++d) {
            float a[4], b[4];
            *(float4*)a = *(const float4*)&Qt[d][ty * 4];
            *(float4*)b = *(const float4*)&Kt[d][tx * 4];
#pragma unroll
            for (int i = 0; i < 4; ++i)
#pragma unroll
                for (int j = 0; j < 4; ++j) S[i][j] = fmaf(a[i], b[j], S[i][j]);
        }
#pragma unroll
        for (int i = 0; i < 4; ++i) {
#pragma unroll
            for (int j = 0; j < 4; ++j) S[i][j] *= 0.125f;
            float pm = fmaxf(fmaxf(S[i][0], S[i][1]), fmaxf(S[i][2], S[i][3]));
#pragma unroll
            for (int off = 1; off < 16; off <<= 1) pm = fmaxf(pm, __shfl_xor(pm, off));
            const float mnew = fmaxf(mrow[i], pm);
            const float corr = __expf(mrow[i] - mnew);
            float rsum = 0.f;
#pragma unroll
            for (int j = 0; j < 4; ++j) { S[i][j] = __expf(S[i][j] - mnew); rsum += S[i][j]; }
#pragma unroll
            for (int off = 1; off < 16; off <<= 1) rsum += __shfl_xor(rsum, off);
            mrow[i] = mnew;
            lrow[i] = lrow[i] * corr + rsum;
#pragma unroll
            for (int j = 0; j < 4; ++j) O[i][j] *= corr;
        }
#pragma unroll
        for (int i = 0; i < 4; ++i)
            *(float4*)&Ps[ty * 4 + i][tx * 4] = *(float4*)&S[i][0];
        __syncthreads();
#pragma unroll 4
        for (int k = 0; k < 64; k += 4) {
            float a[4][4];
#pragma unroll
            for (int i = 0; i < 4; ++i)
                *(float4*)&a[i][0] = *(const float4*)&Ps[ty * 4 + i][k];
#pragma unroll
            for (int kk = 0; kk < 4; ++kk) {
                float bv[4];
                *(float4*)bv = *(const float4*)&Vs[k + kk][tx * 4];
#pragma unroll
                for (int i = 0; i < 4; ++i)
#pragma unroll
                    for (int j = 0; j < 4; ++j)
                        O[i][j] = fmaf(a[i][kk], bv[j], O[i][j]);
            }
        }
    }

    float* obase = qkv + ((size_t)bb * LL + (size_t)qt * 64) * rs_ + hh * DD;
#pragma unroll
    for (int i = 0; i < 4; ++i) {
        const float inv = 1.f / lrow[i];
        float4 o;
        o.x = O[i][0] * inv; o.y = O[i][1] * inv;
        o.z = O[i][2] * inv; o.w = O[i][3] * inv;
        *(float4*)(obase + (size_t)(ty * 4 + i) * rs_ + tx * 4) = o;
    }
}

// ---------------------------------------------------------------------------
extern "C" void kernel_launch(void* const* d_in, const int* in_sizes, int n_in,
                              void* d_out, int out_size, void* d_ws, size_t ws_size,
                              hipStream_t stream)
{
    const float* x    = (const float*)d_in[0];
    const float* Wqkv = (const float*)d_in[1];
    const float* bqkv = (const float*)d_in[2];
    const float* gq   = (const float*)d_in[3];
    const float* gk   = (const float*)d_in[4];
    const float* Wout = (const float*)d_in[5];
    const float* bout = (const float*)d_in[6];
    float* out = (float*)d_out;

    const size_t NEED = 92274688ull; // 88 MiB

    if (ws_size >= NEED) {
        char* wsb = (char*)d_ws;
        ushort_t* Qbh = (ushort_t*)(wsb);                 // 16 MiB
        ushort_t* Kh  = (ushort_t*)(wsb + 16777216);      // 16 MiB
        ushort_t* Vth = (ushort_t*)(wsb + 33554432);      // 16 MiB
        ushort_t* Hb  = (ushort_t*)(wsb + 50331648);      // 16 MiB
        ushort_t* wqh = (ushort_t*)(wsb + 67108864);      // 6 MiB
        ushort_t* woh = (ushort_t*)(wsb + 73400320);      // 2 MiB
        ushort_t* xh  = (ushort_t*)(wsb + 75497472);      // 16 MiB

        transp_hi<<<dim3(3 * CC / 64, CC / 64), 256, 0, stream>>>(Wqkv, wqh, CC, 3 * CC);
        transp_hi<<<dim3(CC / 64, CC / 64), 256, 0, stream>>>(Wout, woh, CC, CC);
        round_bf16<<<dim3(MM * CC / 8 / 256), 256, 0, stream>>>(x, xh, MM * CC);

        gemm_qkv<<<dim3(24 * 64), 256, 0, stream>>>(
            xh, wqh, bqkv, gq, gk, Qbh, Kh, Vth);

        flash8<<<dim3(1024), 256, 0, stream>>>(Qbh, Kh, Vth, Hb);

        gemm_out1<<<dim3(8 * 64), 256, 0, stream>>>(Hb, woh, bout, out);
    } else {
        // legacy fp32 path
        float* qkv = (float*)d_ws;
        gemm_bias<<<dim3((3 * CC) / Bn, MM / Bb), 256, 0, stream>>>(
            x, Wqkv, bqkv, qkv, MM, 3 * CC, CC, CC, 3 * CC, 3 * CC);
        rmsnorm_qk<<<dim3((MM * HH * 2 * 64) / 256), 256, 0, stream>>>(qkv, gq, gk);
        flash_fp32<<<dim3(LL / 64, HH, BB), 256, 0, stream>>>(qkv);
        gemm_bias<<<dim3(CC / Bn, MM / Bb), 256, 0, stream>>>(
            qkv, Wout, bout, out, MM, CC, CC, 3 * CC, CC, CC);
    }
}